// Round 7
// baseline (511.380 us; speedup 1.0000x reference)
//
#include <hip/hip_runtime.h>
#include <hip/hip_bf16.h>
#include <math.h>

#define BSHIFT 7
#define BWIDTH (1 << BSHIFT)       // 128 dst per bucket
#define A3_TILE 2048

__device__ inline unsigned int f2bf(float f) {
    unsigned int u = __float_as_uint(f);
    return (u + 0x7FFFu + ((u >> 16) & 1u)) >> 16;   // RNE
}
__device__ inline float bflo(unsigned int u) { return __uint_as_float(u << 16); }
__device__ inline float bfhi(unsigned int u) { return __uint_as_float(u & 0xFFFF0000u); }

// ---------------- GEMM1: h1b(bf16) = x @ W1^T, plus s_src1/s_dst1 ----------------
#define G1_TN 256
#define G1_KC 16
__global__ __launch_bounds__(256) void gemm1_kernel(
    const float* __restrict__ x, const float* __restrict__ W1,
    const float* __restrict__ a_src, const float* __restrict__ a_dst,
    unsigned short* __restrict__ h1b, float* __restrict__ s1s,
    float* __restrict__ s1d, int N)
{
    __shared__ float Ws[128 * 64];      // Ws[k*64+c] = W1[c*128+k]
    __shared__ float xs[G1_KC][260];
    int tid = threadIdx.x;
    int nb = blockIdx.x * G1_TN;

    for (int i = tid; i < 64 * 128; i += 256) {
        int k = i >> 6, c = i & 63;
        Ws[i] = W1[c * 128 + k];
    }

    int ng = tid & 31;
    int cg = tid >> 5;
    int c0 = cg * 8;
    float acc[8][8];
    #pragma unroll
    for (int q = 0; q < 8; ++q)
        #pragma unroll
        for (int j = 0; j < 8; ++j) acc[q][j] = 0.f;

    for (int kc = 0; kc < 128; kc += G1_KC) {
        __syncthreads();
        #pragma unroll
        for (int r = 0; r < 4; ++r) {
            int i4 = tid + r * 256;
            int nl = i4 >> 2;
            int kk4 = (i4 & 3) * 4;
            int n = nb + nl;
            float4 v = (n < N) ? *(const float4*)&x[(size_t)n * 128 + kc + kk4]
                               : make_float4(0.f, 0.f, 0.f, 0.f);
            xs[kk4 + 0][nl] = v.x;
            xs[kk4 + 1][nl] = v.y;
            xs[kk4 + 2][nl] = v.z;
            xs[kk4 + 3][nl] = v.w;
        }
        __syncthreads();
        #pragma unroll
        for (int kk = 0; kk < G1_KC; ++kk) {
            float4 xa = *(const float4*)&xs[kk][ng * 4];
            float4 xb = *(const float4*)&xs[kk][128 + ng * 4];
            const float* wr = &Ws[(kc + kk) * 64 + c0];
            float4 w0 = *(const float4*)&wr[0];
            float4 w1 = *(const float4*)&wr[4];
            float xv[8] = {xa.x, xa.y, xa.z, xa.w, xb.x, xb.y, xb.z, xb.w};
            float wv[8] = {w0.x, w0.y, w0.z, w0.w, w1.x, w1.y, w1.z, w1.w};
            #pragma unroll
            for (int q = 0; q < 8; ++q)
                #pragma unroll
                for (int j = 0; j < 8; ++j)
                    acc[q][j] += xv[q] * wv[j];
        }
    }

    #pragma unroll
    for (int q = 0; q < 8; ++q) {
        int nl = (q < 4) ? (ng * 4 + q) : (128 + ng * 4 + (q - 4));
        int n = nb + nl;
        float ss = 0.f, sd = 0.f;
        #pragma unroll
        for (int j = 0; j < 8; ++j) {
            ss += acc[q][j] * a_src[c0 + j];
            sd += acc[q][j] * a_dst[c0 + j];
        }
        ss += __shfl_xor(ss, 32);
        sd += __shfl_xor(sd, 32);
        if (n < N) {
            uint4 pk;
            pk.x = f2bf(acc[q][0]) | (f2bf(acc[q][1]) << 16);
            pk.y = f2bf(acc[q][2]) | (f2bf(acc[q][3]) << 16);
            pk.z = f2bf(acc[q][4]) | (f2bf(acc[q][5]) << 16);
            pk.w = f2bf(acc[q][6]) | (f2bf(acc[q][7]) << 16);
            *(uint4*)(h1b + (size_t)n * 64 + c0) = pk;
            if ((cg & 1) == 0) {
                s1s[n * 4 + (cg >> 1)] = ss;
                s1d[n * 4 + (cg >> 1)] = sd;
            }
        }
    }
}

// ---------------- A1: bucket histogram (LDS-staged) ----------------
__global__ __launch_bounds__(256) void bhist_kernel(
    const int* __restrict__ ei, int* __restrict__ bhist, int E, int NBK)
{
    __shared__ int h[1024];
    for (int i = threadIdx.x; i < 1024; i += 256) h[i] = 0;
    __syncthreads();
    int stride = gridDim.x * 256;
    for (int e = blockIdx.x * 256 + threadIdx.x; e < E; e += stride)
        atomicAdd(&h[ei[E + e] >> BSHIFT], 1);
    __syncthreads();
    for (int b = threadIdx.x; b < NBK; b += 256) {
        int c = h[b];
        if (c) atomicAdd(&bhist[b], c);
    }
}

// ---------------- A2: exclusive scan over buckets -> bb, bcur ----------------
__global__ __launch_bounds__(1024) void bscan_kernel(
    const int* __restrict__ bhist, int* __restrict__ bb, int* __restrict__ bcur, int NBK)
{
    __shared__ int sh[1024];
    int t = threadIdx.x;
    int v = (t < NBK) ? bhist[t] : 0;
    sh[t] = v;
    __syncthreads();
    for (int o = 1; o < 1024; o <<= 1) {
        int u = (t >= o) ? sh[t - o] : 0;
        __syncthreads();
        sh[t] += u;
        __syncthreads();
    }
    int incl = sh[t];
    int excl = incl - v;
    if (t < NBK) { bb[t] = excl; bcur[t] = excl; }
    if (t == NBK - 1) bb[NBK] = incl;
}

// ---------------- A3: partition edges into bucket regions (packed) ----------------
__global__ __launch_bounds__(256) void partition_kernel(
    const int* __restrict__ ei, int* __restrict__ bcur, int* __restrict__ pairs,
    int E, int NBK)
{
    __shared__ int hist[1024];
    __shared__ int scanb[1024];
    __shared__ int gbase[1024];
    __shared__ int partial[256];
    __shared__ int stage_pack[A3_TILE];
    __shared__ int stage_pos[A3_TILE];
    int t = threadIdx.x;
    int e0 = blockIdx.x * A3_TILE;
    for (int i = t; i < 1024; i += 256) hist[i] = 0;
    __syncthreads();
    int my_b[8], my_rank[8], my_pack[8];
    #pragma unroll
    for (int j = 0; j < 8; ++j) {
        int e = e0 + j * 256 + t;
        int b = -1, pack = 0, r = 0;
        if (e < E) {
            int s = ei[e], d = ei[E + e];
            b = d >> BSHIFT;
            pack = ((d & (BWIDTH - 1)) << 17) | s;
            r = atomicAdd(&hist[b], 1);
        }
        my_b[j] = b; my_pack[j] = pack; my_rank[j] = r;
    }
    __syncthreads();
    int b4 = t * 4;
    int h0 = hist[b4], h1v = hist[b4 + 1], h2v = hist[b4 + 2], h3v = hist[b4 + 3];
    int tot = h0 + h1v + h2v + h3v;
    partial[t] = tot;
    __syncthreads();
    for (int o = 1; o < 256; o <<= 1) {
        int u = (t >= o) ? partial[t - o] : 0;
        __syncthreads();
        partial[t] += u;
        __syncthreads();
    }
    int excl = partial[t] - tot;
    scanb[b4]     = excl;
    scanb[b4 + 1] = excl + h0;
    scanb[b4 + 2] = excl + h0 + h1v;
    scanb[b4 + 3] = excl + h0 + h1v + h2v;
    int nvalid = partial[255];
    for (int b = t; b < NBK; b += 256) {
        int c = hist[b];
        if (c > 0) gbase[b] = atomicAdd(&bcur[b], c);
    }
    __syncthreads();
    #pragma unroll
    for (int j = 0; j < 8; ++j) {
        int b = my_b[j];
        if (b >= 0) {
            int slot = scanb[b] + my_rank[j];
            stage_pack[slot] = my_pack[j];
            stage_pos[slot]  = gbase[b] + my_rank[j];
        }
    }
    __syncthreads();
    for (int i = t; i < nvalid; i += 256)
        pairs[stage_pos[i]] = stage_pack[i];
}

// ---------------- B1: per-dst offs directly from bucket ----------------
__global__ __launch_bounds__(128) void offs_kernel(
    const int* __restrict__ pairs, const int* __restrict__ bb,
    int* __restrict__ offs, int N, int NBK, int E)
{
    int b = blockIdx.x;
    __shared__ int hist[BWIDTH];
    int t = threadIdx.x;
    hist[t] = 0;
    __syncthreads();
    int s = bb[b], e = bb[b + 1];
    for (int i = s + t; i < e; i += 128)
        atomicAdd(&hist[(pairs[i] >> 17) & (BWIDTH - 1)], 1);
    __syncthreads();
    int v = hist[t];
    for (int o = 1; o < BWIDTH; o <<= 1) {
        int u = (t >= o) ? hist[t - o] : 0;
        __syncthreads();
        hist[t] += u;
        __syncthreads();
    }
    int excl = hist[t] - v;
    int dst = b * BWIDTH + t;
    if (dst < N) offs[dst] = s + excl;
    if (b == 0 && t == 0) offs[N] = E;
}

// ---------------- B2: scatter src into CSR, LDS cursors ----------------
__global__ __launch_bounds__(128) void scat_kernel(
    const int* __restrict__ pairs, const int* __restrict__ bb,
    const int* __restrict__ offs, int* __restrict__ csr_src, int N)
{
    int b = blockIdx.x;
    __shared__ int cur[BWIDTH];
    int t = threadIdx.x;
    int dst = b * BWIDTH + t;
    cur[t] = (dst < N) ? offs[dst] : 0;
    __syncthreads();
    int s = bb[b], e = bb[b + 1];
    for (int i = s + t; i < e; i += 128) {
        int p = pairs[i];
        int pos = atomicAdd(&cur[(p >> 17) & (BWIDTH - 1)], 1);
        csr_src[pos] = p & 0x1FFFF;
    }
}

// ---- Conv1 aggregation (bf16 gather) + ELU + FUSED gemm2 -> h2p[N,16] bf16 ----
// 16 threads per node: 4 heads x 4 edge-quarters
__global__ __launch_bounds__(256) void agg1_kernel(
    const int* __restrict__ offs, const int* __restrict__ csr_src,
    const unsigned short* __restrict__ h1b, const float* __restrict__ s1s,
    const float* __restrict__ s1d, const float* __restrict__ b1,
    const float* __restrict__ W2, const float* __restrict__ as2,
    const float* __restrict__ ad2, unsigned short* __restrict__ h2p, int N)
{
    __shared__ float w2s[640];
    for (int i = threadIdx.x; i < 640; i += 256) w2s[i] = W2[i];
    __syncthreads();

    int tid = blockIdx.x * 256 + threadIdx.x;
    int n = tid >> 4, h = tid & 3, sub = (tid >> 2) & 3;
    float xl[16];
    #pragma unroll
    for (int j = 0; j < 16; ++j) xl[j] = 0.f;
    float den = 0.f;

    if (n < N) {
        float sdst = s1d[n * 4 + h];
        if (sub == 0) {   // self-loop
            float s = s1s[n * 4 + h] + sdst;
            s = (s >= 0.f) ? s : 0.2f * s;
            float w = __expf(s);
            den = w;
            const uint4* hp = (const uint4*)(h1b + ((size_t)n << 6) + (h << 4));
            uint4 a = hp[0], b = hp[1];
            xl[0] = w * bflo(a.x); xl[1] = w * bfhi(a.x);
            xl[2] = w * bflo(a.y); xl[3] = w * bfhi(a.y);
            xl[4] = w * bflo(a.z); xl[5] = w * bfhi(a.z);
            xl[6] = w * bflo(a.w); xl[7] = w * bfhi(a.w);
            xl[8]  = w * bflo(b.x); xl[9]  = w * bfhi(b.x);
            xl[10] = w * bflo(b.y); xl[11] = w * bfhi(b.y);
            xl[12] = w * bflo(b.z); xl[13] = w * bfhi(b.z);
            xl[14] = w * bflo(b.w); xl[15] = w * bfhi(b.w);
        }
        int row = offs[n], end = offs[n + 1];
        for (int i = row + sub; i < end; i += 4) {
            int src = csr_src[i];
            float ss = s1s[src * 4 + h] + sdst;
            ss = (ss >= 0.f) ? ss : 0.2f * ss;
            float we = __expf(ss);
            den += we;
            const uint4* sp = (const uint4*)(h1b + ((size_t)src << 6) + (h << 4));
            uint4 a = sp[0], b = sp[1];
            xl[0] += we * bflo(a.x); xl[1] += we * bfhi(a.x);
            xl[2] += we * bflo(a.y); xl[3] += we * bfhi(a.y);
            xl[4] += we * bflo(a.z); xl[5] += we * bfhi(a.z);
            xl[6] += we * bflo(a.w); xl[7] += we * bfhi(a.w);
            xl[8]  += we * bflo(b.x); xl[9]  += we * bfhi(b.x);
            xl[10] += we * bflo(b.y); xl[11] += we * bfhi(b.y);
            xl[12] += we * bflo(b.z); xl[13] += we * bfhi(b.z);
            xl[14] += we * bflo(b.w); xl[15] += we * bfhi(b.w);
        }
    }
    // merge edge-quarters within each head
    #pragma unroll
    for (int j = 0; j < 16; ++j) {
        xl[j] += __shfl_xor(xl[j], 4);
        xl[j] += __shfl_xor(xl[j], 8);
    }
    den += __shfl_xor(den, 4);
    den += __shfl_xor(den, 8);

    float inv = 1.f / (den + 1e-16f);
    #pragma unroll
    for (int j = 0; j < 16; ++j) {
        float v = xl[j] * inv + b1[h * 16 + j];
        xl[j] = (v > 0.f) ? v : (__expf(v) - 1.f);
    }

    // fused layer-2 matmul: part[c] = sum_j xl[j] * W2[c][h*16+j]
    float part[10];
    #pragma unroll
    for (int c = 0; c < 10; ++c) {
        const float* wr = &w2s[c * 64 + h * 16];
        float p = 0.f;
        #pragma unroll
        for (int j = 0; j < 16; ++j) p += xl[j] * wr[j];
        part[c] = p;
    }
    #pragma unroll
    for (int c = 0; c < 10; ++c) {
        part[c] += __shfl_xor(part[c], 1);
        part[c] += __shfl_xor(part[c], 2);
    }
    if (n < N && sub == 0) {
        if (h == 0) {
            uint4 pk;
            pk.x = f2bf(part[0]) | (f2bf(part[1]) << 16);
            pk.y = f2bf(part[2]) | (f2bf(part[3]) << 16);
            pk.z = f2bf(part[4]) | (f2bf(part[5]) << 16);
            pk.w = f2bf(part[6]) | (f2bf(part[7]) << 16);
            *(uint4*)(h2p + (size_t)n * 16) = pk;
        } else if (h == 1) {
            float ss = 0.f, sd = 0.f;
            #pragma unroll
            for (int c = 0; c < 10; ++c) {
                ss += part[c] * as2[c];
                sd += part[c] * ad2[c];
            }
            uint2 pk;
            pk.x = f2bf(part[8]) | (f2bf(part[9]) << 16);
            pk.y = f2bf(ss) | (f2bf(sd) << 16);
            *(uint2*)(h2p + (size_t)n * 16 + 8) = pk;
        }
    }
}

// ---- Conv2 aggregation (bf16 rows, 16 threads/node) + normalize + pool ----
__global__ __launch_bounds__(256) void agg2_pool_kernel(
    const int* __restrict__ offs, const int* __restrict__ csr_src,
    const unsigned short* __restrict__ h2p, const float* __restrict__ b2,
    const int* __restrict__ batch, float* __restrict__ pooled,
    float* __restrict__ cnt, int N)
{
    int tid = blockIdx.x * 256 + threadIdx.x;
    int n = tid >> 4, t = tid & 15;
    bool active = n < N;
    float acc[10];
    #pragma unroll
    for (int c = 0; c < 10; ++c) acc[c] = 0.f;
    float den = 0.f;
    int g = -1;
    if (active) {
        g = batch[n];
        uint2 d1 = *(const uint2*)(h2p + (size_t)n * 16 + 8);  // {c8|c9, ss|sd}
        float sdst = bfhi(d1.y);
        if (t == 0) {
            uint4 d0 = *(const uint4*)(h2p + (size_t)n * 16);
            float s = bflo(d1.y) + sdst;
            s = (s >= 0.f) ? s : 0.2f * s;
            float w = __expf(s);
            den = w;
            acc[0] = w * bflo(d0.x); acc[1] = w * bfhi(d0.x);
            acc[2] = w * bflo(d0.y); acc[3] = w * bfhi(d0.y);
            acc[4] = w * bflo(d0.z); acc[5] = w * bfhi(d0.z);
            acc[6] = w * bflo(d0.w); acc[7] = w * bfhi(d0.w);
            acc[8] = w * bflo(d1.x); acc[9] = w * bfhi(d1.x);
        }
        int row = offs[n], end = offs[n + 1];
        for (int i = row + t; i < end; i += 16) {
            int src = csr_src[i];
            uint4 s0 = *(const uint4*)(h2p + (size_t)src * 16);
            uint2 s1 = *(const uint2*)(h2p + (size_t)src * 16 + 8);
            float s = bflo(s1.y) + sdst;
            s = (s >= 0.f) ? s : 0.2f * s;
            float we = __expf(s);
            den += we;
            acc[0] += we * bflo(s0.x); acc[1] += we * bfhi(s0.x);
            acc[2] += we * bflo(s0.y); acc[3] += we * bfhi(s0.y);
            acc[4] += we * bflo(s0.z); acc[5] += we * bfhi(s0.z);
            acc[6] += we * bflo(s0.w); acc[7] += we * bfhi(s0.w);
            acc[8] += we * bflo(s1.x); acc[9] += we * bfhi(s1.x);
        }
    }
    // 16-lane butterfly: all lanes of the node get full sums
    #pragma unroll
    for (int c = 0; c < 10; ++c) {
        acc[c] += __shfl_xor(acc[c], 1);
        acc[c] += __shfl_xor(acc[c], 2);
        acc[c] += __shfl_xor(acc[c], 4);
        acc[c] += __shfl_xor(acc[c], 8);
    }
    den += __shfl_xor(den, 1);
    den += __shfl_xor(den, 2);
    den += __shfl_xor(den, 4);
    den += __shfl_xor(den, 8);

    bool leader = active && (t == 0);
    float inv = 1.f / (den + 1e-16f);
    float vals[10];
    #pragma unroll
    for (int c = 0; c < 10; ++c)
        vals[c] = leader ? (acc[c] * inv + b2[c]) : 0.f;

    int lane = threadIdx.x & 63;
    int g0 = __shfl(g, 0);
    bool uniform = __all(g == g0 || g < 0);
    if (uniform) {
        if (g0 >= 0) {
            #pragma unroll
            for (int c = 0; c < 10; ++c) {
                float v = vals[c];
                for (int o = 32; o > 0; o >>= 1) v += __shfl_down(v, o);
                if (lane == 0) atomicAdd(&pooled[g0 * 10 + c], v);
            }
            float one = leader ? 1.f : 0.f;
            for (int o = 32; o > 0; o >>= 1) one += __shfl_down(one, o);
            if (lane == 0) atomicAdd(&cnt[g0], one);
        }
    } else if (leader) {
        #pragma unroll
        for (int c = 0; c < 10; ++c) atomicAdd(&pooled[g * 10 + c], vals[c]);
        atomicAdd(&cnt[g], 1.f);
    }
}

// ---------------- Final: mean + log_softmax ----------------
__global__ void final_kernel(const float* __restrict__ pooled,
                             const float* __restrict__ cnt, float* __restrict__ out)
{
    int g = threadIdx.x;
    if (g >= 64) return;
    float c = cnt[g];
    if (c < 1.f) c = 1.f;
    float v[10], m = -1e30f;
    #pragma unroll
    for (int i = 0; i < 10; ++i) {
        v[i] = pooled[g * 10 + i] / c;
        m = fmaxf(m, v[i]);
    }
    float s = 0.f;
    #pragma unroll
    for (int i = 0; i < 10; ++i) s += __expf(v[i] - m);
    float lse = m + logf(s);
    #pragma unroll
    for (int i = 0; i < 10; ++i) out[g * 10 + i] = v[i] - lse;
}

extern "C" void kernel_launch(void* const* d_in, const int* in_sizes, int n_in,
                              void* d_out, int out_size, void* d_ws, size_t ws_size,
                              hipStream_t stream) {
    const float* x       = (const float*)d_in[0];
    const int*   ei      = (const int*)  d_in[1];
    const int*   batch   = (const int*)  d_in[2];
    const float* W1      = (const float*)d_in[3];
    const float* a_src1  = (const float*)d_in[4];
    const float* a_dst1  = (const float*)d_in[5];
    const float* b1      = (const float*)d_in[6];
    const float* W2      = (const float*)d_in[7];
    const float* a_src2  = (const float*)d_in[8];
    const float* a_dst2  = (const float*)d_in[9];
    const float* b2      = (const float*)d_in[10];
    float* out = (float*)d_out;

    int N = in_sizes[0] / 128;
    int E = in_sizes[1] / 2;
    int NBK = (N + BWIDTH - 1) >> BSHIFT;

    float* f = (float*)d_ws;
    size_t off = 0;
    unsigned short* h1b = (unsigned short*)(f + off); off += (size_t)N * 32;  // N*64 bf16
    float* s1s  = f + off; off += (size_t)N * 4;
    float* s1d  = f + off; off += (size_t)N * 4;
    // time-aliased: pairs (E ints, live A3..scat) then h2p (N*16 bf16, agg1..agg2)
    unsigned short* h2p = (unsigned short*)(f + off);
    int*  pairs = (int*)(f + off);
    size_t r1 = ((size_t)N * 8 > (size_t)E) ? (size_t)N * 8 : (size_t)E;
    off += r1;
    int* iw = (int*)(f + off);
    size_t ioff = 0;
    int* offs    = iw + ioff; ioff += (size_t)N + 1;
    int* csr_src = iw + ioff; ioff += (size_t)E;
    int* bb      = iw + ioff; ioff += (size_t)NBK + 1;
    int* bcur    = iw + ioff; ioff += (size_t)NBK;
    int*   bhist  = iw + ioff;
    float* pooled = (float*)(iw + ioff + NBK);
    float* cnt    = pooled + 640;

    hipMemsetAsync((void*)bhist, 0, ((size_t)NBK + 704) * sizeof(int), stream);

    int g1_blocks = (N + G1_TN - 1) / G1_TN;
    gemm1_kernel<<<g1_blocks, 256, 0, stream>>>(x, W1, a_src1, a_dst1, h1b, s1s, s1d, N);

    bhist_kernel<<<256, 256, 0, stream>>>(ei, bhist, E, NBK);
    bscan_kernel<<<1, 1024, 0, stream>>>(bhist, bb, bcur, NBK);
    int ntiles = (E + A3_TILE - 1) / A3_TILE;
    partition_kernel<<<ntiles, 256, 0, stream>>>(ei, bcur, pairs, E, NBK);
    offs_kernel<<<NBK, 128, 0, stream>>>(pairs, bb, offs, N, NBK, E);
    scat_kernel<<<NBK, 128, 0, stream>>>(pairs, bb, offs, csr_src, N);

    agg1_kernel<<<(N * 16 + 255) / 256, 256, 0, stream>>>(
        offs, csr_src, h1b, s1s, s1d, b1, W2, a_src2, a_dst2, h2p, N);

    agg2_pool_kernel<<<(N * 16 + 255) / 256, 256, 0, stream>>>(
        offs, csr_src, h2p, b2, batch, pooled, cnt, N);

    final_kernel<<<1, 64, 0, stream>>>(pooled, cnt, out);
}

// Round 8
// 228.117 us; speedup vs baseline: 2.2417x; 2.2417x over previous
//
#include <hip/hip_runtime.h>
#include <hip/hip_bf16.h>
#include <math.h>

#define BSHIFT 7
#define BWIDTH (1 << BSHIFT)       // 128 dst per bucket
#define A3_TILE 2048

__device__ inline unsigned int f2bf(float f) {
    unsigned int u = __float_as_uint(f);
    return (u + 0x7FFFu + ((u >> 16) & 1u)) >> 16;   // RNE
}
__device__ inline float bflo(unsigned int u) { return __uint_as_float(u << 16); }
__device__ inline float bfhi(unsigned int u) { return __uint_as_float(u & 0xFFFF0000u); }

// ---------------- GEMM1: h1b(bf16) = x @ W1^T, plus s_src1/s_dst1 ----------------
#define G1_TN 256
#define G1_KC 16
__global__ __launch_bounds__(256) void gemm1_kernel(
    const float* __restrict__ x, const float* __restrict__ W1,
    const float* __restrict__ a_src, const float* __restrict__ a_dst,
    unsigned short* __restrict__ h1b, float* __restrict__ s1s,
    float* __restrict__ s1d, int N)
{
    __shared__ float Ws[128 * 64];      // Ws[k*64+c] = W1[c*128+k]
    __shared__ float xs[G1_KC][260];
    int tid = threadIdx.x;
    int nb = blockIdx.x * G1_TN;

    for (int i = tid; i < 64 * 128; i += 256) {
        int k = i >> 6, c = i & 63;
        Ws[i] = W1[c * 128 + k];
    }

    int ng = tid & 31;
    int cg = tid >> 5;
    int c0 = cg * 8;
    float acc[8][8];
    #pragma unroll
    for (int q = 0; q < 8; ++q)
        #pragma unroll
        for (int j = 0; j < 8; ++j) acc[q][j] = 0.f;

    for (int kc = 0; kc < 128; kc += G1_KC) {
        __syncthreads();
        #pragma unroll
        for (int r = 0; r < 4; ++r) {
            int i4 = tid + r * 256;
            int nl = i4 >> 2;
            int kk4 = (i4 & 3) * 4;
            int n = nb + nl;
            float4 v = (n < N) ? *(const float4*)&x[(size_t)n * 128 + kc + kk4]
                               : make_float4(0.f, 0.f, 0.f, 0.f);
            xs[kk4 + 0][nl] = v.x;
            xs[kk4 + 1][nl] = v.y;
            xs[kk4 + 2][nl] = v.z;
            xs[kk4 + 3][nl] = v.w;
        }
        __syncthreads();
        #pragma unroll
        for (int kk = 0; kk < G1_KC; ++kk) {
            float4 xa = *(const float4*)&xs[kk][ng * 4];
            float4 xb = *(const float4*)&xs[kk][128 + ng * 4];
            const float* wr = &Ws[(kc + kk) * 64 + c0];
            float4 w0 = *(const float4*)&wr[0];
            float4 w1 = *(const float4*)&wr[4];
            float xv[8] = {xa.x, xa.y, xa.z, xa.w, xb.x, xb.y, xb.z, xb.w};
            float wv[8] = {w0.x, w0.y, w0.z, w0.w, w1.x, w1.y, w1.z, w1.w};
            #pragma unroll
            for (int q = 0; q < 8; ++q)
                #pragma unroll
                for (int j = 0; j < 8; ++j)
                    acc[q][j] += xv[q] * wv[j];
        }
    }

    #pragma unroll
    for (int q = 0; q < 8; ++q) {
        int nl = (q < 4) ? (ng * 4 + q) : (128 + ng * 4 + (q - 4));
        int n = nb + nl;
        float ss = 0.f, sd = 0.f;
        #pragma unroll
        for (int j = 0; j < 8; ++j) {
            ss += acc[q][j] * a_src[c0 + j];
            sd += acc[q][j] * a_dst[c0 + j];
        }
        ss += __shfl_xor(ss, 32);
        sd += __shfl_xor(sd, 32);
        if (n < N) {
            uint4 pk;
            pk.x = f2bf(acc[q][0]) | (f2bf(acc[q][1]) << 16);
            pk.y = f2bf(acc[q][2]) | (f2bf(acc[q][3]) << 16);
            pk.z = f2bf(acc[q][4]) | (f2bf(acc[q][5]) << 16);
            pk.w = f2bf(acc[q][6]) | (f2bf(acc[q][7]) << 16);
            *(uint4*)(h1b + (size_t)n * 64 + c0) = pk;
            if ((cg & 1) == 0) {
                s1s[n * 4 + (cg >> 1)] = ss;
                s1d[n * 4 + (cg >> 1)] = sd;
            }
        }
    }
}

// ---------------- A1: bucket histogram (LDS-staged) ----------------
__global__ __launch_bounds__(256) void bhist_kernel(
    const int* __restrict__ ei, int* __restrict__ bhist, int E, int NBK)
{
    __shared__ int h[1024];
    for (int i = threadIdx.x; i < 1024; i += 256) h[i] = 0;
    __syncthreads();
    int stride = gridDim.x * 256;
    for (int e = blockIdx.x * 256 + threadIdx.x; e < E; e += stride)
        atomicAdd(&h[ei[E + e] >> BSHIFT], 1);
    __syncthreads();
    for (int b = threadIdx.x; b < NBK; b += 256) {
        int c = h[b];
        if (c) atomicAdd(&bhist[b], c);
    }
}

// ---------------- A2: exclusive scan over buckets -> bb, bcur ----------------
__global__ __launch_bounds__(1024) void bscan_kernel(
    const int* __restrict__ bhist, int* __restrict__ bb, int* __restrict__ bcur, int NBK)
{
    __shared__ int sh[1024];
    int t = threadIdx.x;
    int v = (t < NBK) ? bhist[t] : 0;
    sh[t] = v;
    __syncthreads();
    for (int o = 1; o < 1024; o <<= 1) {
        int u = (t >= o) ? sh[t - o] : 0;
        __syncthreads();
        sh[t] += u;
        __syncthreads();
    }
    int incl = sh[t];
    int excl = incl - v;
    if (t < NBK) { bb[t] = excl; bcur[t] = excl; }
    if (t == NBK - 1) bb[NBK] = incl;
}

// ---------------- A3: partition edges into bucket regions (packed) ----------------
__global__ __launch_bounds__(256) void partition_kernel(
    const int* __restrict__ ei, int* __restrict__ bcur, int* __restrict__ pairs,
    int E, int NBK)
{
    __shared__ int hist[1024];
    __shared__ int scanb[1024];
    __shared__ int gbase[1024];
    __shared__ int partial[256];
    __shared__ int stage_pack[A3_TILE];
    __shared__ int stage_pos[A3_TILE];
    int t = threadIdx.x;
    int e0 = blockIdx.x * A3_TILE;
    for (int i = t; i < 1024; i += 256) hist[i] = 0;
    __syncthreads();
    int my_b[8], my_rank[8], my_pack[8];
    #pragma unroll
    for (int j = 0; j < 8; ++j) {
        int e = e0 + j * 256 + t;
        int b = -1, pack = 0, r = 0;
        if (e < E) {
            int s = ei[e], d = ei[E + e];
            b = d >> BSHIFT;
            pack = ((d & (BWIDTH - 1)) << 17) | s;
            r = atomicAdd(&hist[b], 1);
        }
        my_b[j] = b; my_pack[j] = pack; my_rank[j] = r;
    }
    __syncthreads();
    int b4 = t * 4;
    int h0 = hist[b4], h1v = hist[b4 + 1], h2v = hist[b4 + 2], h3v = hist[b4 + 3];
    int tot = h0 + h1v + h2v + h3v;
    partial[t] = tot;
    __syncthreads();
    for (int o = 1; o < 256; o <<= 1) {
        int u = (t >= o) ? partial[t - o] : 0;
        __syncthreads();
        partial[t] += u;
        __syncthreads();
    }
    int excl = partial[t] - tot;
    scanb[b4]     = excl;
    scanb[b4 + 1] = excl + h0;
    scanb[b4 + 2] = excl + h0 + h1v;
    scanb[b4 + 3] = excl + h0 + h1v + h2v;
    int nvalid = partial[255];
    for (int b = t; b < NBK; b += 256) {
        int c = hist[b];
        if (c > 0) gbase[b] = atomicAdd(&bcur[b], c);
    }
    __syncthreads();
    #pragma unroll
    for (int j = 0; j < 8; ++j) {
        int b = my_b[j];
        if (b >= 0) {
            int slot = scanb[b] + my_rank[j];
            stage_pack[slot] = my_pack[j];
            stage_pos[slot]  = gbase[b] + my_rank[j];
        }
    }
    __syncthreads();
    for (int i = t; i < nvalid; i += 256)
        pairs[stage_pos[i]] = stage_pack[i];
}

// ---------------- B1: per-dst offs directly from bucket ----------------
__global__ __launch_bounds__(128) void offs_kernel(
    const int* __restrict__ pairs, const int* __restrict__ bb,
    int* __restrict__ offs, int N, int NBK, int E)
{
    int b = blockIdx.x;
    __shared__ int hist[BWIDTH];
    int t = threadIdx.x;
    hist[t] = 0;
    __syncthreads();
    int s = bb[b], e = bb[b + 1];
    for (int i = s + t; i < e; i += 128)
        atomicAdd(&hist[(pairs[i] >> 17) & (BWIDTH - 1)], 1);
    __syncthreads();
    int v = hist[t];
    for (int o = 1; o < BWIDTH; o <<= 1) {
        int u = (t >= o) ? hist[t - o] : 0;
        __syncthreads();
        hist[t] += u;
        __syncthreads();
    }
    int excl = hist[t] - v;
    int dst = b * BWIDTH + t;
    if (dst < N) offs[dst] = s + excl;
    if (b == 0 && t == 0) offs[N] = E;
}

// ---------------- B2: scatter src into CSR, LDS cursors ----------------
__global__ __launch_bounds__(128) void scat_kernel(
    const int* __restrict__ pairs, const int* __restrict__ bb,
    const int* __restrict__ offs, int* __restrict__ csr_src, int N)
{
    int b = blockIdx.x;
    __shared__ int cur[BWIDTH];
    int t = threadIdx.x;
    int dst = b * BWIDTH + t;
    cur[t] = (dst < N) ? offs[dst] : 0;
    __syncthreads();
    int s = bb[b], e = bb[b + 1];
    for (int i = s + t; i < e; i += 128) {
        int p = pairs[i];
        int pos = atomicAdd(&cur[(p >> 17) & (BWIDTH - 1)], 1);
        csr_src[pos] = p & 0x1FFFF;
    }
}

// ---- Conv1 aggregation (bf16 gather) + ELU + FUSED gemm2 -> h2p[N,16] bf16 ----
// 16 threads per node: 4 heads x 4 edge-quarters
__global__ __launch_bounds__(256) void agg1_kernel(
    const int* __restrict__ offs, const int* __restrict__ csr_src,
    const unsigned short* __restrict__ h1b, const float* __restrict__ s1s,
    const float* __restrict__ s1d, const float* __restrict__ b1,
    const float* __restrict__ W2, const float* __restrict__ as2,
    const float* __restrict__ ad2, unsigned short* __restrict__ h2p, int N)
{
    __shared__ float w2s[640];
    for (int i = threadIdx.x; i < 640; i += 256) w2s[i] = W2[i];
    __syncthreads();

    int tid = blockIdx.x * 256 + threadIdx.x;
    int n = tid >> 4, h = tid & 3, sub = (tid >> 2) & 3;
    float xl[16];
    #pragma unroll
    for (int j = 0; j < 16; ++j) xl[j] = 0.f;
    float den = 0.f;

    if (n < N) {
        float sdst = s1d[n * 4 + h];
        if (sub == 0) {   // self-loop
            float s = s1s[n * 4 + h] + sdst;
            s = (s >= 0.f) ? s : 0.2f * s;
            float w = __expf(s);
            den = w;
            const uint4* hp = (const uint4*)(h1b + ((size_t)n << 6) + (h << 4));
            uint4 a = hp[0], b = hp[1];
            xl[0] = w * bflo(a.x); xl[1] = w * bfhi(a.x);
            xl[2] = w * bflo(a.y); xl[3] = w * bfhi(a.y);
            xl[4] = w * bflo(a.z); xl[5] = w * bfhi(a.z);
            xl[6] = w * bflo(a.w); xl[7] = w * bfhi(a.w);
            xl[8]  = w * bflo(b.x); xl[9]  = w * bfhi(b.x);
            xl[10] = w * bflo(b.y); xl[11] = w * bfhi(b.y);
            xl[12] = w * bflo(b.z); xl[13] = w * bfhi(b.z);
            xl[14] = w * bflo(b.w); xl[15] = w * bfhi(b.w);
        }
        int row = offs[n], end = offs[n + 1];
        for (int i = row + sub; i < end; i += 4) {
            int src = csr_src[i];
            float ss = s1s[src * 4 + h] + sdst;
            ss = (ss >= 0.f) ? ss : 0.2f * ss;
            float we = __expf(ss);
            den += we;
            const uint4* sp = (const uint4*)(h1b + ((size_t)src << 6) + (h << 4));
            uint4 a = sp[0], b = sp[1];
            xl[0] += we * bflo(a.x); xl[1] += we * bfhi(a.x);
            xl[2] += we * bflo(a.y); xl[3] += we * bfhi(a.y);
            xl[4] += we * bflo(a.z); xl[5] += we * bfhi(a.z);
            xl[6] += we * bflo(a.w); xl[7] += we * bfhi(a.w);
            xl[8]  += we * bflo(b.x); xl[9]  += we * bfhi(b.x);
            xl[10] += we * bflo(b.y); xl[11] += we * bfhi(b.y);
            xl[12] += we * bflo(b.z); xl[13] += we * bfhi(b.z);
            xl[14] += we * bflo(b.w); xl[15] += we * bfhi(b.w);
        }
    }
    // merge edge-quarters within each head
    #pragma unroll
    for (int j = 0; j < 16; ++j) {
        xl[j] += __shfl_xor(xl[j], 4);
        xl[j] += __shfl_xor(xl[j], 8);
    }
    den += __shfl_xor(den, 4);
    den += __shfl_xor(den, 8);

    float inv = 1.f / (den + 1e-16f);
    #pragma unroll
    for (int j = 0; j < 16; ++j) {
        float v = xl[j] * inv + b1[h * 16 + j];
        xl[j] = (v > 0.f) ? v : (__expf(v) - 1.f);
    }

    // fused layer-2 matmul: part[c] = sum_j xl[j] * W2[c][h*16+j]
    float part[10];
    #pragma unroll
    for (int c = 0; c < 10; ++c) {
        const float* wr = &w2s[c * 64 + h * 16];
        float p = 0.f;
        #pragma unroll
        for (int j = 0; j < 16; ++j) p += xl[j] * wr[j];
        part[c] = p;
    }
    #pragma unroll
    for (int c = 0; c < 10; ++c) {
        part[c] += __shfl_xor(part[c], 1);
        part[c] += __shfl_xor(part[c], 2);
    }
    if (n < N && sub == 0) {
        if (h == 0) {
            uint4 pk;
            pk.x = f2bf(part[0]) | (f2bf(part[1]) << 16);
            pk.y = f2bf(part[2]) | (f2bf(part[3]) << 16);
            pk.z = f2bf(part[4]) | (f2bf(part[5]) << 16);
            pk.w = f2bf(part[6]) | (f2bf(part[7]) << 16);
            *(uint4*)(h2p + (size_t)n * 16) = pk;
        } else if (h == 1) {
            float ss = 0.f, sd = 0.f;
            #pragma unroll
            for (int c = 0; c < 10; ++c) {
                ss += part[c] * as2[c];
                sd += part[c] * ad2[c];
            }
            uint2 pk;
            pk.x = f2bf(part[8]) | (f2bf(part[9]) << 16);
            pk.y = f2bf(ss) | (f2bf(sd) << 16);
            *(uint2*)(h2p + (size_t)n * 16 + 8) = pk;
        }
    }
}

// ---- Conv2 aggregation (bf16 rows, 8 threads/node) -> node_out[N][12] f32 ----
// NO atomics: leader writes the normalized per-node result.
__global__ __launch_bounds__(256) void agg2_kernel(
    const int* __restrict__ offs, const int* __restrict__ csr_src,
    const unsigned short* __restrict__ h2p, const float* __restrict__ b2,
    float* __restrict__ node_out, int N)
{
    int tid = blockIdx.x * 256 + threadIdx.x;
    int n = tid >> 3, t = tid & 7;
    if (n >= N) return;
    float acc[10];
    #pragma unroll
    for (int c = 0; c < 10; ++c) acc[c] = 0.f;
    float den = 0.f;

    uint2 d1 = *(const uint2*)(h2p + (size_t)n * 16 + 8);  // {c8|c9, ss|sd}
    float sdst = bfhi(d1.y);
    if (t == 0) {
        uint4 d0 = *(const uint4*)(h2p + (size_t)n * 16);
        float s = bflo(d1.y) + sdst;
        s = (s >= 0.f) ? s : 0.2f * s;
        float w = __expf(s);
        den = w;
        acc[0] = w * bflo(d0.x); acc[1] = w * bfhi(d0.x);
        acc[2] = w * bflo(d0.y); acc[3] = w * bfhi(d0.y);
        acc[4] = w * bflo(d0.z); acc[5] = w * bfhi(d0.z);
        acc[6] = w * bflo(d0.w); acc[7] = w * bfhi(d0.w);
        acc[8] = w * bflo(d1.x); acc[9] = w * bfhi(d1.x);
    }
    int row = offs[n], end = offs[n + 1];
    for (int i = row + t; i < end; i += 8) {
        int src = csr_src[i];
        uint4 s0 = *(const uint4*)(h2p + (size_t)src * 16);
        uint2 s1 = *(const uint2*)(h2p + (size_t)src * 16 + 8);
        float s = bflo(s1.y) + sdst;
        s = (s >= 0.f) ? s : 0.2f * s;
        float we = __expf(s);
        den += we;
        acc[0] += we * bflo(s0.x); acc[1] += we * bfhi(s0.x);
        acc[2] += we * bflo(s0.y); acc[3] += we * bfhi(s0.y);
        acc[4] += we * bflo(s0.z); acc[5] += we * bfhi(s0.z);
        acc[6] += we * bflo(s0.w); acc[7] += we * bfhi(s0.w);
        acc[8] += we * bflo(s1.x); acc[9] += we * bfhi(s1.x);
    }
    // 8-lane butterfly
    #pragma unroll
    for (int c = 0; c < 10; ++c) {
        acc[c] += __shfl_xor(acc[c], 1);
        acc[c] += __shfl_xor(acc[c], 2);
        acc[c] += __shfl_xor(acc[c], 4);
    }
    den += __shfl_xor(den, 1);
    den += __shfl_xor(den, 2);
    den += __shfl_xor(den, 4);

    if (t == 0) {
        float inv = 1.f / (den + 1e-16f);
        float* o = &node_out[(size_t)n * 12];
        *(float4*)o = make_float4(acc[0]*inv + b2[0], acc[1]*inv + b2[1],
                                  acc[2]*inv + b2[2], acc[3]*inv + b2[3]);
        *(float4*)(o + 4) = make_float4(acc[4]*inv + b2[4], acc[5]*inv + b2[5],
                                        acc[6]*inv + b2[6], acc[7]*inv + b2[7]);
        *(float2*)(o + 8) = make_float2(acc[8]*inv + b2[8], acc[9]*inv + b2[9]);
    }
}

// ---- Pool: one block per graph; batch sorted -> binary-search range; no atomics ----
__global__ __launch_bounds__(256) void pool_kernel(
    const float* __restrict__ node_out, const int* __restrict__ batch,
    float* __restrict__ pooled, float* __restrict__ cnt, int N)
{
    int g = blockIdx.x;
    // lower_bound(batch, g) and lower_bound(batch, g+1)
    int lo = 0, hi = N;
    while (lo < hi) { int m = (lo + hi) >> 1; if (batch[m] < g) lo = m + 1; else hi = m; }
    int s0 = lo;
    hi = N;
    while (lo < hi) { int m = (lo + hi) >> 1; if (batch[m] < g + 1) lo = m + 1; else hi = m; }
    int s1 = lo;

    float acc[10];
    #pragma unroll
    for (int c = 0; c < 10; ++c) acc[c] = 0.f;
    for (int i = s0 + threadIdx.x; i < s1; i += 256) {
        const float* o = &node_out[(size_t)i * 12];
        float4 a = *(const float4*)o;
        float4 b = *(const float4*)(o + 4);
        float2 d = *(const float2*)(o + 8);
        acc[0] += a.x; acc[1] += a.y; acc[2] += a.z; acc[3] += a.w;
        acc[4] += b.x; acc[5] += b.y; acc[6] += b.z; acc[7] += b.w;
        acc[8] += d.x; acc[9] += d.y;
    }
    // wave reduce
    #pragma unroll
    for (int c = 0; c < 10; ++c)
        for (int o = 32; o > 0; o >>= 1) acc[c] += __shfl_down(acc[c], o);
    __shared__ float part[4][10];
    int wave = threadIdx.x >> 6, lane = threadIdx.x & 63;
    if (lane == 0)
        #pragma unroll
        for (int c = 0; c < 10; ++c) part[wave][c] = acc[c];
    __syncthreads();
    if (threadIdx.x < 10) {
        float s = part[0][threadIdx.x] + part[1][threadIdx.x]
                + part[2][threadIdx.x] + part[3][threadIdx.x];
        pooled[g * 10 + threadIdx.x] = s;
        if (threadIdx.x == 0) cnt[g] = (float)(s1 - s0);
    }
}

// ---------------- Final: mean + log_softmax ----------------
__global__ void final_kernel(const float* __restrict__ pooled,
                             const float* __restrict__ cnt, float* __restrict__ out)
{
    int g = threadIdx.x;
    if (g >= 64) return;
    float c = cnt[g];
    if (c < 1.f) c = 1.f;
    float v[10], m = -1e30f;
    #pragma unroll
    for (int i = 0; i < 10; ++i) {
        v[i] = pooled[g * 10 + i] / c;
        m = fmaxf(m, v[i]);
    }
    float s = 0.f;
    #pragma unroll
    for (int i = 0; i < 10; ++i) s += __expf(v[i] - m);
    float lse = m + logf(s);
    #pragma unroll
    for (int i = 0; i < 10; ++i) out[g * 10 + i] = v[i] - lse;
}

extern "C" void kernel_launch(void* const* d_in, const int* in_sizes, int n_in,
                              void* d_out, int out_size, void* d_ws, size_t ws_size,
                              hipStream_t stream) {
    const float* x       = (const float*)d_in[0];
    const int*   ei      = (const int*)  d_in[1];
    const int*   batch   = (const int*)  d_in[2];
    const float* W1      = (const float*)d_in[3];
    const float* a_src1  = (const float*)d_in[4];
    const float* a_dst1  = (const float*)d_in[5];
    const float* b1      = (const float*)d_in[6];
    const float* W2      = (const float*)d_in[7];
    const float* a_src2  = (const float*)d_in[8];
    const float* a_dst2  = (const float*)d_in[9];
    const float* b2      = (const float*)d_in[10];
    float* out = (float*)d_out;

    int N = in_sizes[0] / 128;
    int E = in_sizes[1] / 2;
    int NBK = (N + BWIDTH - 1) >> BSHIFT;

    float* f = (float*)d_ws;
    size_t off = 0;
    unsigned short* h1b = (unsigned short*)(f + off);
    float* node_out = (float*)h1b;      // aliased: h1b dead after agg1, node_out live agg2..pool
    off += (size_t)N * 32;              // N*64 bf16 = N*32 floats (>= N*12 floats)
    float* s1s  = f + off; off += (size_t)N * 4;
    float* s1d  = f + off; off += (size_t)N * 4;
    // time-aliased: pairs (E ints, live A3..scat) then h2p (N*16 bf16, agg1..agg2)
    unsigned short* h2p = (unsigned short*)(f + off);
    int*  pairs = (int*)(f + off);
    size_t r1 = ((size_t)N * 8 > (size_t)E) ? (size_t)N * 8 : (size_t)E;
    off += r1;
    int* iw = (int*)(f + off);
    size_t ioff = 0;
    int* offs    = iw + ioff; ioff += (size_t)N + 1;
    int* csr_src = iw + ioff; ioff += (size_t)E;
    int* bb      = iw + ioff; ioff += (size_t)NBK + 1;
    int* bcur    = iw + ioff; ioff += (size_t)NBK;
    int*   bhist  = iw + ioff;
    float* pooled = (float*)(iw + ioff + NBK);
    float* cnt    = pooled + 640;

    hipMemsetAsync((void*)bhist, 0, (size_t)NBK * sizeof(int), stream);

    int g1_blocks = (N + G1_TN - 1) / G1_TN;
    gemm1_kernel<<<g1_blocks, 256, 0, stream>>>(x, W1, a_src1, a_dst1, h1b, s1s, s1d, N);

    bhist_kernel<<<256, 256, 0, stream>>>(ei, bhist, E, NBK);
    bscan_kernel<<<1, 1024, 0, stream>>>(bhist, bb, bcur, NBK);
    int ntiles = (E + A3_TILE - 1) / A3_TILE;
    partition_kernel<<<ntiles, 256, 0, stream>>>(ei, bcur, pairs, E, NBK);
    offs_kernel<<<NBK, 128, 0, stream>>>(pairs, bb, offs, N, NBK, E);
    scat_kernel<<<NBK, 128, 0, stream>>>(pairs, bb, offs, csr_src, N);

    agg1_kernel<<<(N * 16 + 255) / 256, 256, 0, stream>>>(
        offs, csr_src, h1b, s1s, s1d, b1, W2, a_src2, a_dst2, h2p, N);

    agg2_kernel<<<(N * 8 + 255) / 256, 256, 0, stream>>>(
        offs, csr_src, h2p, b2, node_out, N);

    pool_kernel<<<64, 256, 0, stream>>>(node_out, batch, pooled, cnt, N);

    final_kernel<<<1, 64, 0, stream>>>(pooled, cnt, out);
}

// Round 9
// 211.854 us; speedup vs baseline: 2.4138x; 1.0768x over previous
//
#include <hip/hip_runtime.h>
#include <hip/hip_bf16.h>
#include <math.h>

#define BSHIFT 7
#define BWIDTH (1 << BSHIFT)       // 128 dst per bucket
#define A3_TILE 2048

typedef float floatx2 __attribute__((ext_vector_type(2)));

__device__ inline unsigned int f2bf(float f) {
    unsigned int u = __float_as_uint(f);
    return (u + 0x7FFFu + ((u >> 16) & 1u)) >> 16;   // RNE
}
__device__ inline float bflo(unsigned int u) { return __uint_as_float(u << 16); }
__device__ inline float bfhi(unsigned int u) { return __uint_as_float(u & 0xFFFF0000u); }

// decode 16 fp8 (one uint4) and fma into xl[0..15]
__device__ inline void fp8x16_fma(uint4 Wv, float we, float* xl) {
    floatx2 p;
    p = __builtin_amdgcn_cvt_pk_f32_fp8((int)Wv.x, false); xl[0] += we*p[0]; xl[1] += we*p[1];
    p = __builtin_amdgcn_cvt_pk_f32_fp8((int)Wv.x, true);  xl[2] += we*p[0]; xl[3] += we*p[1];
    p = __builtin_amdgcn_cvt_pk_f32_fp8((int)Wv.y, false); xl[4] += we*p[0]; xl[5] += we*p[1];
    p = __builtin_amdgcn_cvt_pk_f32_fp8((int)Wv.y, true);  xl[6] += we*p[0]; xl[7] += we*p[1];
    p = __builtin_amdgcn_cvt_pk_f32_fp8((int)Wv.z, false); xl[8] += we*p[0]; xl[9] += we*p[1];
    p = __builtin_amdgcn_cvt_pk_f32_fp8((int)Wv.z, true);  xl[10] += we*p[0]; xl[11] += we*p[1];
    p = __builtin_amdgcn_cvt_pk_f32_fp8((int)Wv.w, false); xl[12] += we*p[0]; xl[13] += we*p[1];
    p = __builtin_amdgcn_cvt_pk_f32_fp8((int)Wv.w, true);  xl[14] += we*p[0]; xl[15] += we*p[1];
}

// ---------------- GEMM1: h1f(fp8) = x @ W1^T, plus s_src1/s_dst1 ----------------
#define G1_TN 256
#define G1_KC 16
__global__ __launch_bounds__(256) void gemm1_kernel(
    const float* __restrict__ x, const float* __restrict__ W1,
    const float* __restrict__ a_src, const float* __restrict__ a_dst,
    unsigned char* __restrict__ h1f, float* __restrict__ s1s,
    float* __restrict__ s1d, int N)
{
    __shared__ float Ws[128 * 64];      // Ws[k*64+c] = W1[c*128+k]
    __shared__ float xs[G1_KC][260];
    int tid = threadIdx.x;
    int nb = blockIdx.x * G1_TN;

    for (int i = tid; i < 64 * 128; i += 256) {
        int k = i >> 6, c = i & 63;
        Ws[i] = W1[c * 128 + k];
    }

    int ng = tid & 31;
    int cg = tid >> 5;
    int c0 = cg * 8;
    float acc[8][8];
    #pragma unroll
    for (int q = 0; q < 8; ++q)
        #pragma unroll
        for (int j = 0; j < 8; ++j) acc[q][j] = 0.f;

    for (int kc = 0; kc < 128; kc += G1_KC) {
        __syncthreads();
        #pragma unroll
        for (int r = 0; r < 4; ++r) {
            int i4 = tid + r * 256;
            int nl = i4 >> 2;
            int kk4 = (i4 & 3) * 4;
            int n = nb + nl;
            float4 v = (n < N) ? *(const float4*)&x[(size_t)n * 128 + kc + kk4]
                               : make_float4(0.f, 0.f, 0.f, 0.f);
            xs[kk4 + 0][nl] = v.x;
            xs[kk4 + 1][nl] = v.y;
            xs[kk4 + 2][nl] = v.z;
            xs[kk4 + 3][nl] = v.w;
        }
        __syncthreads();
        #pragma unroll
        for (int kk = 0; kk < G1_KC; ++kk) {
            float4 xa = *(const float4*)&xs[kk][ng * 4];
            float4 xb = *(const float4*)&xs[kk][128 + ng * 4];
            const float* wr = &Ws[(kc + kk) * 64 + c0];
            float4 w0 = *(const float4*)&wr[0];
            float4 w1 = *(const float4*)&wr[4];
            float xv[8] = {xa.x, xa.y, xa.z, xa.w, xb.x, xb.y, xb.z, xb.w};
            float wv[8] = {w0.x, w0.y, w0.z, w0.w, w1.x, w1.y, w1.z, w1.w};
            #pragma unroll
            for (int q = 0; q < 8; ++q)
                #pragma unroll
                for (int j = 0; j < 8; ++j)
                    acc[q][j] += xv[q] * wv[j];
        }
    }

    #pragma unroll
    for (int q = 0; q < 8; ++q) {
        int nl = (q < 4) ? (ng * 4 + q) : (128 + ng * 4 + (q - 4));
        int n = nb + nl;
        float ss = 0.f, sd = 0.f;
        #pragma unroll
        for (int j = 0; j < 8; ++j) {
            ss += acc[q][j] * a_src[c0 + j];
            sd += acc[q][j] * a_dst[c0 + j];
        }
        ss += __shfl_xor(ss, 32);
        sd += __shfl_xor(sd, 32);
        if (n < N) {
            unsigned int w0 = (unsigned int)__builtin_amdgcn_cvt_pk_fp8_f32(acc[q][0], acc[q][1], 0, false);
            w0 = (unsigned int)__builtin_amdgcn_cvt_pk_fp8_f32(acc[q][2], acc[q][3], (int)w0, true);
            unsigned int w1 = (unsigned int)__builtin_amdgcn_cvt_pk_fp8_f32(acc[q][4], acc[q][5], 0, false);
            w1 = (unsigned int)__builtin_amdgcn_cvt_pk_fp8_f32(acc[q][6], acc[q][7], (int)w1, true);
            *(uint2*)(h1f + (size_t)n * 64 + c0) = make_uint2(w0, w1);
            if ((cg & 1) == 0) {
                s1s[n * 4 + (cg >> 1)] = ss;
                s1d[n * 4 + (cg >> 1)] = sd;
            }
        }
    }
}

// ---------------- A1: bucket histogram (LDS-staged) ----------------
__global__ __launch_bounds__(256) void bhist_kernel(
    const int* __restrict__ ei, int* __restrict__ bhist, int E, int NBK)
{
    __shared__ int h[1024];
    for (int i = threadIdx.x; i < 1024; i += 256) h[i] = 0;
    __syncthreads();
    int stride = gridDim.x * 256;
    for (int e = blockIdx.x * 256 + threadIdx.x; e < E; e += stride)
        atomicAdd(&h[ei[E + e] >> BSHIFT], 1);
    __syncthreads();
    for (int b = threadIdx.x; b < NBK; b += 256) {
        int c = h[b];
        if (c) atomicAdd(&bhist[b], c);
    }
}

// ---------------- A2: exclusive scan over buckets -> bb, bcur ----------------
__global__ __launch_bounds__(1024) void bscan_kernel(
    const int* __restrict__ bhist, int* __restrict__ bb, int* __restrict__ bcur, int NBK)
{
    __shared__ int sh[1024];
    int t = threadIdx.x;
    int v = (t < NBK) ? bhist[t] : 0;
    sh[t] = v;
    __syncthreads();
    for (int o = 1; o < 1024; o <<= 1) {
        int u = (t >= o) ? sh[t - o] : 0;
        __syncthreads();
        sh[t] += u;
        __syncthreads();
    }
    int incl = sh[t];
    int excl = incl - v;
    if (t < NBK) { bb[t] = excl; bcur[t] = excl; }
    if (t == NBK - 1) bb[NBK] = incl;
}

// ---------------- A3: partition edges into bucket regions (packed) ----------------
__global__ __launch_bounds__(256) void partition_kernel(
    const int* __restrict__ ei, int* __restrict__ bcur, int* __restrict__ pairs,
    int E, int NBK)
{
    __shared__ int hist[1024];
    __shared__ int scanb[1024];
    __shared__ int gbase[1024];
    __shared__ int partial[256];
    __shared__ int stage_pack[A3_TILE];
    __shared__ int stage_pos[A3_TILE];
    int t = threadIdx.x;
    int e0 = blockIdx.x * A3_TILE;
    for (int i = t; i < 1024; i += 256) hist[i] = 0;
    __syncthreads();
    int my_b[8], my_rank[8], my_pack[8];
    #pragma unroll
    for (int j = 0; j < 8; ++j) {
        int e = e0 + j * 256 + t;
        int b = -1, pack = 0, r = 0;
        if (e < E) {
            int s = ei[e], d = ei[E + e];
            b = d >> BSHIFT;
            pack = ((d & (BWIDTH - 1)) << 17) | s;
            r = atomicAdd(&hist[b], 1);
        }
        my_b[j] = b; my_pack[j] = pack; my_rank[j] = r;
    }
    __syncthreads();
    int b4 = t * 4;
    int h0 = hist[b4], h1v = hist[b4 + 1], h2v = hist[b4 + 2], h3v = hist[b4 + 3];
    int tot = h0 + h1v + h2v + h3v;
    partial[t] = tot;
    __syncthreads();
    for (int o = 1; o < 256; o <<= 1) {
        int u = (t >= o) ? partial[t - o] : 0;
        __syncthreads();
        partial[t] += u;
        __syncthreads();
    }
    int excl = partial[t] - tot;
    scanb[b4]     = excl;
    scanb[b4 + 1] = excl + h0;
    scanb[b4 + 2] = excl + h0 + h1v;
    scanb[b4 + 3] = excl + h0 + h1v + h2v;
    int nvalid = partial[255];
    for (int b = t; b < NBK; b += 256) {
        int c = hist[b];
        if (c > 0) gbase[b] = atomicAdd(&bcur[b], c);
    }
    __syncthreads();
    #pragma unroll
    for (int j = 0; j < 8; ++j) {
        int b = my_b[j];
        if (b >= 0) {
            int slot = scanb[b] + my_rank[j];
            stage_pack[slot] = my_pack[j];
            stage_pos[slot]  = gbase[b] + my_rank[j];
        }
    }
    __syncthreads();
    for (int i = t; i < nvalid; i += 256)
        pairs[stage_pos[i]] = stage_pack[i];
}

// ---------------- B1: per-dst offs directly from bucket ----------------
__global__ __launch_bounds__(128) void offs_kernel(
    const int* __restrict__ pairs, const int* __restrict__ bb,
    int* __restrict__ offs, int N, int NBK, int E)
{
    int b = blockIdx.x;
    __shared__ int hist[BWIDTH];
    int t = threadIdx.x;
    hist[t] = 0;
    __syncthreads();
    int s = bb[b], e = bb[b + 1];
    for (int i = s + t; i < e; i += 128)
        atomicAdd(&hist[(pairs[i] >> 17) & (BWIDTH - 1)], 1);
    __syncthreads();
    int v = hist[t];
    for (int o = 1; o < BWIDTH; o <<= 1) {
        int u = (t >= o) ? hist[t - o] : 0;
        __syncthreads();
        hist[t] += u;
        __syncthreads();
    }
    int excl = hist[t] - v;
    int dst = b * BWIDTH + t;
    if (dst < N) offs[dst] = s + excl;
    if (b == 0 && t == 0) offs[N] = E;
}

// ---------------- B2: scatter src into CSR, LDS cursors ----------------
__global__ __launch_bounds__(128) void scat_kernel(
    const int* __restrict__ pairs, const int* __restrict__ bb,
    const int* __restrict__ offs, int* __restrict__ csr_src, int N)
{
    int b = blockIdx.x;
    __shared__ int cur[BWIDTH];
    int t = threadIdx.x;
    int dst = b * BWIDTH + t;
    cur[t] = (dst < N) ? offs[dst] : 0;
    __syncthreads();
    int s = bb[b], e = bb[b + 1];
    for (int i = s + t; i < e; i += 128) {
        int p = pairs[i];
        int pos = atomicAdd(&cur[(p >> 17) & (BWIDTH - 1)], 1);
        csr_src[pos] = p & 0x1FFFF;
    }
}

// ---- Conv1 aggregation (fp8 gather) + ELU + FUSED gemm2 -> h2p[N,16] bf16 ----
// 16 threads per node: 4 heads x 4 edge-quarters; gemm2 c-split across subs
__global__ __launch_bounds__(256) void agg1_kernel(
    const int* __restrict__ offs, const int* __restrict__ csr_src,
    const unsigned char* __restrict__ h1f, const float* __restrict__ s1s,
    const float* __restrict__ s1d, const float* __restrict__ b1,
    const float* __restrict__ W2, const float* __restrict__ as2,
    const float* __restrict__ ad2, unsigned short* __restrict__ h2p, int N)
{
    __shared__ float w2s[640];
    for (int i = threadIdx.x; i < 640; i += 256) w2s[i] = W2[i];
    __syncthreads();

    int tid = blockIdx.x * 256 + threadIdx.x;
    int n = tid >> 4, h = tid & 3, sub = (tid >> 2) & 3;
    float xl[16];
    #pragma unroll
    for (int j = 0; j < 16; ++j) xl[j] = 0.f;
    float den = 0.f;

    if (n < N) {
        float sdst = s1d[n * 4 + h];
        if (sub == 0) {   // self-loop
            float s = s1s[n * 4 + h] + sdst;
            s = (s >= 0.f) ? s : 0.2f * s;
            float w = __expf(s);
            den = w;
            uint4 Wv = *(const uint4*)(h1f + ((size_t)n << 6) + (h << 4));
            fp8x16_fma(Wv, w, xl);
        }
        int row = offs[n], end = offs[n + 1];
        for (int i = row + sub; i < end; i += 4) {
            int src = csr_src[i];
            float ss = s1s[src * 4 + h] + sdst;
            ss = (ss >= 0.f) ? ss : 0.2f * ss;
            float we = __expf(ss);
            den += we;
            uint4 Wv = *(const uint4*)(h1f + ((size_t)src << 6) + (h << 4));
            fp8x16_fma(Wv, we, xl);
        }
    }
    // merge edge-quarters within each head
    #pragma unroll
    for (int j = 0; j < 16; ++j) {
        xl[j] += __shfl_xor(xl[j], 4);
        xl[j] += __shfl_xor(xl[j], 8);
    }
    den += __shfl_xor(den, 4);
    den += __shfl_xor(den, 8);

    float inv = 1.f / (den + 1e-16f);
    #pragma unroll
    for (int j = 0; j < 16; ++j) {
        float v = xl[j] * inv + b1[h * 16 + j];
        xl[j] = (v > 0.f) ? v : (__expf(v) - 1.f);
    }

    // fused layer-2 matmul, c-split across subs: sub0:c0-2 sub1:c3-5 sub2:c6-8 sub3:c9
    int clo = sub * 3;
    int nc = (sub == 3) ? 1 : 3;
    float part[3] = {0.f, 0.f, 0.f};
    #pragma unroll
    for (int idx = 0; idx < 3; ++idx) {
        if (idx < nc) {
            const float* wr = &w2s[(clo + idx) * 64 + h * 16];
            float p = 0.f;
            #pragma unroll
            for (int j = 0; j < 16; ++j) p += xl[j] * wr[j];
            part[idx] = p;
        }
    }
    #pragma unroll
    for (int idx = 0; idx < 3; ++idx) {
        part[idx] += __shfl_xor(part[idx], 1);
        part[idx] += __shfl_xor(part[idx], 2);
    }
    float ssp = 0.f, sdp = 0.f;
    #pragma unroll
    for (int idx = 0; idx < 3; ++idx) {
        if (idx < nc) {
            ssp += part[idx] * as2[clo + idx];
            sdp += part[idx] * ad2[clo + idx];
        }
    }
    ssp += __shfl_xor(ssp, 4); ssp += __shfl_xor(ssp, 8);
    sdp += __shfl_xor(sdp, 4); sdp += __shfl_xor(sdp, 8);

    if (n < N && h == 0) {
        #pragma unroll
        for (int idx = 0; idx < 3; ++idx)
            if (idx < nc)
                h2p[(size_t)n * 16 + clo + idx] = (unsigned short)f2bf(part[idx]);
        if (sub == 3) {
            h2p[(size_t)n * 16 + 10] = (unsigned short)f2bf(ssp);
            h2p[(size_t)n * 16 + 11] = (unsigned short)f2bf(sdp);
        }
    }
}

// ---- Conv2 aggregation (bf16 rows, 8 threads/node) -> node_out[N][12] f32 ----
__global__ __launch_bounds__(256) void agg2_kernel(
    const int* __restrict__ offs, const int* __restrict__ csr_src,
    const unsigned short* __restrict__ h2p, const float* __restrict__ b2,
    float* __restrict__ node_out, int N)
{
    int tid = blockIdx.x * 256 + threadIdx.x;
    int n = tid >> 3, t = tid & 7;
    if (n >= N) return;
    float acc[10];
    #pragma unroll
    for (int c = 0; c < 10; ++c) acc[c] = 0.f;
    float den = 0.f;

    uint2 d1 = *(const uint2*)(h2p + (size_t)n * 16 + 8);  // {c8|c9, ss|sd}
    float sdst = bfhi(d1.y);
    if (t == 0) {
        uint4 d0 = *(const uint4*)(h2p + (size_t)n * 16);
        float s = bflo(d1.y) + sdst;
        s = (s >= 0.f) ? s : 0.2f * s;
        float w = __expf(s);
        den = w;
        acc[0] = w * bflo(d0.x); acc[1] = w * bfhi(d0.x);
        acc[2] = w * bflo(d0.y); acc[3] = w * bfhi(d0.y);
        acc[4] = w * bflo(d0.z); acc[5] = w * bfhi(d0.z);
        acc[6] = w * bflo(d0.w); acc[7] = w * bfhi(d0.w);
        acc[8] = w * bflo(d1.x); acc[9] = w * bfhi(d1.x);
    }
    int row = offs[n], end = offs[n + 1];
    for (int i = row + t; i < end; i += 8) {
        int src = csr_src[i];
        uint4 s0 = *(const uint4*)(h2p + (size_t)src * 16);
        uint2 s1 = *(const uint2*)(h2p + (size_t)src * 16 + 8);
        float s = bflo(s1.y) + sdst;
        s = (s >= 0.f) ? s : 0.2f * s;
        float we = __expf(s);
        den += we;
        acc[0] += we * bflo(s0.x); acc[1] += we * bfhi(s0.x);
        acc[2] += we * bflo(s0.y); acc[3] += we * bfhi(s0.y);
        acc[4] += we * bflo(s0.z); acc[5] += we * bfhi(s0.z);
        acc[6] += we * bflo(s0.w); acc[7] += we * bfhi(s0.w);
        acc[8] += we * bflo(s1.x); acc[9] += we * bfhi(s1.x);
    }
    #pragma unroll
    for (int c = 0; c < 10; ++c) {
        acc[c] += __shfl_xor(acc[c], 1);
        acc[c] += __shfl_xor(acc[c], 2);
        acc[c] += __shfl_xor(acc[c], 4);
    }
    den += __shfl_xor(den, 1);
    den += __shfl_xor(den, 2);
    den += __shfl_xor(den, 4);

    if (t == 0) {
        float inv = 1.f / (den + 1e-16f);
        float* o = &node_out[(size_t)n * 12];
        *(float4*)o = make_float4(acc[0]*inv + b2[0], acc[1]*inv + b2[1],
                                  acc[2]*inv + b2[2], acc[3]*inv + b2[3]);
        *(float4*)(o + 4) = make_float4(acc[4]*inv + b2[4], acc[5]*inv + b2[5],
                                        acc[6]*inv + b2[6], acc[7]*inv + b2[7]);
        *(float2*)(o + 8) = make_float2(acc[8]*inv + b2[8], acc[9]*inv + b2[9]);
    }
}

// ---- Pool: one block per graph; batch sorted -> binary-search range; no atomics ----
__global__ __launch_bounds__(256) void pool_kernel(
    const float* __restrict__ node_out, const int* __restrict__ batch,
    float* __restrict__ pooled, float* __restrict__ cnt, int N)
{
    int g = blockIdx.x;
    int lo = 0, hi = N;
    while (lo < hi) { int m = (lo + hi) >> 1; if (batch[m] < g) lo = m + 1; else hi = m; }
    int s0 = lo;
    hi = N;
    while (lo < hi) { int m = (lo + hi) >> 1; if (batch[m] < g + 1) lo = m + 1; else hi = m; }
    int s1 = lo;

    float acc[10];
    #pragma unroll
    for (int c = 0; c < 10; ++c) acc[c] = 0.f;
    for (int i = s0 + threadIdx.x; i < s1; i += 256) {
        const float* o = &node_out[(size_t)i * 12];
        float4 a = *(const float4*)o;
        float4 b = *(const float4*)(o + 4);
        float2 d = *(const float2*)(o + 8);
        acc[0] += a.x; acc[1] += a.y; acc[2] += a.z; acc[3] += a.w;
        acc[4] += b.x; acc[5] += b.y; acc[6] += b.z; acc[7] += b.w;
        acc[8] += d.x; acc[9] += d.y;
    }
    #pragma unroll
    for (int c = 0; c < 10; ++c)
        for (int o = 32; o > 0; o >>= 1) acc[c] += __shfl_down(acc[c], o);
    __shared__ float part[4][10];
    int wave = threadIdx.x >> 6, lane = threadIdx.x & 63;
    if (lane == 0)
        #pragma unroll
        for (int c = 0; c < 10; ++c) part[wave][c] = acc[c];
    __syncthreads();
    if (threadIdx.x < 10) {
        float s = part[0][threadIdx.x] + part[1][threadIdx.x]
                + part[2][threadIdx.x] + part[3][threadIdx.x];
        pooled[g * 10 + threadIdx.x] = s;
        if (threadIdx.x == 0) cnt[g] = (float)(s1 - s0);
    }
}

// ---------------- Final: mean + log_softmax ----------------
__global__ void final_kernel(const float* __restrict__ pooled,
                             const float* __restrict__ cnt, float* __restrict__ out)
{
    int g = threadIdx.x;
    if (g >= 64) return;
    float c = cnt[g];
    if (c < 1.f) c = 1.f;
    float v[10], m = -1e30f;
    #pragma unroll
    for (int i = 0; i < 10; ++i) {
        v[i] = pooled[g * 10 + i] / c;
        m = fmaxf(m, v[i]);
    }
    float s = 0.f;
    #pragma unroll
    for (int i = 0; i < 10; ++i) s += __expf(v[i] - m);
    float lse = m + logf(s);
    #pragma unroll
    for (int i = 0; i < 10; ++i) out[g * 10 + i] = v[i] - lse;
}

extern "C" void kernel_launch(void* const* d_in, const int* in_sizes, int n_in,
                              void* d_out, int out_size, void* d_ws, size_t ws_size,
                              hipStream_t stream) {
    const float* x       = (const float*)d_in[0];
    const int*   ei      = (const int*)  d_in[1];
    const int*   batch   = (const int*)  d_in[2];
    const float* W1      = (const float*)d_in[3];
    const float* a_src1  = (const float*)d_in[4];
    const float* a_dst1  = (const float*)d_in[5];
    const float* b1      = (const float*)d_in[6];
    const float* W2      = (const float*)d_in[7];
    const float* a_src2  = (const float*)d_in[8];
    const float* a_dst2  = (const float*)d_in[9];
    const float* b2      = (const float*)d_in[10];
    float* out = (float*)d_out;

    int N = in_sizes[0] / 128;
    int E = in_sizes[1] / 2;
    int NBK = (N + BWIDTH - 1) >> BSHIFT;

    float* f = (float*)d_ws;
    size_t off = 0;
    unsigned char* h1f = (unsigned char*)(f + off);
    float* node_out = (float*)h1f;      // aliased: h1f dead after agg1, node_out agg2..pool
    off += (size_t)N * 16;              // N*64 fp8 bytes = N*16 floats (>= N*12 floats)
    float* s1s  = f + off; off += (size_t)N * 4;
    float* s1d  = f + off; off += (size_t)N * 4;
    // time-aliased: pairs (E ints, live A3..scat) then h2p (N*16 bf16, agg1..agg2)
    unsigned short* h2p = (unsigned short*)(f + off);
    int*  pairs = (int*)(f + off);
    size_t r1 = ((size_t)N * 8 > (size_t)E) ? (size_t)N * 8 : (size_t)E;
    off += r1;
    int* iw = (int*)(f + off);
    size_t ioff = 0;
    int* offs    = iw + ioff; ioff += (size_t)N + 1;
    int* csr_src = iw + ioff; ioff += (size_t)E;
    int* bb      = iw + ioff; ioff += (size_t)NBK + 1;
    int* bcur    = iw + ioff; ioff += (size_t)NBK;
    int*   bhist  = iw + ioff;
    float* pooled = (float*)(iw + ioff + NBK);
    float* cnt    = pooled + 640;

    hipMemsetAsync((void*)bhist, 0, (size_t)NBK * sizeof(int), stream);

    int g1_blocks = (N + G1_TN - 1) / G1_TN;
    gemm1_kernel<<<g1_blocks, 256, 0, stream>>>(x, W1, a_src1, a_dst1, h1f, s1s, s1d, N);

    bhist_kernel<<<256, 256, 0, stream>>>(ei, bhist, E, NBK);
    bscan_kernel<<<1, 1024, 0, stream>>>(bhist, bb, bcur, NBK);
    int ntiles = (E + A3_TILE - 1) / A3_TILE;
    partition_kernel<<<ntiles, 256, 0, stream>>>(ei, bcur, pairs, E, NBK);
    offs_kernel<<<NBK, 128, 0, stream>>>(pairs, bb, offs, N, NBK, E);
    scat_kernel<<<NBK, 128, 0, stream>>>(pairs, bb, offs, csr_src, N);

    agg1_kernel<<<(N * 16 + 255) / 256, 256, 0, stream>>>(
        offs, csr_src, h1f, s1s, s1d, b1, W2, a_src2, a_dst2, h2p, N);

    agg2_kernel<<<(N * 8 + 255) / 256, 256, 0, stream>>>(
        offs, csr_src, h2p, b2, node_out, N);

    pool_kernel<<<64, 256, 0, stream>>>(node_out, batch, pooled, cnt, N);

    final_kernel<<<1, 64, 0, stream>>>(pooled, cnt, out);
}

// Round 10
// 170.485 us; speedup vs baseline: 2.9996x; 1.2427x over previous
//
#include <hip/hip_runtime.h>
#include <hip/hip_bf16.h>
#include <math.h>

#define BSHIFT 7
#define BWIDTH (1 << BSHIFT)       // 128 dst per bucket
#define A3_TILE 2048

typedef float floatx2 __attribute__((ext_vector_type(2)));
typedef __attribute__((ext_vector_type(8))) short bf16x8;
typedef __attribute__((ext_vector_type(4))) float f32x4;

__device__ inline unsigned int f2bf(float f) {
    unsigned int u = __float_as_uint(f);
    return (u + 0x7FFFu + ((u >> 16) & 1u)) >> 16;   // RNE
}
__device__ inline float bflo(unsigned int u) { return __uint_as_float(u << 16); }
__device__ inline float bfhi(unsigned int u) { return __uint_as_float(u & 0xFFFF0000u); }

// decode 16 fp8 (one uint4) and fma into xl[0..15]
__device__ inline void fp8x16_fma(uint4 Wv, float we, float* xl) {
    floatx2 p;
    p = __builtin_amdgcn_cvt_pk_f32_fp8((int)Wv.x, false); xl[0] += we*p[0]; xl[1] += we*p[1];
    p = __builtin_amdgcn_cvt_pk_f32_fp8((int)Wv.x, true);  xl[2] += we*p[0]; xl[3] += we*p[1];
    p = __builtin_amdgcn_cvt_pk_f32_fp8((int)Wv.y, false); xl[4] += we*p[0]; xl[5] += we*p[1];
    p = __builtin_amdgcn_cvt_pk_f32_fp8((int)Wv.y, true);  xl[6] += we*p[0]; xl[7] += we*p[1];
    p = __builtin_amdgcn_cvt_pk_f32_fp8((int)Wv.z, false); xl[8] += we*p[0]; xl[9] += we*p[1];
    p = __builtin_amdgcn_cvt_pk_f32_fp8((int)Wv.z, true);  xl[10] += we*p[0]; xl[11] += we*p[1];
    p = __builtin_amdgcn_cvt_pk_f32_fp8((int)Wv.w, false); xl[12] += we*p[0]; xl[13] += we*p[1];
    p = __builtin_amdgcn_cvt_pk_f32_fp8((int)Wv.w, true);  xl[14] += we*p[0]; xl[15] += we*p[1];
}

// ---------------- GEMM1 (MFMA bf16): h1f(fp8) = x @ W1^T, plus s1s/s1d ----------------
// block = 128 nodes x 64 ch, K=128 staged once; 4 waves, each 32 nodes x 64 ch
#define G1_BM 128
__global__ __launch_bounds__(256) void gemm1_kernel(
    const float* __restrict__ x, const float* __restrict__ W1,
    const float* __restrict__ a_src, const float* __restrict__ a_dst,
    unsigned char* __restrict__ h1f, float* __restrict__ s1s,
    float* __restrict__ s1d, int N)
{
    __shared__ __align__(16) char smem[52224];
    unsigned short (*xb)[136] = (unsigned short(*)[136])smem;          // 128x136 bf16 = 34816B
    unsigned short (*wb)[136] = (unsigned short(*)[136])(smem + 34816);// 64x136 bf16 = 17408B
    float (*hls)[68] = (float(*)[68])smem;                             // epilogue overlay (34816B)

    int tid = threadIdx.x;
    int nb = blockIdx.x * G1_BM;

    // stage W1 [64][128] f32 -> bf16
    #pragma unroll
    for (int r = 0; r < 8; ++r) {
        int i = tid + r * 256;            // 2048 float4s
        int ch = i >> 5, kq = i & 31;
        float4 v = *(const float4*)&W1[ch * 128 + kq * 4];
        uint2 pk;
        pk.x = f2bf(v.x) | (f2bf(v.y) << 16);
        pk.y = f2bf(v.z) | (f2bf(v.w) << 16);
        *(uint2*)&wb[ch][kq * 4] = pk;
    }
    // stage x tile [128][128] f32 -> bf16
    #pragma unroll
    for (int r = 0; r < 16; ++r) {
        int i = tid + r * 256;            // 4096 float4s
        int nl = i >> 5, kq = i & 31;
        int n = nb + nl;
        float4 v = (n < N) ? *(const float4*)&x[(size_t)n * 128 + kq * 4]
                           : make_float4(0.f, 0.f, 0.f, 0.f);
        uint2 pk;
        pk.x = f2bf(v.x) | (f2bf(v.y) << 16);
        pk.y = f2bf(v.z) | (f2bf(v.w) << 16);
        *(uint2*)&xb[nl][kq * 4] = pk;
    }
    __syncthreads();

    int lane = tid & 63, wv = tid >> 6;
    int lr = lane & 15, lk = lane >> 4;
    f32x4 acc[2][4];
    #pragma unroll
    for (int mt = 0; mt < 2; ++mt)
        #pragma unroll
        for (int nt = 0; nt < 4; ++nt) acc[mt][nt] = (f32x4){0.f, 0.f, 0.f, 0.f};

    #pragma unroll
    for (int ks = 0; ks < 4; ++ks) {
        int k0 = ks * 32 + lk * 8;
        bf16x8 af0 = *(const bf16x8*)&xb[wv * 32 + lr][k0];
        bf16x8 af1 = *(const bf16x8*)&xb[wv * 32 + 16 + lr][k0];
        #pragma unroll
        for (int nt = 0; nt < 4; ++nt) {
            bf16x8 bf = *(const bf16x8*)&wb[nt * 16 + lr][k0];
            acc[0][nt] = __builtin_amdgcn_mfma_f32_16x16x32_bf16(af0, bf, acc[0][nt], 0, 0, 0);
            acc[1][nt] = __builtin_amdgcn_mfma_f32_16x16x32_bf16(af1, bf, acc[1][nt], 0, 0, 0);
        }
    }
    __syncthreads();
    // restage D to hls[node][ch]  (D: row=(lane>>4)*4+reg from A=x, col=lane&15 from B=W)
    #pragma unroll
    for (int mt = 0; mt < 2; ++mt)
        #pragma unroll
        for (int nt = 0; nt < 4; ++nt)
            #pragma unroll
            for (int reg = 0; reg < 4; ++reg)
                hls[wv * 32 + mt * 16 + lk * 4 + reg][nt * 16 + lr] = acc[mt][nt][reg];
    __syncthreads();

    // emit fp8 row + per-head scores: 2 threads per node (halves align to head pairs)
    int nl = tid >> 1, half = tid & 1;
    int n = nb + nl;
    if (n < N) {
        float v[32];
        #pragma unroll
        for (int q = 0; q < 8; ++q) {
            float4 t4 = *(const float4*)&hls[nl][half * 32 + q * 4];
            v[q*4+0] = t4.x; v[q*4+1] = t4.y; v[q*4+2] = t4.z; v[q*4+3] = t4.w;
        }
        int h0 = half * 2, h1 = half * 2 + 1;
        float ss0 = 0.f, sd0 = 0.f, ss1 = 0.f, sd1 = 0.f;
        #pragma unroll
        for (int j = 0; j < 16; ++j) {
            ss0 += v[j] * a_src[h0 * 16 + j];
            sd0 += v[j] * a_dst[h0 * 16 + j];
            ss1 += v[16 + j] * a_src[h1 * 16 + j];
            sd1 += v[16 + j] * a_dst[h1 * 16 + j];
        }
        s1s[n * 4 + h0] = ss0; s1d[n * 4 + h0] = sd0;
        s1s[n * 4 + h1] = ss1; s1d[n * 4 + h1] = sd1;

        unsigned int w0, w1v, w2v, w3v, w4v, w5v, w6v, w7v;
        w0  = (unsigned)__builtin_amdgcn_cvt_pk_fp8_f32(v[0],  v[1],  0, false);
        w0  = (unsigned)__builtin_amdgcn_cvt_pk_fp8_f32(v[2],  v[3],  (int)w0, true);
        w1v = (unsigned)__builtin_amdgcn_cvt_pk_fp8_f32(v[4],  v[5],  0, false);
        w1v = (unsigned)__builtin_amdgcn_cvt_pk_fp8_f32(v[6],  v[7],  (int)w1v, true);
        w2v = (unsigned)__builtin_amdgcn_cvt_pk_fp8_f32(v[8],  v[9],  0, false);
        w2v = (unsigned)__builtin_amdgcn_cvt_pk_fp8_f32(v[10], v[11], (int)w2v, true);
        w3v = (unsigned)__builtin_amdgcn_cvt_pk_fp8_f32(v[12], v[13], 0, false);
        w3v = (unsigned)__builtin_amdgcn_cvt_pk_fp8_f32(v[14], v[15], (int)w3v, true);
        w4v = (unsigned)__builtin_amdgcn_cvt_pk_fp8_f32(v[16], v[17], 0, false);
        w4v = (unsigned)__builtin_amdgcn_cvt_pk_fp8_f32(v[18], v[19], (int)w4v, true);
        w5v = (unsigned)__builtin_amdgcn_cvt_pk_fp8_f32(v[20], v[21], 0, false);
        w5v = (unsigned)__builtin_amdgcn_cvt_pk_fp8_f32(v[22], v[23], (int)w5v, true);
        w6v = (unsigned)__builtin_amdgcn_cvt_pk_fp8_f32(v[24], v[25], 0, false);
        w6v = (unsigned)__builtin_amdgcn_cvt_pk_fp8_f32(v[26], v[27], (int)w6v, true);
        w7v = (unsigned)__builtin_amdgcn_cvt_pk_fp8_f32(v[28], v[29], 0, false);
        w7v = (unsigned)__builtin_amdgcn_cvt_pk_fp8_f32(v[30], v[31], (int)w7v, true);
        *(uint4*)(h1f + (size_t)n * 64 + half * 32)      = make_uint4(w0, w1v, w2v, w3v);
        *(uint4*)(h1f + (size_t)n * 64 + half * 32 + 16) = make_uint4(w4v, w5v, w6v, w7v);
    }
}

// ---------------- A1: bucket histogram (LDS-staged) ----------------
__global__ __launch_bounds__(256) void bhist_kernel(
    const int* __restrict__ ei, int* __restrict__ bhist, int E, int NBK)
{
    __shared__ int h[1024];
    for (int i = threadIdx.x; i < 1024; i += 256) h[i] = 0;
    __syncthreads();
    int stride = gridDim.x * 256;
    for (int e = blockIdx.x * 256 + threadIdx.x; e < E; e += stride)
        atomicAdd(&h[ei[E + e] >> BSHIFT], 1);
    __syncthreads();
    for (int b = threadIdx.x; b < NBK; b += 256) {
        int c = h[b];
        if (c) atomicAdd(&bhist[b], c);
    }
}

// ---------------- A2: exclusive scan over buckets -> bb, bcur ----------------
__global__ __launch_bounds__(1024) void bscan_kernel(
    const int* __restrict__ bhist, int* __restrict__ bb, int* __restrict__ bcur, int NBK)
{
    __shared__ int sh[1024];
    int t = threadIdx.x;
    int v = (t < NBK) ? bhist[t] : 0;
    sh[t] = v;
    __syncthreads();
    for (int o = 1; o < 1024; o <<= 1) {
        int u = (t >= o) ? sh[t - o] : 0;
        __syncthreads();
        sh[t] += u;
        __syncthreads();
    }
    int incl = sh[t];
    int excl = incl - v;
    if (t < NBK) { bb[t] = excl; bcur[t] = excl; }
    if (t == NBK - 1) bb[NBK] = incl;
}

// ---------------- A3: partition edges into bucket regions (packed) ----------------
__global__ __launch_bounds__(256) void partition_kernel(
    const int* __restrict__ ei, int* __restrict__ bcur, int* __restrict__ pairs,
    int E, int NBK)
{
    __shared__ int hist[1024];
    __shared__ int scanb[1024];
    __shared__ int gbase[1024];
    __shared__ int partial[256];
    __shared__ int stage_pack[A3_TILE];
    __shared__ int stage_pos[A3_TILE];
    int t = threadIdx.x;
    int e0 = blockIdx.x * A3_TILE;
    for (int i = t; i < 1024; i += 256) hist[i] = 0;
    __syncthreads();
    int my_b[8], my_rank[8], my_pack[8];
    #pragma unroll
    for (int j = 0; j < 8; ++j) {
        int e = e0 + j * 256 + t;
        int b = -1, pack = 0, r = 0;
        if (e < E) {
            int s = ei[e], d = ei[E + e];
            b = d >> BSHIFT;
            pack = ((d & (BWIDTH - 1)) << 17) | s;
            r = atomicAdd(&hist[b], 1);
        }
        my_b[j] = b; my_pack[j] = pack; my_rank[j] = r;
    }
    __syncthreads();
    int b4 = t * 4;
    int h0 = hist[b4], h1v = hist[b4 + 1], h2v = hist[b4 + 2], h3v = hist[b4 + 3];
    int tot = h0 + h1v + h2v + h3v;
    partial[t] = tot;
    __syncthreads();
    for (int o = 1; o < 256; o <<= 1) {
        int u = (t >= o) ? partial[t - o] : 0;
        __syncthreads();
        partial[t] += u;
        __syncthreads();
    }
    int excl = partial[t] - tot;
    scanb[b4]     = excl;
    scanb[b4 + 1] = excl + h0;
    scanb[b4 + 2] = excl + h0 + h1v;
    scanb[b4 + 3] = excl + h0 + h1v + h2v;
    int nvalid = partial[255];
    for (int b = t; b < NBK; b += 256) {
        int c = hist[b];
        if (c > 0) gbase[b] = atomicAdd(&bcur[b], c);
    }
    __syncthreads();
    #pragma unroll
    for (int j = 0; j < 8; ++j) {
        int b = my_b[j];
        if (b >= 0) {
            int slot = scanb[b] + my_rank[j];
            stage_pack[slot] = my_pack[j];
            stage_pos[slot]  = gbase[b] + my_rank[j];
        }
    }
    __syncthreads();
    for (int i = t; i < nvalid; i += 256)
        pairs[stage_pos[i]] = stage_pack[i];
}

// ---------------- B1: per-dst offs directly from bucket ----------------
__global__ __launch_bounds__(128) void offs_kernel(
    const int* __restrict__ pairs, const int* __restrict__ bb,
    int* __restrict__ offs, int N, int NBK, int E)
{
    int b = blockIdx.x;
    __shared__ int hist[BWIDTH];
    int t = threadIdx.x;
    hist[t] = 0;
    __syncthreads();
    int s = bb[b], e = bb[b + 1];
    for (int i = s + t; i < e; i += 128)
        atomicAdd(&hist[(pairs[i] >> 17) & (BWIDTH - 1)], 1);
    __syncthreads();
    int v = hist[t];
    for (int o = 1; o < BWIDTH; o <<= 1) {
        int u = (t >= o) ? hist[t - o] : 0;
        __syncthreads();
        hist[t] += u;
        __syncthreads();
    }
    int excl = hist[t] - v;
    int dst = b * BWIDTH + t;
    if (dst < N) offs[dst] = s + excl;
    if (b == 0 && t == 0) offs[N] = E;
}

// ---------------- B2: scatter src into CSR, LDS cursors ----------------
__global__ __launch_bounds__(128) void scat_kernel(
    const int* __restrict__ pairs, const int* __restrict__ bb,
    const int* __restrict__ offs, int* __restrict__ csr_src, int N)
{
    int b = blockIdx.x;
    __shared__ int cur[BWIDTH];
    int t = threadIdx.x;
    int dst = b * BWIDTH + t;
    cur[t] = (dst < N) ? offs[dst] : 0;
    __syncthreads();
    int s = bb[b], e = bb[b + 1];
    for (int i = s + t; i < e; i += 128) {
        int p = pairs[i];
        int pos = atomicAdd(&cur[(p >> 17) & (BWIDTH - 1)], 1);
        csr_src[pos] = p & 0x1FFFF;
    }
}

// ---- Conv1 aggregation (fp8 gather) + ELU + FUSED gemm2 -> h2p[N,16] bf16 ----
// 16 threads per node: 4 heads x 4 edge-quarters; gemm2 c-split across subs
__global__ __launch_bounds__(256) void agg1_kernel(
    const int* __restrict__ offs, const int* __restrict__ csr_src,
    const unsigned char* __restrict__ h1f, const float* __restrict__ s1s,
    const float* __restrict__ s1d, const float* __restrict__ b1,
    const float* __restrict__ W2, const float* __restrict__ as2,
    const float* __restrict__ ad2, unsigned short* __restrict__ h2p, int N)
{
    __shared__ float w2s[640];
    for (int i = threadIdx.x; i < 640; i += 256) w2s[i] = W2[i];
    __syncthreads();

    int tid = blockIdx.x * 256 + threadIdx.x;
    int n = tid >> 4, h = tid & 3, sub = (tid >> 2) & 3;
    float xl[16];
    #pragma unroll
    for (int j = 0; j < 16; ++j) xl[j] = 0.f;
    float den = 0.f;

    if (n < N) {
        float sdst = s1d[n * 4 + h];
        if (sub == 0) {   // self-loop
            float s = s1s[n * 4 + h] + sdst;
            s = (s >= 0.f) ? s : 0.2f * s;
            float w = __expf(s);
            den = w;
            uint4 Wv = *(const uint4*)(h1f + ((size_t)n << 6) + (h << 4));
            fp8x16_fma(Wv, w, xl);
        }
        int row = offs[n], end = offs[n + 1];
        for (int i = row + sub; i < end; i += 4) {
            int src = csr_src[i];
            float ss = s1s[src * 4 + h] + sdst;
            ss = (ss >= 0.f) ? ss : 0.2f * ss;
            float we = __expf(ss);
            den += we;
            uint4 Wv = *(const uint4*)(h1f + ((size_t)src << 6) + (h << 4));
            fp8x16_fma(Wv, we, xl);
        }
    }
    // merge edge-quarters within each head
    #pragma unroll
    for (int j = 0; j < 16; ++j) {
        xl[j] += __shfl_xor(xl[j], 4);
        xl[j] += __shfl_xor(xl[j], 8);
    }
    den += __shfl_xor(den, 4);
    den += __shfl_xor(den, 8);

    float inv = 1.f / (den + 1e-16f);
    #pragma unroll
    for (int j = 0; j < 16; ++j) {
        float v = xl[j] * inv + b1[h * 16 + j];
        xl[j] = (v > 0.f) ? v : (__expf(v) - 1.f);
    }

    // fused layer-2 matmul, c-split across subs: sub0:c0-2 sub1:c3-5 sub2:c6-8 sub3:c9
    int clo = sub * 3;
    int nc = (sub == 3) ? 1 : 3;
    float part[3] = {0.f, 0.f, 0.f};
    #pragma unroll
    for (int idx = 0; idx < 3; ++idx) {
        if (idx < nc) {
            const float* wr = &w2s[(clo + idx) * 64 + h * 16];
            float p = 0.f;
            #pragma unroll
            for (int j = 0; j < 16; ++j) p += xl[j] * wr[j];
            part[idx] = p;
        }
    }
    #pragma unroll
    for (int idx = 0; idx < 3; ++idx) {
        part[idx] += __shfl_xor(part[idx], 1);
        part[idx] += __shfl_xor(part[idx], 2);
    }
    float ssp = 0.f, sdp = 0.f;
    #pragma unroll
    for (int idx = 0; idx < 3; ++idx) {
        if (idx < nc) {
            ssp += part[idx] * as2[clo + idx];
            sdp += part[idx] * ad2[clo + idx];
        }
    }
    ssp += __shfl_xor(ssp, 4); ssp += __shfl_xor(ssp, 8);
    sdp += __shfl_xor(sdp, 4); sdp += __shfl_xor(sdp, 8);

    if (n < N && h == 0) {
        #pragma unroll
        for (int idx = 0; idx < 3; ++idx)
            if (idx < nc)
                h2p[(size_t)n * 16 + clo + idx] = (unsigned short)f2bf(part[idx]);
        if (sub == 3) {
            h2p[(size_t)n * 16 + 10] = (unsigned short)f2bf(ssp);
            h2p[(size_t)n * 16 + 11] = (unsigned short)f2bf(sdp);
        }
    }
}

// ---- Conv2 aggregation (bf16 rows, 8 threads/node) -> node_out[N][12] f32 ----
__global__ __launch_bounds__(256) void agg2_kernel(
    const int* __restrict__ offs, const int* __restrict__ csr_src,
    const unsigned short* __restrict__ h2p, const float* __restrict__ b2,
    float* __restrict__ node_out, int N)
{
    int tid = blockIdx.x * 256 + threadIdx.x;
    int n = tid >> 3, t = tid & 7;
    if (n >= N) return;
    float acc[10];
    #pragma unroll
    for (int c = 0; c < 10; ++c) acc[c] = 0.f;
    float den = 0.f;

    uint2 d1 = *(const uint2*)(h2p + (size_t)n * 16 + 8);  // {c8|c9, ss|sd}
    float sdst = bfhi(d1.y);
    if (t == 0) {
        uint4 d0 = *(const uint4*)(h2p + (size_t)n * 16);
        float s = bflo(d1.y) + sdst;
        s = (s >= 0.f) ? s : 0.2f * s;
        float w = __expf(s);
        den = w;
        acc[0] = w * bflo(d0.x); acc[1] = w * bfhi(d0.x);
        acc[2] = w * bflo(d0.y); acc[3] = w * bfhi(d0.y);
        acc[4] = w * bflo(d0.z); acc[5] = w * bfhi(d0.z);
        acc[6] = w * bflo(d0.w); acc[7] = w * bfhi(d0.w);
        acc[8] = w * bflo(d1.x); acc[9] = w * bfhi(d1.x);
    }
    int row = offs[n], end = offs[n + 1];
    for (int i = row + t; i < end; i += 8) {
        int src = csr_src[i];
        uint4 s0 = *(const uint4*)(h2p + (size_t)src * 16);
        uint2 s1 = *(const uint2*)(h2p + (size_t)src * 16 + 8);
        float s = bflo(s1.y) + sdst;
        s = (s >= 0.f) ? s : 0.2f * s;
        float we = __expf(s);
        den += we;
        acc[0] += we * bflo(s0.x); acc[1] += we * bfhi(s0.x);
        acc[2] += we * bflo(s0.y); acc[3] += we * bfhi(s0.y);
        acc[4] += we * bflo(s0.z); acc[5] += we * bfhi(s0.z);
        acc[6] += we * bflo(s0.w); acc[7] += we * bfhi(s0.w);
        acc[8] += we * bflo(s1.x); acc[9] += we * bfhi(s1.x);
    }
    #pragma unroll
    for (int c = 0; c < 10; ++c) {
        acc[c] += __shfl_xor(acc[c], 1);
        acc[c] += __shfl_xor(acc[c], 2);
        acc[c] += __shfl_xor(acc[c], 4);
    }
    den += __shfl_xor(den, 1);
    den += __shfl_xor(den, 2);
    den += __shfl_xor(den, 4);

    if (t == 0) {
        float inv = 1.f / (den + 1e-16f);
        float* o = &node_out[(size_t)n * 12];
        *(float4*)o = make_float4(acc[0]*inv + b2[0], acc[1]*inv + b2[1],
                                  acc[2]*inv + b2[2], acc[3]*inv + b2[3]);
        *(float4*)(o + 4) = make_float4(acc[4]*inv + b2[4], acc[5]*inv + b2[5],
                                        acc[6]*inv + b2[6], acc[7]*inv + b2[7]);
        *(float2*)(o + 8) = make_float2(acc[8]*inv + b2[8], acc[9]*inv + b2[9]);
    }
}

// ---- Pool: one block per graph; batch sorted -> binary-search range; no atomics ----
__global__ __launch_bounds__(256) void pool_kernel(
    const float* __restrict__ node_out, const int* __restrict__ batch,
    float* __restrict__ pooled, float* __restrict__ cnt, int N)
{
    int g = blockIdx.x;
    int lo = 0, hi = N;
    while (lo < hi) { int m = (lo + hi) >> 1; if (batch[m] < g) lo = m + 1; else hi = m; }
    int s0 = lo;
    hi = N;
    while (lo < hi) { int m = (lo + hi) >> 1; if (batch[m] < g + 1) lo = m + 1; else hi = m; }
    int s1 = lo;

    float acc[10];
    #pragma unroll
    for (int c = 0; c < 10; ++c) acc[c] = 0.f;
    for (int i = s0 + threadIdx.x; i < s1; i += 256) {
        const float* o = &node_out[(size_t)i * 12];
        float4 a = *(const float4*)o;
        float4 b = *(const float4*)(o + 4);
        float2 d = *(const float2*)(o + 8);
        acc[0] += a.x; acc[1] += a.y; acc[2] += a.z; acc[3] += a.w;
        acc[4] += b.x; acc[5] += b.y; acc[6] += b.z; acc[7] += b.w;
        acc[8] += d.x; acc[9] += d.y;
    }
    #pragma unroll
    for (int c = 0; c < 10; ++c)
        for (int o = 32; o > 0; o >>= 1) acc[c] += __shfl_down(acc[c], o);
    __shared__ float part[4][10];
    int wave = threadIdx.x >> 6, lane = threadIdx.x & 63;
    if (lane == 0)
        #pragma unroll
        for (int c = 0; c < 10; ++c) part[wave][c] = acc[c];
    __syncthreads();
    if (threadIdx.x < 10) {
        float s = part[0][threadIdx.x] + part[1][threadIdx.x]
                + part[2][threadIdx.x] + part[3][threadIdx.x];
        pooled[g * 10 + threadIdx.x] = s;
        if (threadIdx.x == 0) cnt[g] = (float)(s1 - s0);
    }
}

// ---------------- Final: mean + log_softmax ----------------
__global__ void final_kernel(const float* __restrict__ pooled,
                             const float* __restrict__ cnt, float* __restrict__ out)
{
    int g = threadIdx.x;
    if (g >= 64) return;
    float c = cnt[g];
    if (c < 1.f) c = 1.f;
    float v[10], m = -1e30f;
    #pragma unroll
    for (int i = 0; i < 10; ++i) {
        v[i] = pooled[g * 10 + i] / c;
        m = fmaxf(m, v[i]);
    }
    float s = 0.f;
    #pragma unroll
    for (int i = 0; i < 10; ++i) s += __expf(v[i] - m);
    float lse = m + logf(s);
    #pragma unroll
    for (int i = 0; i < 10; ++i) out[g * 10 + i] = v[i] - lse;
}

extern "C" void kernel_launch(void* const* d_in, const int* in_sizes, int n_in,
                              void* d_out, int out_size, void* d_ws, size_t ws_size,
                              hipStream_t stream) {
    const float* x       = (const float*)d_in[0];
    const int*   ei      = (const int*)  d_in[1];
    const int*   batch   = (const int*)  d_in[2];
    const float* W1      = (const float*)d_in[3];
    const float* a_src1  = (const float*)d_in[4];
    const float* a_dst1  = (const float*)d_in[5];
    const float* b1      = (const float*)d_in[6];
    const float* W2      = (const float*)d_in[7];
    const float* a_src2  = (const float*)d_in[8];
    const float* a_dst2  = (const float*)d_in[9];
    const float* b2      = (const float*)d_in[10];
    float* out = (float*)d_out;

    int N = in_sizes[0] / 128;
    int E = in_sizes[1] / 2;
    int NBK = (N + BWIDTH - 1) >> BSHIFT;

    float* f = (float*)d_ws;
    size_t off = 0;
    unsigned char* h1f = (unsigned char*)(f + off);
    float* node_out = (float*)h1f;      // aliased: h1f dead after agg1, node_out agg2..pool
    off += (size_t)N * 16;              // N*64 fp8 bytes = N*16 floats (>= N*12 floats)
    float* s1s  = f + off; off += (size_t)N * 4;
    float* s1d  = f + off; off += (size_t)N * 4;
    // time-aliased: pairs (E ints, live A3..scat) then h2p (N*16 bf16, agg1..agg2)
    unsigned short* h2p = (unsigned short*)(f + off);
    int*  pairs = (int*)(f + off);
    size_t r1 = ((size_t)N * 8 > (size_t)E) ? (size_t)N * 8 : (size_t)E;
    off += r1;
    int* iw = (int*)(f + off);
    size_t ioff = 0;
    int* offs    = iw + ioff; ioff += (size_t)N + 1;
    int* csr_src = iw + ioff; ioff += (size_t)E;
    int* bb      = iw + ioff; ioff += (size_t)NBK + 1;
    int* bcur    = iw + ioff; ioff += (size_t)NBK;
    int*   bhist  = iw + ioff;
    float* pooled = (float*)(iw + ioff + NBK);
    float* cnt    = pooled + 640;

    hipMemsetAsync((void*)bhist, 0, (size_t)NBK * sizeof(int), stream);

    int g1_blocks = (N + G1_BM - 1) / G1_BM;
    gemm1_kernel<<<g1_blocks, 256, 0, stream>>>(x, W1, a_src1, a_dst1, h1f, s1s, s1d, N);

    bhist_kernel<<<256, 256, 0, stream>>>(ei, bhist, E, NBK);
    bscan_kernel<<<1, 1024, 0, stream>>>(bhist, bb, bcur, NBK);
    int ntiles = (E + A3_TILE - 1) / A3_TILE;
    partition_kernel<<<ntiles, 256, 0, stream>>>(ei, bcur, pairs, E, NBK);
    offs_kernel<<<NBK, 128, 0, stream>>>(pairs, bb, offs, N, NBK, E);
    scat_kernel<<<NBK, 128, 0, stream>>>(pairs, bb, offs, csr_src, N);

    agg1_kernel<<<(N * 16 + 255) / 256, 256, 0, stream>>>(
        offs, csr_src, h1f, s1s, s1d, b1, W2, a_src2, a_dst2, h2p, N);

    agg2_kernel<<<(N * 8 + 255) / 256, 256, 0, stream>>>(
        offs, csr_src, h2p, b2, node_out, N);

    pool_kernel<<<64, 256, 0, stream>>>(node_out, batch, pooled, cnt, N);

    final_kernel<<<1, 64, 0, stream>>>(pooled, cnt, out);
}

// Round 11
// 156.517 us; speedup vs baseline: 3.2672x; 1.0892x over previous
//
#include <hip/hip_runtime.h>
#include <hip/hip_bf16.h>
#include <math.h>

#define BSHIFT 7
#define BWIDTH (1 << BSHIFT)       // 128 dst per bucket
#define A3_TILE 4096

typedef float floatx2 __attribute__((ext_vector_type(2)));
typedef __attribute__((ext_vector_type(8))) short bf16x8;
typedef __attribute__((ext_vector_type(4))) float f32x4;

__device__ inline unsigned int f2bf(float f) {
    unsigned int u = __float_as_uint(f);
    return (u + 0x7FFFu + ((u >> 16) & 1u)) >> 16;   // RNE
}
__device__ inline float bflo(unsigned int u) { return __uint_as_float(u << 16); }
__device__ inline float bfhi(unsigned int u) { return __uint_as_float(u & 0xFFFF0000u); }

// decode 16 fp8 (one uint4), packed-FMA into 8 floatx2 accumulators
__device__ inline void fp8x16_fma2(uint4 Wv, float we, floatx2* q) {
    floatx2 w2; w2[0] = we; w2[1] = we;
    q[0] += w2 * __builtin_amdgcn_cvt_pk_f32_fp8((int)Wv.x, false);
    q[1] += w2 * __builtin_amdgcn_cvt_pk_f32_fp8((int)Wv.x, true);
    q[2] += w2 * __builtin_amdgcn_cvt_pk_f32_fp8((int)Wv.y, false);
    q[3] += w2 * __builtin_amdgcn_cvt_pk_f32_fp8((int)Wv.y, true);
    q[4] += w2 * __builtin_amdgcn_cvt_pk_f32_fp8((int)Wv.z, false);
    q[5] += w2 * __builtin_amdgcn_cvt_pk_f32_fp8((int)Wv.z, true);
    q[6] += w2 * __builtin_amdgcn_cvt_pk_f32_fp8((int)Wv.w, false);
    q[7] += w2 * __builtin_amdgcn_cvt_pk_f32_fp8((int)Wv.w, true);
}

// ---------------- GEMM1 (MFMA bf16): h1f(fp8) = x @ W1^T, plus s1s/s1d ----------------
#define G1_BM 128
__global__ __launch_bounds__(256) void gemm1_kernel(
    const float* __restrict__ x, const float* __restrict__ W1,
    const float* __restrict__ a_src, const float* __restrict__ a_dst,
    unsigned char* __restrict__ h1f, float* __restrict__ s1s,
    float* __restrict__ s1d, int N)
{
    __shared__ __align__(16) char smem[52224];
    unsigned short (*xb)[136] = (unsigned short(*)[136])smem;          // 128x136 bf16
    unsigned short (*wb)[136] = (unsigned short(*)[136])(smem + 34816);// 64x136 bf16
    float (*hls)[68] = (float(*)[68])smem;                             // epilogue overlay

    int tid = threadIdx.x;
    int nb = blockIdx.x * G1_BM;

    #pragma unroll
    for (int r = 0; r < 8; ++r) {
        int i = tid + r * 256;
        int ch = i >> 5, kq = i & 31;
        float4 v = *(const float4*)&W1[ch * 128 + kq * 4];
        uint2 pk;
        pk.x = f2bf(v.x) | (f2bf(v.y) << 16);
        pk.y = f2bf(v.z) | (f2bf(v.w) << 16);
        *(uint2*)&wb[ch][kq * 4] = pk;
    }
    #pragma unroll
    for (int r = 0; r < 16; ++r) {
        int i = tid + r * 256;
        int nl = i >> 5, kq = i & 31;
        int n = nb + nl;
        float4 v = (n < N) ? *(const float4*)&x[(size_t)n * 128 + kq * 4]
                           : make_float4(0.f, 0.f, 0.f, 0.f);
        uint2 pk;
        pk.x = f2bf(v.x) | (f2bf(v.y) << 16);
        pk.y = f2bf(v.z) | (f2bf(v.w) << 16);
        *(uint2*)&xb[nl][kq * 4] = pk;
    }
    __syncthreads();

    int lane = tid & 63, wv = tid >> 6;
    int lr = lane & 15, lk = lane >> 4;
    f32x4 acc[2][4];
    #pragma unroll
    for (int mt = 0; mt < 2; ++mt)
        #pragma unroll
        for (int nt = 0; nt < 4; ++nt) acc[mt][nt] = (f32x4){0.f, 0.f, 0.f, 0.f};

    #pragma unroll
    for (int ks = 0; ks < 4; ++ks) {
        int k0 = ks * 32 + lk * 8;
        bf16x8 af0 = *(const bf16x8*)&xb[wv * 32 + lr][k0];
        bf16x8 af1 = *(const bf16x8*)&xb[wv * 32 + 16 + lr][k0];
        #pragma unroll
        for (int nt = 0; nt < 4; ++nt) {
            bf16x8 bf = *(const bf16x8*)&wb[nt * 16 + lr][k0];
            acc[0][nt] = __builtin_amdgcn_mfma_f32_16x16x32_bf16(af0, bf, acc[0][nt], 0, 0, 0);
            acc[1][nt] = __builtin_amdgcn_mfma_f32_16x16x32_bf16(af1, bf, acc[1][nt], 0, 0, 0);
        }
    }
    __syncthreads();
    #pragma unroll
    for (int mt = 0; mt < 2; ++mt)
        #pragma unroll
        for (int nt = 0; nt < 4; ++nt)
            #pragma unroll
            for (int reg = 0; reg < 4; ++reg)
                hls[wv * 32 + mt * 16 + lk * 4 + reg][nt * 16 + lr] = acc[mt][nt][reg];
    __syncthreads();

    int nl = tid >> 1, half = tid & 1;
    int n = nb + nl;
    if (n < N) {
        float v[32];
        #pragma unroll
        for (int q = 0; q < 8; ++q) {
            float4 t4 = *(const float4*)&hls[nl][half * 32 + q * 4];
            v[q*4+0] = t4.x; v[q*4+1] = t4.y; v[q*4+2] = t4.z; v[q*4+3] = t4.w;
        }
        int h0 = half * 2, h1 = half * 2 + 1;
        float ss0 = 0.f, sd0 = 0.f, ss1 = 0.f, sd1 = 0.f;
        #pragma unroll
        for (int j = 0; j < 16; ++j) {
            ss0 += v[j] * a_src[h0 * 16 + j];
            sd0 += v[j] * a_dst[h0 * 16 + j];
            ss1 += v[16 + j] * a_src[h1 * 16 + j];
            sd1 += v[16 + j] * a_dst[h1 * 16 + j];
        }
        s1s[n * 4 + h0] = ss0; s1d[n * 4 + h0] = sd0;
        s1s[n * 4 + h1] = ss1; s1d[n * 4 + h1] = sd1;

        unsigned int w0, w1v, w2v, w3v, w4v, w5v, w6v, w7v;
        w0  = (unsigned)__builtin_amdgcn_cvt_pk_fp8_f32(v[0],  v[1],  0, false);
        w0  = (unsigned)__builtin_amdgcn_cvt_pk_fp8_f32(v[2],  v[3],  (int)w0, true);
        w1v = (unsigned)__builtin_amdgcn_cvt_pk_fp8_f32(v[4],  v[5],  0, false);
        w1v = (unsigned)__builtin_amdgcn_cvt_pk_fp8_f32(v[6],  v[7],  (int)w1v, true);
        w2v = (unsigned)__builtin_amdgcn_cvt_pk_fp8_f32(v[8],  v[9],  0, false);
        w2v = (unsigned)__builtin_amdgcn_cvt_pk_fp8_f32(v[10], v[11], (int)w2v, true);
        w3v = (unsigned)__builtin_amdgcn_cvt_pk_fp8_f32(v[12], v[13], 0, false);
        w3v = (unsigned)__builtin_amdgcn_cvt_pk_fp8_f32(v[14], v[15], (int)w3v, true);
        w4v = (unsigned)__builtin_amdgcn_cvt_pk_fp8_f32(v[16], v[17], 0, false);
        w4v = (unsigned)__builtin_amdgcn_cvt_pk_fp8_f32(v[18], v[19], (int)w4v, true);
        w5v = (unsigned)__builtin_amdgcn_cvt_pk_fp8_f32(v[20], v[21], 0, false);
        w5v = (unsigned)__builtin_amdgcn_cvt_pk_fp8_f32(v[22], v[23], (int)w5v, true);
        w6v = (unsigned)__builtin_amdgcn_cvt_pk_fp8_f32(v[24], v[25], 0, false);
        w6v = (unsigned)__builtin_amdgcn_cvt_pk_fp8_f32(v[26], v[27], (int)w6v, true);
        w7v = (unsigned)__builtin_amdgcn_cvt_pk_fp8_f32(v[28], v[29], 0, false);
        w7v = (unsigned)__builtin_amdgcn_cvt_pk_fp8_f32(v[30], v[31], (int)w7v, true);
        *(uint4*)(h1f + (size_t)n * 64 + half * 32)      = make_uint4(w0, w1v, w2v, w3v);
        *(uint4*)(h1f + (size_t)n * 64 + half * 32 + 16) = make_uint4(w4v, w5v, w6v, w7v);
    }
}

// ---------------- A1: bucket histogram (LDS-staged) ----------------
__global__ __launch_bounds__(256) void bhist_kernel(
    const int* __restrict__ ei, int* __restrict__ bhist, int E, int NBK)
{
    __shared__ int h[1024];
    for (int i = threadIdx.x; i < 1024; i += 256) h[i] = 0;
    __syncthreads();
    int stride = gridDim.x * 256;
    for (int e = blockIdx.x * 256 + threadIdx.x; e < E; e += stride)
        atomicAdd(&h[ei[E + e] >> BSHIFT], 1);
    __syncthreads();
    for (int b = threadIdx.x; b < NBK; b += 256) {
        int c = h[b];
        if (c) atomicAdd(&bhist[b], c);
    }
}

// ---------------- A2: exclusive scan over buckets -> bb, bcur ----------------
__global__ __launch_bounds__(1024) void bscan_kernel(
    const int* __restrict__ bhist, int* __restrict__ bb, int* __restrict__ bcur, int NBK)
{
    __shared__ int sh[1024];
    int t = threadIdx.x;
    int v = (t < NBK) ? bhist[t] : 0;
    sh[t] = v;
    __syncthreads();
    for (int o = 1; o < 1024; o <<= 1) {
        int u = (t >= o) ? sh[t - o] : 0;
        __syncthreads();
        sh[t] += u;
        __syncthreads();
    }
    int incl = sh[t];
    int excl = incl - v;
    if (t < NBK) { bb[t] = excl; bcur[t] = excl; }
    if (t == NBK - 1) bb[NBK] = incl;
}

// ---------------- A3: partition edges into bucket regions (packed) ----------------
__global__ __launch_bounds__(256) void partition_kernel(
    const int* __restrict__ ei, int* __restrict__ bcur, int* __restrict__ pairs,
    int E, int NBK)
{
    __shared__ int hist[1024];
    __shared__ int scanb[1024];
    __shared__ int gbase[1024];
    __shared__ int partial[256];
    __shared__ int stage_pack[A3_TILE];
    __shared__ int stage_pos[A3_TILE];
    int t = threadIdx.x;
    int e0 = blockIdx.x * A3_TILE;
    for (int i = t; i < 1024; i += 256) hist[i] = 0;
    __syncthreads();
    int my_b[16], my_rank[16], my_pack[16];
    #pragma unroll
    for (int j = 0; j < 16; ++j) {
        int e = e0 + j * 256 + t;
        int b = -1, pack = 0, r = 0;
        if (e < E) {
            int s = ei[e], d = ei[E + e];
            b = d >> BSHIFT;
            pack = ((d & (BWIDTH - 1)) << 17) | s;
            r = atomicAdd(&hist[b], 1);
        }
        my_b[j] = b; my_pack[j] = pack; my_rank[j] = r;
    }
    __syncthreads();
    int b4 = t * 4;
    int h0 = hist[b4], h1v = hist[b4 + 1], h2v = hist[b4 + 2], h3v = hist[b4 + 3];
    int tot = h0 + h1v + h2v + h3v;
    partial[t] = tot;
    __syncthreads();
    for (int o = 1; o < 256; o <<= 1) {
        int u = (t >= o) ? partial[t - o] : 0;
        __syncthreads();
        partial[t] += u;
        __syncthreads();
    }
    int excl = partial[t] - tot;
    scanb[b4]     = excl;
    scanb[b4 + 1] = excl + h0;
    scanb[b4 + 2] = excl + h0 + h1v;
    scanb[b4 + 3] = excl + h0 + h1v + h2v;
    int nvalid = partial[255];
    for (int b = t; b < NBK; b += 256) {
        int c = hist[b];
        if (c > 0) gbase[b] = atomicAdd(&bcur[b], c);
    }
    __syncthreads();
    #pragma unroll
    for (int j = 0; j < 16; ++j) {
        int b = my_b[j];
        if (b >= 0) {
            int slot = scanb[b] + my_rank[j];
            stage_pack[slot] = my_pack[j];
            stage_pos[slot]  = gbase[b] + my_rank[j];
        }
    }
    __syncthreads();
    for (int i = t; i < nvalid; i += 256)
        pairs[stage_pos[i]] = stage_pack[i];
}

// ---------------- B1: per-dst offs directly from bucket ----------------
__global__ __launch_bounds__(128) void offs_kernel(
    const int* __restrict__ pairs, const int* __restrict__ bb,
    int* __restrict__ offs, int N, int NBK, int E)
{
    int b = blockIdx.x;
    __shared__ int hist[BWIDTH];
    int t = threadIdx.x;
    hist[t] = 0;
    __syncthreads();
    int s = bb[b], e = bb[b + 1];
    for (int i = s + t; i < e; i += 128)
        atomicAdd(&hist[(pairs[i] >> 17) & (BWIDTH - 1)], 1);
    __syncthreads();
    int v = hist[t];
    for (int o = 1; o < BWIDTH; o <<= 1) {
        int u = (t >= o) ? hist[t - o] : 0;
        __syncthreads();
        hist[t] += u;
        __syncthreads();
    }
    int excl = hist[t] - v;
    int dst = b * BWIDTH + t;
    if (dst < N) offs[dst] = s + excl;
    if (b == 0 && t == 0) offs[N] = E;
}

// ---------------- B2: scatter src into CSR, LDS cursors ----------------
__global__ __launch_bounds__(128) void scat_kernel(
    const int* __restrict__ pairs, const int* __restrict__ bb,
    const int* __restrict__ offs, int* __restrict__ csr_src, int N)
{
    int b = blockIdx.x;
    __shared__ int cur[BWIDTH];
    int t = threadIdx.x;
    int dst = b * BWIDTH + t;
    cur[t] = (dst < N) ? offs[dst] : 0;
    __syncthreads();
    int s = bb[b], e = bb[b + 1];
    for (int i = s + t; i < e; i += 128) {
        int p = pairs[i];
        int pos = atomicAdd(&cur[(p >> 17) & (BWIDTH - 1)], 1);
        csr_src[pos] = p & 0x1FFFF;
    }
}

// ---- Conv1 aggregation (fp8 gather, 2-edge unroll, pk-fma) + ELU + fused gemm2 ----
// 16 threads per node: 4 heads x 4 edge-quarters; gemm2 c-split across subs
__global__ __launch_bounds__(256) void agg1_kernel(
    const int* __restrict__ offs, const int* __restrict__ csr_src,
    const unsigned char* __restrict__ h1f, const float* __restrict__ s1s,
    const float* __restrict__ s1d, const float* __restrict__ b1,
    const float* __restrict__ W2, const float* __restrict__ as2,
    const float* __restrict__ ad2, unsigned short* __restrict__ h2p, int N)
{
    __shared__ float w2s[640];
    for (int i = threadIdx.x; i < 640; i += 256) w2s[i] = W2[i];
    __syncthreads();

    int tid = blockIdx.x * 256 + threadIdx.x;
    int n = tid >> 4, h = tid & 3, sub = (tid >> 2) & 3;
    floatx2 xq[8];
    #pragma unroll
    for (int j = 0; j < 8; ++j) { xq[j][0] = 0.f; xq[j][1] = 0.f; }
    float den = 0.f;

    if (n < N) {
        float sdst = s1d[n * 4 + h];
        if (sub == 0) {   // self-loop
            float s = s1s[n * 4 + h] + sdst;
            s = (s >= 0.f) ? s : 0.2f * s;
            float w = __expf(s);
            den = w;
            uint4 Wv = *(const uint4*)(h1f + ((size_t)n << 6) + (h << 4));
            fp8x16_fma2(Wv, w, xq);
        }
        int row = offs[n], end = offs[n + 1];
        int i = row + sub;
        for (; i + 4 < end; i += 8) {     // two edges per iteration (MLP)
            int src0 = csr_src[i];
            int src1 = csr_src[i + 4];
            uint4 W0 = *(const uint4*)(h1f + ((size_t)src0 << 6) + (h << 4));
            uint4 W1 = *(const uint4*)(h1f + ((size_t)src1 << 6) + (h << 4));
            float a0 = s1s[src0 * 4 + h];
            float a1 = s1s[src1 * 4 + h];
            float e0 = a0 + sdst; e0 = (e0 >= 0.f) ? e0 : 0.2f * e0;
            float e1 = a1 + sdst; e1 = (e1 >= 0.f) ? e1 : 0.2f * e1;
            float w0 = __expf(e0);
            float w1 = __expf(e1);
            den += w0 + w1;
            fp8x16_fma2(W0, w0, xq);
            fp8x16_fma2(W1, w1, xq);
        }
        if (i < end) {
            int src = csr_src[i];
            uint4 Wv = *(const uint4*)(h1f + ((size_t)src << 6) + (h << 4));
            float ss = s1s[src * 4 + h] + sdst;
            ss = (ss >= 0.f) ? ss : 0.2f * ss;
            float we = __expf(ss);
            den += we;
            fp8x16_fma2(Wv, we, xq);
        }
    }
    float* xl = (float*)xq;
    // merge edge-quarters within each head
    #pragma unroll
    for (int j = 0; j < 16; ++j) {
        xl[j] += __shfl_xor(xl[j], 4);
        xl[j] += __shfl_xor(xl[j], 8);
    }
    den += __shfl_xor(den, 4);
    den += __shfl_xor(den, 8);

    float inv = 1.f / (den + 1e-16f);
    #pragma unroll
    for (int j = 0; j < 16; ++j) {
        float v = xl[j] * inv + b1[h * 16 + j];
        xl[j] = (v > 0.f) ? v : (__expf(v) - 1.f);
    }

    // fused layer-2 matmul, c-split across subs: sub0:c0-2 sub1:c3-5 sub2:c6-8 sub3:c9
    int clo = sub * 3;
    int nc = (sub == 3) ? 1 : 3;
    float part[3] = {0.f, 0.f, 0.f};
    #pragma unroll
    for (int idx = 0; idx < 3; ++idx) {
        if (idx < nc) {
            const float* wr = &w2s[(clo + idx) * 64 + h * 16];
            float p = 0.f;
            #pragma unroll
            for (int j = 0; j < 16; ++j) p += xl[j] * wr[j];
            part[idx] = p;
        }
    }
    #pragma unroll
    for (int idx = 0; idx < 3; ++idx) {
        part[idx] += __shfl_xor(part[idx], 1);
        part[idx] += __shfl_xor(part[idx], 2);
    }
    float ssp = 0.f, sdp = 0.f;
    #pragma unroll
    for (int idx = 0; idx < 3; ++idx) {
        if (idx < nc) {
            ssp += part[idx] * as2[clo + idx];
            sdp += part[idx] * ad2[clo + idx];
        }
    }
    ssp += __shfl_xor(ssp, 4); ssp += __shfl_xor(ssp, 8);
    sdp += __shfl_xor(sdp, 4); sdp += __shfl_xor(sdp, 8);

    if (n < N && h == 0) {
        #pragma unroll
        for (int idx = 0; idx < 3; ++idx)
            if (idx < nc)
                h2p[(size_t)n * 16 + clo + idx] = (unsigned short)f2bf(part[idx]);
        if (sub == 3) {
            h2p[(size_t)n * 16 + 10] = (unsigned short)f2bf(ssp);
            h2p[(size_t)n * 16 + 11] = (unsigned short)f2bf(sdp);
        }
    }
}

// ---- Conv2 aggregation (bf16 rows, 8 threads/node, 2-edge unroll) -> node_out ----
__global__ __launch_bounds__(256) void agg2_kernel(
    const int* __restrict__ offs, const int* __restrict__ csr_src,
    const unsigned short* __restrict__ h2p, const float* __restrict__ b2,
    float* __restrict__ node_out, int N)
{
    int tid = blockIdx.x * 256 + threadIdx.x;
    int n = tid >> 3, t = tid & 7;
    if (n >= N) return;
    floatx2 aq[5];
    #pragma unroll
    for (int c = 0; c < 5; ++c) { aq[c][0] = 0.f; aq[c][1] = 0.f; }
    float den = 0.f;

    uint2 d1 = *(const uint2*)(h2p + (size_t)n * 16 + 8);  // {c8|c9, ss|sd}
    float sdst = bfhi(d1.y);
    if (t == 0) {
        uint4 d0 = *(const uint4*)(h2p + (size_t)n * 16);
        float s = bflo(d1.y) + sdst;
        s = (s >= 0.f) ? s : 0.2f * s;
        float w = __expf(s);
        den = w;
        floatx2 w2; w2[0] = w; w2[1] = w;
        floatx2 p;
        p[0] = bflo(d0.x); p[1] = bfhi(d0.x); aq[0] += w2 * p;
        p[0] = bflo(d0.y); p[1] = bfhi(d0.y); aq[1] += w2 * p;
        p[0] = bflo(d0.z); p[1] = bfhi(d0.z); aq[2] += w2 * p;
        p[0] = bflo(d0.w); p[1] = bfhi(d0.w); aq[3] += w2 * p;
        p[0] = bflo(d1.x); p[1] = bfhi(d1.x); aq[4] += w2 * p;
    }
    int row = offs[n], end = offs[n + 1];
    int i = row + t;
    for (; i + 8 < end; i += 16) {        // two edges per iteration (MLP)
        int src0 = csr_src[i];
        int src1 = csr_src[i + 8];
        uint4 A0 = *(const uint4*)(h2p + (size_t)src0 * 16);
        uint2 B0 = *(const uint2*)(h2p + (size_t)src0 * 16 + 8);
        uint4 A1 = *(const uint4*)(h2p + (size_t)src1 * 16);
        uint2 B1 = *(const uint2*)(h2p + (size_t)src1 * 16 + 8);
        float e0 = bflo(B0.y) + sdst; e0 = (e0 >= 0.f) ? e0 : 0.2f * e0;
        float e1 = bflo(B1.y) + sdst; e1 = (e1 >= 0.f) ? e1 : 0.2f * e1;
        float w0 = __expf(e0);
        float w1 = __expf(e1);
        den += w0 + w1;
        floatx2 w20; w20[0] = w0; w20[1] = w0;
        floatx2 w21; w21[0] = w1; w21[1] = w1;
        floatx2 p;
        p[0] = bflo(A0.x); p[1] = bfhi(A0.x); aq[0] += w20 * p;
        p[0] = bflo(A0.y); p[1] = bfhi(A0.y); aq[1] += w20 * p;
        p[0] = bflo(A0.z); p[1] = bfhi(A0.z); aq[2] += w20 * p;
        p[0] = bflo(A0.w); p[1] = bfhi(A0.w); aq[3] += w20 * p;
        p[0] = bflo(B0.x); p[1] = bfhi(B0.x); aq[4] += w20 * p;
        p[0] = bflo(A1.x); p[1] = bfhi(A1.x); aq[0] += w21 * p;
        p[0] = bflo(A1.y); p[1] = bfhi(A1.y); aq[1] += w21 * p;
        p[0] = bflo(A1.z); p[1] = bfhi(A1.z); aq[2] += w21 * p;
        p[0] = bflo(A1.w); p[1] = bfhi(A1.w); aq[3] += w21 * p;
        p[0] = bflo(B1.x); p[1] = bfhi(B1.x); aq[4] += w21 * p;
    }
    if (i < end) {
        int src = csr_src[i];
        uint4 A0 = *(const uint4*)(h2p + (size_t)src * 16);
        uint2 B0 = *(const uint2*)(h2p + (size_t)src * 16 + 8);
        float s = bflo(B0.y) + sdst;
        s = (s >= 0.f) ? s : 0.2f * s;
        float we = __expf(s);
        den += we;
        floatx2 w2; w2[0] = we; w2[1] = we;
        floatx2 p;
        p[0] = bflo(A0.x); p[1] = bfhi(A0.x); aq[0] += w2 * p;
        p[0] = bflo(A0.y); p[1] = bfhi(A0.y); aq[1] += w2 * p;
        p[0] = bflo(A0.z); p[1] = bfhi(A0.z); aq[2] += w2 * p;
        p[0] = bflo(A0.w); p[1] = bfhi(A0.w); aq[3] += w2 * p;
        p[0] = bflo(B0.x); p[1] = bfhi(B0.x); aq[4] += w2 * p;
    }
    float* acc = (float*)aq;
    #pragma unroll
    for (int c = 0; c < 10; ++c) {
        acc[c] += __shfl_xor(acc[c], 1);
        acc[c] += __shfl_xor(acc[c], 2);
        acc[c] += __shfl_xor(acc[c], 4);
    }
    den += __shfl_xor(den, 1);
    den += __shfl_xor(den, 2);
    den += __shfl_xor(den, 4);

    if (t == 0) {
        float inv = 1.f / (den + 1e-16f);
        float* o = &node_out[(size_t)n * 12];
        *(float4*)o = make_float4(acc[0]*inv + b2[0], acc[1]*inv + b2[1],
                                  acc[2]*inv + b2[2], acc[3]*inv + b2[3]);
        *(float4*)(o + 4) = make_float4(acc[4]*inv + b2[4], acc[5]*inv + b2[5],
                                        acc[6]*inv + b2[6], acc[7]*inv + b2[7]);
        *(float2*)(o + 8) = make_float2(acc[8]*inv + b2[8], acc[9]*inv + b2[9]);
    }
}

// ---- Pool: one block per graph; batch sorted -> binary-search range; no atomics ----
__global__ __launch_bounds__(256) void pool_kernel(
    const float* __restrict__ node_out, const int* __restrict__ batch,
    float* __restrict__ pooled, float* __restrict__ cnt, int N)
{
    int g = blockIdx.x;
    int lo = 0, hi = N;
    while (lo < hi) { int m = (lo + hi) >> 1; if (batch[m] < g) lo = m + 1; else hi = m; }
    int s0 = lo;
    hi = N;
    while (lo < hi) { int m = (lo + hi) >> 1; if (batch[m] < g + 1) lo = m + 1; else hi = m; }
    int s1 = lo;

    float acc[10];
    #pragma unroll
    for (int c = 0; c < 10; ++c) acc[c] = 0.f;
    for (int i = s0 + threadIdx.x; i < s1; i += 256) {
        const float* o = &node_out[(size_t)i * 12];
        float4 a = *(const float4*)o;
        float4 b = *(const float4*)(o + 4);
        float2 d = *(const float2*)(o + 8);
        acc[0] += a.x; acc[1] += a.y; acc[2] += a.z; acc[3] += a.w;
        acc[4] += b.x; acc[5] += b.y; acc[6] += b.z; acc[7] += b.w;
        acc[8] += d.x; acc[9] += d.y;
    }
    #pragma unroll
    for (int c = 0; c < 10; ++c)
        for (int o = 32; o > 0; o >>= 1) acc[c] += __shfl_down(acc[c], o);
    __shared__ float part[4][10];
    int wave = threadIdx.x >> 6, lane = threadIdx.x & 63;
    if (lane == 0)
        #pragma unroll
        for (int c = 0; c < 10; ++c) part[wave][c] = acc[c];
    __syncthreads();
    if (threadIdx.x < 10) {
        float s = part[0][threadIdx.x] + part[1][threadIdx.x]
                + part[2][threadIdx.x] + part[3][threadIdx.x];
        pooled[g * 10 + threadIdx.x] = s;
        if (threadIdx.x == 0) cnt[g] = (float)(s1 - s0);
    }
}

// ---------------- Final: mean + log_softmax ----------------
__global__ void final_kernel(const float* __restrict__ pooled,
                             const float* __restrict__ cnt, float* __restrict__ out)
{
    int g = threadIdx.x;
    if (g >= 64) return;
    float c = cnt[g];
    if (c < 1.f) c = 1.f;
    float v[10], m = -1e30f;
    #pragma unroll
    for (int i = 0; i < 10; ++i) {
        v[i] = pooled[g * 10 + i] / c;
        m = fmaxf(m, v[i]);
    }
    float s = 0.f;
    #pragma unroll
    for (int i = 0; i < 10; ++i) s += __expf(v[i] - m);
    float lse = m + logf(s);
    #pragma unroll
    for (int i = 0; i < 10; ++i) out[g * 10 + i] = v[i] - lse;
}

extern "C" void kernel_launch(void* const* d_in, const int* in_sizes, int n_in,
                              void* d_out, int out_size, void* d_ws, size_t ws_size,
                              hipStream_t stream) {
    const float* x       = (const float*)d_in[0];
    const int*   ei      = (const int*)  d_in[1];
    const int*   batch   = (const int*)  d_in[2];
    const float* W1      = (const float*)d_in[3];
    const float* a_src1  = (const float*)d_in[4];
    const float* a_dst1  = (const float*)d_in[5];
    const float* b1      = (const float*)d_in[6];
    const float* W2      = (const float*)d_in[7];
    const float* a_src2  = (const float*)d_in[8];
    const float* a_dst2  = (const float*)d_in[9];
    const float* b2      = (const float*)d_in[10];
    float* out = (float*)d_out;

    int N = in_sizes[0] / 128;
    int E = in_sizes[1] / 2;
    int NBK = (N + BWIDTH - 1) >> BSHIFT;

    float* f = (float*)d_ws;
    size_t off = 0;
    unsigned char* h1f = (unsigned char*)(f + off);
    float* node_out = (float*)h1f;      // aliased: h1f dead after agg1, node_out agg2..pool
    off += (size_t)N * 16;              // N*64 fp8 bytes = N*16 floats (>= N*12 floats)
    float* s1s  = f + off; off += (size_t)N * 4;
    float* s1d  = f + off; off += (size_t)N * 4;
    // time-aliased: pairs (E ints, live A3..scat) then h2p (N*16 bf16, agg1..agg2)
    unsigned short* h2p = (unsigned short*)(f + off);
    int*  pairs = (int*)(f + off);
    size_t r1 = ((size_t)N * 8 > (size_t)E) ? (size_t)N * 8 : (size_t)E;
    off += r1;
    int* iw = (int*)(f + off);
    size_t ioff = 0;
    int* offs    = iw + ioff; ioff += (size_t)N + 1;
    int* csr_src = iw + ioff; ioff += (size_t)E;
    int* bb      = iw + ioff; ioff += (size_t)NBK + 1;
    int* bcur    = iw + ioff; ioff += (size_t)NBK;
    int*   bhist  = iw + ioff;
    float* pooled = (float*)(iw + ioff + NBK);
    float* cnt    = pooled + 640;

    hipMemsetAsync((void*)bhist, 0, (size_t)NBK * sizeof(int), stream);

    int g1_blocks = (N + G1_BM - 1) / G1_BM;
    gemm1_kernel<<<g1_blocks, 256, 0, stream>>>(x, W1, a_src1, a_dst1, h1f, s1s, s1d, N);

    bhist_kernel<<<256, 256, 0, stream>>>(ei, bhist, E, NBK);
    bscan_kernel<<<1, 1024, 0, stream>>>(bhist, bb, bcur, NBK);
    int ntiles = (E + A3_TILE - 1) / A3_TILE;
    partition_kernel<<<ntiles, 256, 0, stream>>>(ei, bcur, pairs, E, NBK);
    offs_kernel<<<NBK, 128, 0, stream>>>(pairs, bb, offs, N, NBK, E);
    scat_kernel<<<NBK, 128, 0, stream>>>(pairs, bb, offs, csr_src, N);

    agg1_kernel<<<(N * 16 + 255) / 256, 256, 0, stream>>>(
        offs, csr_src, h1f, s1s, s1d, b1, W2, a_src2, a_dst2, h2p, N);

    agg2_kernel<<<(N * 8 + 255) / 256, 256, 0, stream>>>(
        offs, csr_src, h2p, b2, node_out, N);

    pool_kernel<<<64, 256, 0, stream>>>(node_out, batch, pooled, cnt, N);

    final_kernel<<<1, 64, 0, stream>>>(pooled, cnt, out);
}

// Round 12
// 145.194 us; speedup vs baseline: 3.5221x; 1.0780x over previous
//
#include <hip/hip_runtime.h>
#include <hip/hip_bf16.h>
#include <math.h>

#define BSHIFT 7
#define BWIDTH (1 << BSHIFT)       // 128 dst per bucket
#define BCAP 2560                  // bucket capacity (mean 2046, +11 sigma)
#define A3_TILE 4096

typedef float floatx2 __attribute__((ext_vector_type(2)));
typedef __attribute__((ext_vector_type(8))) short bf16x8;
typedef __attribute__((ext_vector_type(4))) float f32x4;

__device__ inline unsigned int f2bf(float f) {
    unsigned int u = __float_as_uint(f);
    return (u + 0x7FFFu + ((u >> 16) & 1u)) >> 16;   // RNE
}
__device__ inline float bflo(unsigned int u) { return __uint_as_float(u << 16); }
__device__ inline float bfhi(unsigned int u) { return __uint_as_float(u & 0xFFFF0000u); }

// decode 16 fp8 (one uint4), packed-FMA into 8 floatx2 accumulators
__device__ inline void fp8x16_fma2(uint4 Wv, float we, floatx2* q) {
    floatx2 w2; w2[0] = we; w2[1] = we;
    q[0] += w2 * __builtin_amdgcn_cvt_pk_f32_fp8((int)Wv.x, false);
    q[1] += w2 * __builtin_amdgcn_cvt_pk_f32_fp8((int)Wv.x, true);
    q[2] += w2 * __builtin_amdgcn_cvt_pk_f32_fp8((int)Wv.y, false);
    q[3] += w2 * __builtin_amdgcn_cvt_pk_f32_fp8((int)Wv.y, true);
    q[4] += w2 * __builtin_amdgcn_cvt_pk_f32_fp8((int)Wv.z, false);
    q[5] += w2 * __builtin_amdgcn_cvt_pk_f32_fp8((int)Wv.z, true);
    q[6] += w2 * __builtin_amdgcn_cvt_pk_f32_fp8((int)Wv.w, false);
    q[7] += w2 * __builtin_amdgcn_cvt_pk_f32_fp8((int)Wv.w, true);
}

// ---------------- GEMM1 (MFMA bf16): h1f(fp8) = x @ W1^T, plus s1s/s1d ----------------
#define G1_BM 128
__global__ __launch_bounds__(256) void gemm1_kernel(
    const float* __restrict__ x, const float* __restrict__ W1,
    const float* __restrict__ a_src, const float* __restrict__ a_dst,
    unsigned char* __restrict__ h1f, float* __restrict__ s1s,
    float* __restrict__ s1d, int N)
{
    __shared__ __align__(16) char smem[52224];
    unsigned short (*xb)[136] = (unsigned short(*)[136])smem;          // 128x136 bf16
    unsigned short (*wb)[136] = (unsigned short(*)[136])(smem + 34816);// 64x136 bf16
    float (*hls)[68] = (float(*)[68])smem;                             // epilogue overlay

    int tid = threadIdx.x;
    int nb = blockIdx.x * G1_BM;

    #pragma unroll
    for (int r = 0; r < 8; ++r) {
        int i = tid + r * 256;
        int ch = i >> 5, kq = i & 31;
        float4 v = *(const float4*)&W1[ch * 128 + kq * 4];
        uint2 pk;
        pk.x = f2bf(v.x) | (f2bf(v.y) << 16);
        pk.y = f2bf(v.z) | (f2bf(v.w) << 16);
        *(uint2*)&wb[ch][kq * 4] = pk;
    }
    #pragma unroll
    for (int r = 0; r < 16; ++r) {
        int i = tid + r * 256;
        int nl = i >> 5, kq = i & 31;
        int n = nb + nl;
        float4 v = (n < N) ? *(const float4*)&x[(size_t)n * 128 + kq * 4]
                           : make_float4(0.f, 0.f, 0.f, 0.f);
        uint2 pk;
        pk.x = f2bf(v.x) | (f2bf(v.y) << 16);
        pk.y = f2bf(v.z) | (f2bf(v.w) << 16);
        *(uint2*)&xb[nl][kq * 4] = pk;
    }
    __syncthreads();

    int lane = tid & 63, wv = tid >> 6;
    int lr = lane & 15, lk = lane >> 4;
    f32x4 acc[2][4];
    #pragma unroll
    for (int mt = 0; mt < 2; ++mt)
        #pragma unroll
        for (int nt = 0; nt < 4; ++nt) acc[mt][nt] = (f32x4){0.f, 0.f, 0.f, 0.f};

    #pragma unroll
    for (int ks = 0; ks < 4; ++ks) {
        int k0 = ks * 32 + lk * 8;
        bf16x8 af0 = *(const bf16x8*)&xb[wv * 32 + lr][k0];
        bf16x8 af1 = *(const bf16x8*)&xb[wv * 32 + 16 + lr][k0];
        #pragma unroll
        for (int nt = 0; nt < 4; ++nt) {
            bf16x8 bf = *(const bf16x8*)&wb[nt * 16 + lr][k0];
            acc[0][nt] = __builtin_amdgcn_mfma_f32_16x16x32_bf16(af0, bf, acc[0][nt], 0, 0, 0);
            acc[1][nt] = __builtin_amdgcn_mfma_f32_16x16x32_bf16(af1, bf, acc[1][nt], 0, 0, 0);
        }
    }
    __syncthreads();
    #pragma unroll
    for (int mt = 0; mt < 2; ++mt)
        #pragma unroll
        for (int nt = 0; nt < 4; ++nt)
            #pragma unroll
            for (int reg = 0; reg < 4; ++reg)
                hls[wv * 32 + mt * 16 + lk * 4 + reg][nt * 16 + lr] = acc[mt][nt][reg];
    __syncthreads();

    int nl = tid >> 1, half = tid & 1;
    int n = nb + nl;
    if (n < N) {
        float v[32];
        #pragma unroll
        for (int q = 0; q < 8; ++q) {
            float4 t4 = *(const float4*)&hls[nl][half * 32 + q * 4];
            v[q*4+0] = t4.x; v[q*4+1] = t4.y; v[q*4+2] = t4.z; v[q*4+3] = t4.w;
        }
        int h0 = half * 2, h1 = half * 2 + 1;
        float ss0 = 0.f, sd0 = 0.f, ss1 = 0.f, sd1 = 0.f;
        #pragma unroll
        for (int j = 0; j < 16; ++j) {
            ss0 += v[j] * a_src[h0 * 16 + j];
            sd0 += v[j] * a_dst[h0 * 16 + j];
            ss1 += v[16 + j] * a_src[h1 * 16 + j];
            sd1 += v[16 + j] * a_dst[h1 * 16 + j];
        }
        s1s[n * 4 + h0] = ss0; s1d[n * 4 + h0] = sd0;
        s1s[n * 4 + h1] = ss1; s1d[n * 4 + h1] = sd1;

        unsigned int w0, w1v, w2v, w3v, w4v, w5v, w6v, w7v;
        w0  = (unsigned)__builtin_amdgcn_cvt_pk_fp8_f32(v[0],  v[1],  0, false);
        w0  = (unsigned)__builtin_amdgcn_cvt_pk_fp8_f32(v[2],  v[3],  (int)w0, true);
        w1v = (unsigned)__builtin_amdgcn_cvt_pk_fp8_f32(v[4],  v[5],  0, false);
        w1v = (unsigned)__builtin_amdgcn_cvt_pk_fp8_f32(v[6],  v[7],  (int)w1v, true);
        w2v = (unsigned)__builtin_amdgcn_cvt_pk_fp8_f32(v[8],  v[9],  0, false);
        w2v = (unsigned)__builtin_amdgcn_cvt_pk_fp8_f32(v[10], v[11], (int)w2v, true);
        w3v = (unsigned)__builtin_amdgcn_cvt_pk_fp8_f32(v[12], v[13], 0, false);
        w3v = (unsigned)__builtin_amdgcn_cvt_pk_fp8_f32(v[14], v[15], (int)w3v, true);
        w4v = (unsigned)__builtin_amdgcn_cvt_pk_fp8_f32(v[16], v[17], 0, false);
        w4v = (unsigned)__builtin_amdgcn_cvt_pk_fp8_f32(v[18], v[19], (int)w4v, true);
        w5v = (unsigned)__builtin_amdgcn_cvt_pk_fp8_f32(v[20], v[21], 0, false);
        w5v = (unsigned)__builtin_amdgcn_cvt_pk_fp8_f32(v[22], v[23], (int)w5v, true);
        w6v = (unsigned)__builtin_amdgcn_cvt_pk_fp8_f32(v[24], v[25], 0, false);
        w6v = (unsigned)__builtin_amdgcn_cvt_pk_fp8_f32(v[26], v[27], (int)w6v, true);
        w7v = (unsigned)__builtin_amdgcn_cvt_pk_fp8_f32(v[28], v[29], 0, false);
        w7v = (unsigned)__builtin_amdgcn_cvt_pk_fp8_f32(v[30], v[31], (int)w7v, true);
        *(uint4*)(h1f + (size_t)n * 64 + half * 32)      = make_uint4(w0, w1v, w2v, w3v);
        *(uint4*)(h1f + (size_t)n * 64 + half * 32 + 16) = make_uint4(w4v, w5v, w6v, w7v);
    }
}

// ---------------- A3: partition edges into fixed-capacity buckets (packed) ----------------
__global__ __launch_bounds__(256) void partition_kernel(
    const int* __restrict__ ei, int* __restrict__ bcnt, int* __restrict__ pairs,
    int E, int NBK)
{
    __shared__ int hist[1024];
    __shared__ int scanb[1024];
    __shared__ int gbase[1024];
    __shared__ int partial[256];
    __shared__ int stage_pack[A3_TILE];
    __shared__ int stage_pos[A3_TILE];
    int t = threadIdx.x;
    int e0 = blockIdx.x * A3_TILE;
    for (int i = t; i < 1024; i += 256) hist[i] = 0;
    __syncthreads();
    int my_b[16], my_rank[16], my_pack[16];
    #pragma unroll
    for (int j = 0; j < 16; ++j) {
        int e = e0 + j * 256 + t;
        int b = -1, pack = 0, r = 0;
        if (e < E) {
            int s = ei[e], d = ei[E + e];
            b = d >> BSHIFT;
            pack = ((d & (BWIDTH - 1)) << 17) | s;
            r = atomicAdd(&hist[b], 1);
        }
        my_b[j] = b; my_pack[j] = pack; my_rank[j] = r;
    }
    __syncthreads();
    int b4 = t * 4;
    int h0 = hist[b4], h1v = hist[b4 + 1], h2v = hist[b4 + 2], h3v = hist[b4 + 3];
    int tot = h0 + h1v + h2v + h3v;
    partial[t] = tot;
    __syncthreads();
    for (int o = 1; o < 256; o <<= 1) {
        int u = (t >= o) ? partial[t - o] : 0;
        __syncthreads();
        partial[t] += u;
        __syncthreads();
    }
    int excl = partial[t] - tot;
    scanb[b4]     = excl;
    scanb[b4 + 1] = excl + h0;
    scanb[b4 + 2] = excl + h0 + h1v;
    scanb[b4 + 3] = excl + h0 + h1v + h2v;
    int nvalid = partial[255];
    for (int b = t; b < NBK; b += 256) {
        int c = hist[b];
        if (c > 0) gbase[b] = b * BCAP + atomicAdd(&bcnt[b], c);
    }
    __syncthreads();
    #pragma unroll
    for (int j = 0; j < 16; ++j) {
        int b = my_b[j];
        if (b >= 0) {
            int slot = scanb[b] + my_rank[j];
            stage_pack[slot] = my_pack[j];
            stage_pos[slot]  = gbase[b] + my_rank[j];
        }
    }
    __syncthreads();
    for (int i = t; i < nvalid; i += 256)
        pairs[stage_pos[i]] = stage_pack[i];
}

// ---- B: build padded CSR + meta from one bucket (LDS-staged, one pass) ----
// meta[n] = (local_start << 16) | deg ; csr row for n = (n>>7)*BCAP + local_start
__global__ __launch_bounds__(256) void buildcsr_kernel(
    const int* __restrict__ pairs, const int* __restrict__ bcnt,
    int* __restrict__ csr_src, int* __restrict__ meta, int N)
{
    int b = blockIdx.x;
    __shared__ int stage[BCAP];
    __shared__ int hist[BWIDTH];
    __shared__ int scn[BWIDTH];
    __shared__ int cur[BWIDTH];
    int t = threadIdx.x;
    if (t < BWIDTH) hist[t] = 0;
    __syncthreads();
    int cnt = bcnt[b];
    int base = b * BCAP;
    for (int i = t; i < cnt; i += 256) {
        int p = pairs[base + i];
        stage[i] = p;
        atomicAdd(&hist[(p >> 17) & (BWIDTH - 1)], 1);
    }
    __syncthreads();
    int v = (t < BWIDTH) ? hist[t] : 0;
    if (t < BWIDTH) scn[t] = v;
    __syncthreads();
    for (int o = 1; o < BWIDTH; o <<= 1) {
        int u = (t < BWIDTH && t >= o) ? scn[t - o] : 0;
        __syncthreads();
        if (t < BWIDTH) scn[t] += u;
        __syncthreads();
    }
    if (t < BWIDTH) {
        int excl = scn[t] - v;
        cur[t] = excl;
        int dst = b * BWIDTH + t;
        if (dst < N) meta[dst] = (excl << 16) | v;
    }
    __syncthreads();
    for (int i = t; i < cnt; i += 256) {
        int p = stage[i];
        int slot = atomicAdd(&cur[(p >> 17) & (BWIDTH - 1)], 1);
        csr_src[base + slot] = p & 0x1FFFF;
    }
}

// ---- Conv1 aggregation (fp8 gather, 4-edge unroll) + ELU + fused gemm2 ----
// 16 threads per node: 4 heads x 4 edge-quarters; gemm2 c-split across subs
__global__ __launch_bounds__(256) void agg1_kernel(
    const int* __restrict__ meta, const int* __restrict__ csr_src,
    const unsigned char* __restrict__ h1f, const float* __restrict__ s1s,
    const float* __restrict__ s1d, const float* __restrict__ b1,
    const float* __restrict__ W2, const float* __restrict__ as2,
    const float* __restrict__ ad2, unsigned short* __restrict__ h2p, int N)
{
    __shared__ float w2s[640];
    for (int i = threadIdx.x; i < 640; i += 256) w2s[i] = W2[i];
    __syncthreads();

    int tid = blockIdx.x * 256 + threadIdx.x;
    int n = tid >> 4, h = tid & 3, sub = (tid >> 2) & 3;
    floatx2 xq[8];
    #pragma unroll
    for (int j = 0; j < 8; ++j) { xq[j][0] = 0.f; xq[j][1] = 0.f; }
    float den = 0.f;

    if (n < N) {
        float sdst = s1d[n * 4 + h];
        if (sub == 0) {   // self-loop
            float s = s1s[n * 4 + h] + sdst;
            s = (s >= 0.f) ? s : 0.2f * s;
            float w = __expf(s);
            den = w;
            uint4 Wv = *(const uint4*)(h1f + ((size_t)n << 6) + (h << 4));
            fp8x16_fma2(Wv, w, xq);
        }
        int mn = meta[n];
        int row = (n >> BSHIFT) * BCAP + (mn >> 16);
        int end = row + (mn & 0xFFFF);
        int i = row + sub;
        for (; i + 12 < end; i += 16) {    // 4 edges per iteration, all valid
            int s0 = csr_src[i];
            int s1v = csr_src[i + 4];
            int s2v = csr_src[i + 8];
            int s3v = csr_src[i + 12];
            uint4 W0 = *(const uint4*)(h1f + ((size_t)s0 << 6) + (h << 4));
            uint4 W1 = *(const uint4*)(h1f + ((size_t)s1v << 6) + (h << 4));
            uint4 W2v = *(const uint4*)(h1f + ((size_t)s2v << 6) + (h << 4));
            uint4 W3 = *(const uint4*)(h1f + ((size_t)s3v << 6) + (h << 4));
            float a0 = s1s[s0 * 4 + h], a1 = s1s[s1v * 4 + h];
            float a2 = s1s[s2v * 4 + h], a3 = s1s[s3v * 4 + h];
            float e0 = a0 + sdst; e0 = (e0 >= 0.f) ? e0 : 0.2f * e0;
            float e1 = a1 + sdst; e1 = (e1 >= 0.f) ? e1 : 0.2f * e1;
            float e2 = a2 + sdst; e2 = (e2 >= 0.f) ? e2 : 0.2f * e2;
            float e3 = a3 + sdst; e3 = (e3 >= 0.f) ? e3 : 0.2f * e3;
            float w0 = __expf(e0), w1 = __expf(e1);
            float w2 = __expf(e2), w3 = __expf(e3);
            den += (w0 + w1) + (w2 + w3);
            fp8x16_fma2(W0, w0, xq);
            fp8x16_fma2(W1, w1, xq);
            fp8x16_fma2(W2v, w2, xq);
            fp8x16_fma2(W3, w3, xq);
        }
        if (i < end) {                     // remainder: up to 3 edges, predicated
            int i1 = i + 4, i2 = i + 8;
            bool v1 = i1 < end, v2 = i2 < end;
            int s0 = csr_src[i];
            int s1v = v1 ? csr_src[i1] : s0;
            int s2v = v2 ? csr_src[i2] : s0;
            uint4 W0 = *(const uint4*)(h1f + ((size_t)s0 << 6) + (h << 4));
            uint4 W1 = *(const uint4*)(h1f + ((size_t)s1v << 6) + (h << 4));
            uint4 W2v = *(const uint4*)(h1f + ((size_t)s2v << 6) + (h << 4));
            float a0 = s1s[s0 * 4 + h], a1 = s1s[s1v * 4 + h], a2 = s1s[s2v * 4 + h];
            float e0 = a0 + sdst; e0 = (e0 >= 0.f) ? e0 : 0.2f * e0;
            float e1 = a1 + sdst; e1 = (e1 >= 0.f) ? e1 : 0.2f * e1;
            float e2 = a2 + sdst; e2 = (e2 >= 0.f) ? e2 : 0.2f * e2;
            float w0 = __expf(e0);
            float w1 = v1 ? __expf(e1) : 0.f;
            float w2 = v2 ? __expf(e2) : 0.f;
            den += w0 + w1 + w2;
            fp8x16_fma2(W0, w0, xq);
            fp8x16_fma2(W1, w1, xq);
            fp8x16_fma2(W2v, w2, xq);
        }
    }
    float* xl = (float*)xq;
    // merge edge-quarters within each head
    #pragma unroll
    for (int j = 0; j < 16; ++j) {
        xl[j] += __shfl_xor(xl[j], 4);
        xl[j] += __shfl_xor(xl[j], 8);
    }
    den += __shfl_xor(den, 4);
    den += __shfl_xor(den, 8);

    float inv = 1.f / (den + 1e-16f);
    #pragma unroll
    for (int j = 0; j < 16; ++j) {
        float v = xl[j] * inv + b1[h * 16 + j];
        xl[j] = (v > 0.f) ? v : (__expf(v) - 1.f);
    }

    // fused layer-2 matmul, c-split across subs: sub0:c0-2 sub1:c3-5 sub2:c6-8 sub3:c9
    int clo = sub * 3;
    int nc = (sub == 3) ? 1 : 3;
    float part[3] = {0.f, 0.f, 0.f};
    #pragma unroll
    for (int idx = 0; idx < 3; ++idx) {
        if (idx < nc) {
            const float* wr = &w2s[(clo + idx) * 64 + h * 16];
            float p = 0.f;
            #pragma unroll
            for (int j = 0; j < 16; ++j) p += xl[j] * wr[j];
            part[idx] = p;
        }
    }
    #pragma unroll
    for (int idx = 0; idx < 3; ++idx) {
        part[idx] += __shfl_xor(part[idx], 1);
        part[idx] += __shfl_xor(part[idx], 2);
    }
    float ssp = 0.f, sdp = 0.f;
    #pragma unroll
    for (int idx = 0; idx < 3; ++idx) {
        if (idx < nc) {
            ssp += part[idx] * as2[clo + idx];
            sdp += part[idx] * ad2[clo + idx];
        }
    }
    ssp += __shfl_xor(ssp, 4); ssp += __shfl_xor(ssp, 8);
    sdp += __shfl_xor(sdp, 4); sdp += __shfl_xor(sdp, 8);

    if (n < N && h == 0) {
        #pragma unroll
        for (int idx = 0; idx < 3; ++idx)
            if (idx < nc)
                h2p[(size_t)n * 16 + clo + idx] = (unsigned short)f2bf(part[idx]);
        if (sub == 3) {
            h2p[(size_t)n * 16 + 10] = (unsigned short)f2bf(ssp);
            h2p[(size_t)n * 16 + 11] = (unsigned short)f2bf(sdp);
        }
    }
}

// ---- Conv2 aggregation (bf16 rows, 8 threads/node, 2-edge unroll) -> node_out ----
__global__ __launch_bounds__(256) void agg2_kernel(
    const int* __restrict__ meta, const int* __restrict__ csr_src,
    const unsigned short* __restrict__ h2p, const float* __restrict__ b2,
    float* __restrict__ node_out, int N)
{
    int tid = blockIdx.x * 256 + threadIdx.x;
    int n = tid >> 3, t = tid & 7;
    if (n >= N) return;
    floatx2 aq[5];
    #pragma unroll
    for (int c = 0; c < 5; ++c) { aq[c][0] = 0.f; aq[c][1] = 0.f; }
    float den = 0.f;

    uint2 d1 = *(const uint2*)(h2p + (size_t)n * 16 + 8);  // {c8|c9, ss|sd}
    float sdst = bfhi(d1.y);
    if (t == 0) {
        uint4 d0 = *(const uint4*)(h2p + (size_t)n * 16);
        float s = bflo(d1.y) + sdst;
        s = (s >= 0.f) ? s : 0.2f * s;
        float w = __expf(s);
        den = w;
        floatx2 w2; w2[0] = w; w2[1] = w;
        floatx2 p;
        p[0] = bflo(d0.x); p[1] = bfhi(d0.x); aq[0] += w2 * p;
        p[0] = bflo(d0.y); p[1] = bfhi(d0.y); aq[1] += w2 * p;
        p[0] = bflo(d0.z); p[1] = bfhi(d0.z); aq[2] += w2 * p;
        p[0] = bflo(d0.w); p[1] = bfhi(d0.w); aq[3] += w2 * p;
        p[0] = bflo(d1.x); p[1] = bfhi(d1.x); aq[4] += w2 * p;
    }
    int mn = meta[n];
    int row = (n >> BSHIFT) * BCAP + (mn >> 16);
    int end = row + (mn & 0xFFFF);
    int i = row + t;
    for (; i + 8 < end; i += 16) {        // two edges per iteration (MLP)
        int src0 = csr_src[i];
        int src1 = csr_src[i + 8];
        uint4 A0 = *(const uint4*)(h2p + (size_t)src0 * 16);
        uint2 B0 = *(const uint2*)(h2p + (size_t)src0 * 16 + 8);
        uint4 A1 = *(const uint4*)(h2p + (size_t)src1 * 16);
        uint2 B1 = *(const uint2*)(h2p + (size_t)src1 * 16 + 8);
        float e0 = bflo(B0.y) + sdst; e0 = (e0 >= 0.f) ? e0 : 0.2f * e0;
        float e1 = bflo(B1.y) + sdst; e1 = (e1 >= 0.f) ? e1 : 0.2f * e1;
        float w0 = __expf(e0);
        float w1 = __expf(e1);
        den += w0 + w1;
        floatx2 w20; w20[0] = w0; w20[1] = w0;
        floatx2 w21; w21[0] = w1; w21[1] = w1;
        floatx2 p;
        p[0] = bflo(A0.x); p[1] = bfhi(A0.x); aq[0] += w20 * p;
        p[0] = bflo(A0.y); p[1] = bfhi(A0.y); aq[1] += w20 * p;
        p[0] = bflo(A0.z); p[1] = bfhi(A0.z); aq[2] += w20 * p;
        p[0] = bflo(A0.w); p[1] = bfhi(A0.w); aq[3] += w20 * p;
        p[0] = bflo(B0.x); p[1] = bfhi(B0.x); aq[4] += w20 * p;
        p[0] = bflo(A1.x); p[1] = bfhi(A1.x); aq[0] += w21 * p;
        p[0] = bflo(A1.y); p[1] = bfhi(A1.y); aq[1] += w21 * p;
        p[0] = bflo(A1.z); p[1] = bfhi(A1.z); aq[2] += w21 * p;
        p[0] = bflo(A1.w); p[1] = bfhi(A1.w); aq[3] += w21 * p;
        p[0] = bflo(B1.x); p[1] = bfhi(B1.x); aq[4] += w21 * p;
    }
    if (i < end) {
        int src = csr_src[i];
        uint4 A0 = *(const uint4*)(h2p + (size_t)src * 16);
        uint2 B0 = *(const uint2*)(h2p + (size_t)src * 16 + 8);
        float s = bflo(B0.y) + sdst;
        s = (s >= 0.f) ? s : 0.2f * s;
        float we = __expf(s);
        den += we;
        floatx2 w2; w2[0] = we; w2[1] = we;
        floatx2 p;
        p[0] = bflo(A0.x); p[1] = bfhi(A0.x); aq[0] += w2 * p;
        p[0] = bflo(A0.y); p[1] = bfhi(A0.y); aq[1] += w2 * p;
        p[0] = bflo(A0.z); p[1] = bfhi(A0.z); aq[2] += w2 * p;
        p[0] = bflo(A0.w); p[1] = bfhi(A0.w); aq[3] += w2 * p;
        p[0] = bflo(B0.x); p[1] = bfhi(B0.x); aq[4] += w2 * p;
    }
    float* acc = (float*)aq;
    #pragma unroll
    for (int c = 0; c < 10; ++c) {
        acc[c] += __shfl_xor(acc[c], 1);
        acc[c] += __shfl_xor(acc[c], 2);
        acc[c] += __shfl_xor(acc[c], 4);
    }
    den += __shfl_xor(den, 1);
    den += __shfl_xor(den, 2);
    den += __shfl_xor(den, 4);

    if (t == 0) {
        float inv = 1.f / (den + 1e-16f);
        float* o = &node_out[(size_t)n * 12];
        *(float4*)o = make_float4(acc[0]*inv + b2[0], acc[1]*inv + b2[1],
                                  acc[2]*inv + b2[2], acc[3]*inv + b2[3]);
        *(float4*)(o + 4) = make_float4(acc[4]*inv + b2[4], acc[5]*inv + b2[5],
                                        acc[6]*inv + b2[6], acc[7]*inv + b2[7]);
        *(float2*)(o + 8) = make_float2(acc[8]*inv + b2[8], acc[9]*inv + b2[9]);
    }
}

// ---- Pool: one block per graph; batch sorted -> binary-search range; no atomics ----
__global__ __launch_bounds__(256) void pool_kernel(
    const float* __restrict__ node_out, const int* __restrict__ batch,
    float* __restrict__ pooled, float* __restrict__ cnt, int N)
{
    int g = blockIdx.x;
    int lo = 0, hi = N;
    while (lo < hi) { int m = (lo + hi) >> 1; if (batch[m] < g) lo = m + 1; else hi = m; }
    int s0 = lo;
    hi = N;
    while (lo < hi) { int m = (lo + hi) >> 1; if (batch[m] < g + 1) lo = m + 1; else hi = m; }
    int s1 = lo;

    float acc[10];
    #pragma unroll
    for (int c = 0; c < 10; ++c) acc[c] = 0.f;
    for (int i = s0 + threadIdx.x; i < s1; i += 256) {
        const float* o = &node_out[(size_t)i * 12];
        float4 a = *(const float4*)o;
        float4 b = *(const float4*)(o + 4);
        float2 d = *(const float2*)(o + 8);
        acc[0] += a.x; acc[1] += a.y; acc[2] += a.z; acc[3] += a.w;
        acc[4] += b.x; acc[5] += b.y; acc[6] += b.z; acc[7] += b.w;
        acc[8] += d.x; acc[9] += d.y;
    }
    #pragma unroll
    for (int c = 0; c < 10; ++c)
        for (int o = 32; o > 0; o >>= 1) acc[c] += __shfl_down(acc[c], o);
    __shared__ float part[4][10];
    int wave = threadIdx.x >> 6, lane = threadIdx.x & 63;
    if (lane == 0)
        #pragma unroll
        for (int c = 0; c < 10; ++c) part[wave][c] = acc[c];
    __syncthreads();
    if (threadIdx.x < 10) {
        float s = part[0][threadIdx.x] + part[1][threadIdx.x]
                + part[2][threadIdx.x] + part[3][threadIdx.x];
        pooled[g * 10 + threadIdx.x] = s;
        if (threadIdx.x == 0) cnt[g] = (float)(s1 - s0);
    }
}

// ---------------- Final: mean + log_softmax ----------------
__global__ void final_kernel(const float* __restrict__ pooled,
                             const float* __restrict__ cnt, float* __restrict__ out)
{
    int g = threadIdx.x;
    if (g >= 64) return;
    float c = cnt[g];
    if (c < 1.f) c = 1.f;
    float v[10], m = -1e30f;
    #pragma unroll
    for (int i = 0; i < 10; ++i) {
        v[i] = pooled[g * 10 + i] / c;
        m = fmaxf(m, v[i]);
    }
    float s = 0.f;
    #pragma unroll
    for (int i = 0; i < 10; ++i) s += __expf(v[i] - m);
    float lse = m + logf(s);
    #pragma unroll
    for (int i = 0; i < 10; ++i) out[g * 10 + i] = v[i] - lse;
}

extern "C" void kernel_launch(void* const* d_in, const int* in_sizes, int n_in,
                              void* d_out, int out_size, void* d_ws, size_t ws_size,
                              hipStream_t stream) {
    const float* x       = (const float*)d_in[0];
    const int*   ei      = (const int*)  d_in[1];
    const int*   batch   = (const int*)  d_in[2];
    const float* W1      = (const float*)d_in[3];
    const float* a_src1  = (const float*)d_in[4];
    const float* a_dst1  = (const float*)d_in[5];
    const float* b1      = (const float*)d_in[6];
    const float* W2      = (const float*)d_in[7];
    const float* a_src2  = (const float*)d_in[8];
    const float* a_dst2  = (const float*)d_in[9];
    const float* b2      = (const float*)d_in[10];
    float* out = (float*)d_out;

    int N = in_sizes[0] / 128;
    int E = in_sizes[1] / 2;
    int NBK = (N + BWIDTH - 1) >> BSHIFT;

    float* f = (float*)d_ws;
    size_t off = 0;
    unsigned char* h1f = (unsigned char*)(f + off);
    float* node_out = (float*)h1f;      // aliased: h1f dead after agg1, node_out agg2..pool
    off += (size_t)N * 16;              // N*64 fp8 bytes = N*16 floats (>= N*12 floats)
    float* s1s  = f + off; off += (size_t)N * 4;
    float* s1d  = f + off; off += (size_t)N * 4;
    // time-aliased: pairs (NBK*BCAP ints, live partition..buildcsr) then h2p (N*16 bf16)
    unsigned short* h2p = (unsigned short*)(f + off);
    int*  pairs = (int*)(f + off);
    size_t r1 = ((size_t)N * 8 > (size_t)NBK * BCAP) ? (size_t)N * 8 : (size_t)NBK * BCAP;
    off += r1;
    int* iw = (int*)(f + off);
    size_t ioff = 0;
    int* meta    = iw + ioff; ioff += (size_t)N;
    int* csr_src = iw + ioff; ioff += (size_t)NBK * BCAP;
    int* bcnt    = iw + ioff; ioff += (size_t)NBK;
    float* pooled = (float*)(iw + ioff);
    float* cnt    = pooled + 640;

    hipMemsetAsync((void*)bcnt, 0, (size_t)NBK * sizeof(int), stream);

    int g1_blocks = (N + G1_BM - 1) / G1_BM;
    gemm1_kernel<<<g1_blocks, 256, 0, stream>>>(x, W1, a_src1, a_dst1, h1f, s1s, s1d, N);

    int ntiles = (E + A3_TILE - 1) / A3_TILE;
    partition_kernel<<<ntiles, 256, 0, stream>>>(ei, bcnt, pairs, E, NBK);
    buildcsr_kernel<<<NBK, 256, 0, stream>>>(pairs, bcnt, csr_src, meta, N);

    agg1_kernel<<<(N * 16 + 255) / 256, 256, 0, stream>>>(
        meta, csr_src, h1f, s1s, s1d, b1, W2, a_src2, a_dst2, h2p, N);

    agg2_kernel<<<(N * 8 + 255) / 256, 256, 0, stream>>>(
        meta, csr_src, h2p, b2, node_out, N);

    pool_kernel<<<64, 256, 0, stream>>>(node_out, batch, pooled, cnt, N);

    final_kernel<<<1, 64, 0, stream>>>(pooled, cnt, out);
}

// Round 13
// 133.741 us; speedup vs baseline: 3.8237x; 1.0856x over previous
//
#include <hip/hip_runtime.h>
#include <hip/hip_bf16.h>
#include <math.h>

#define BSHIFT 7
#define BWIDTH (1 << BSHIFT)       // 128 dst per bucket
#define BCAP 2560                  // bucket capacity (mean 2046, +11 sigma)
#define A3_TILE 4096

typedef float floatx2 __attribute__((ext_vector_type(2)));
typedef __attribute__((ext_vector_type(8))) short bf16x8;
typedef __attribute__((ext_vector_type(4))) float f32x4;

__device__ inline unsigned int f2bf(float f) {
    unsigned int u = __float_as_uint(f);
    return (u + 0x7FFFu + ((u >> 16) & 1u)) >> 16;   // RNE
}
__device__ inline float bflo(unsigned int u) { return __uint_as_float(u << 16); }
__device__ inline float bfhi(unsigned int u) { return __uint_as_float(u & 0xFFFF0000u); }

// decode 16 fp8 (one uint4), packed-FMA into 8 floatx2 accumulators
__device__ inline void fp8x16_fma2(uint4 Wv, float we, floatx2* q) {
    floatx2 w2; w2[0] = we; w2[1] = we;
    q[0] += w2 * __builtin_amdgcn_cvt_pk_f32_fp8((int)Wv.x, false);
    q[1] += w2 * __builtin_amdgcn_cvt_pk_f32_fp8((int)Wv.x, true);
    q[2] += w2 * __builtin_amdgcn_cvt_pk_f32_fp8((int)Wv.y, false);
    q[3] += w2 * __builtin_amdgcn_cvt_pk_f32_fp8((int)Wv.y, true);
    q[4] += w2 * __builtin_amdgcn_cvt_pk_f32_fp8((int)Wv.z, false);
    q[5] += w2 * __builtin_amdgcn_cvt_pk_f32_fp8((int)Wv.z, true);
    q[6] += w2 * __builtin_amdgcn_cvt_pk_f32_fp8((int)Wv.w, false);
    q[7] += w2 * __builtin_amdgcn_cvt_pk_f32_fp8((int)Wv.w, true);
}

// ---------------- GEMM1 (MFMA bf16): h1f(fp8) = x @ W1^T, plus s1s/s1d ----------------
#define G1_BM 128
__global__ __launch_bounds__(256) void gemm1_kernel(
    const float* __restrict__ x, const float* __restrict__ W1,
    const float* __restrict__ a_src, const float* __restrict__ a_dst,
    unsigned char* __restrict__ h1f, float* __restrict__ s1s,
    float* __restrict__ s1d, int N)
{
    __shared__ __align__(16) char smem[52224];
    unsigned short (*xb)[136] = (unsigned short(*)[136])smem;          // 128x136 bf16
    unsigned short (*wb)[136] = (unsigned short(*)[136])(smem + 34816);// 64x136 bf16
    float (*hls)[68] = (float(*)[68])smem;                             // epilogue overlay

    int tid = threadIdx.x;
    int nb = blockIdx.x * G1_BM;

    #pragma unroll
    for (int r = 0; r < 8; ++r) {
        int i = tid + r * 256;
        int ch = i >> 5, kq = i & 31;
        float4 v = *(const float4*)&W1[ch * 128 + kq * 4];
        uint2 pk;
        pk.x = f2bf(v.x) | (f2bf(v.y) << 16);
        pk.y = f2bf(v.z) | (f2bf(v.w) << 16);
        *(uint2*)&wb[ch][kq * 4] = pk;
    }
    #pragma unroll
    for (int r = 0; r < 16; ++r) {
        int i = tid + r * 256;
        int nl = i >> 5, kq = i & 31;
        int n = nb + nl;
        float4 v = (n < N) ? *(const float4*)&x[(size_t)n * 128 + kq * 4]
                           : make_float4(0.f, 0.f, 0.f, 0.f);
        uint2 pk;
        pk.x = f2bf(v.x) | (f2bf(v.y) << 16);
        pk.y = f2bf(v.z) | (f2bf(v.w) << 16);
        *(uint2*)&xb[nl][kq * 4] = pk;
    }
    __syncthreads();

    int lane = tid & 63, wv = tid >> 6;
    int lr = lane & 15, lk = lane >> 4;
    f32x4 acc[2][4];
    #pragma unroll
    for (int mt = 0; mt < 2; ++mt)
        #pragma unroll
        for (int nt = 0; nt < 4; ++nt) acc[mt][nt] = (f32x4){0.f, 0.f, 0.f, 0.f};

    #pragma unroll
    for (int ks = 0; ks < 4; ++ks) {
        int k0 = ks * 32 + lk * 8;
        bf16x8 af0 = *(const bf16x8*)&xb[wv * 32 + lr][k0];
        bf16x8 af1 = *(const bf16x8*)&xb[wv * 32 + 16 + lr][k0];
        #pragma unroll
        for (int nt = 0; nt < 4; ++nt) {
            bf16x8 bf = *(const bf16x8*)&wb[nt * 16 + lr][k0];
            acc[0][nt] = __builtin_amdgcn_mfma_f32_16x16x32_bf16(af0, bf, acc[0][nt], 0, 0, 0);
            acc[1][nt] = __builtin_amdgcn_mfma_f32_16x16x32_bf16(af1, bf, acc[1][nt], 0, 0, 0);
        }
    }
    __syncthreads();
    #pragma unroll
    for (int mt = 0; mt < 2; ++mt)
        #pragma unroll
        for (int nt = 0; nt < 4; ++nt)
            #pragma unroll
            for (int reg = 0; reg < 4; ++reg)
                hls[wv * 32 + mt * 16 + lk * 4 + reg][nt * 16 + lr] = acc[mt][nt][reg];
    __syncthreads();

    int nl = tid >> 1, half = tid & 1;
    int n = nb + nl;
    if (n < N) {
        float v[32];
        #pragma unroll
        for (int q = 0; q < 8; ++q) {
            float4 t4 = *(const float4*)&hls[nl][half * 32 + q * 4];
            v[q*4+0] = t4.x; v[q*4+1] = t4.y; v[q*4+2] = t4.z; v[q*4+3] = t4.w;
        }
        int h0 = half * 2, h1 = half * 2 + 1;
        float ss0 = 0.f, sd0 = 0.f, ss1 = 0.f, sd1 = 0.f;
        #pragma unroll
        for (int j = 0; j < 16; ++j) {
            ss0 += v[j] * a_src[h0 * 16 + j];
            sd0 += v[j] * a_dst[h0 * 16 + j];
            ss1 += v[16 + j] * a_src[h1 * 16 + j];
            sd1 += v[16 + j] * a_dst[h1 * 16 + j];
        }
        s1s[n * 4 + h0] = ss0; s1d[n * 4 + h0] = sd0;
        s1s[n * 4 + h1] = ss1; s1d[n * 4 + h1] = sd1;

        unsigned int w0, w1v, w2v, w3v, w4v, w5v, w6v, w7v;
        w0  = (unsigned)__builtin_amdgcn_cvt_pk_fp8_f32(v[0],  v[1],  0, false);
        w0  = (unsigned)__builtin_amdgcn_cvt_pk_fp8_f32(v[2],  v[3],  (int)w0, true);
        w1v = (unsigned)__builtin_amdgcn_cvt_pk_fp8_f32(v[4],  v[5],  0, false);
        w1v = (unsigned)__builtin_amdgcn_cvt_pk_fp8_f32(v[6],  v[7],  (int)w1v, true);
        w2v = (unsigned)__builtin_amdgcn_cvt_pk_fp8_f32(v[8],  v[9],  0, false);
        w2v = (unsigned)__builtin_amdgcn_cvt_pk_fp8_f32(v[10], v[11], (int)w2v, true);
        w3v = (unsigned)__builtin_amdgcn_cvt_pk_fp8_f32(v[12], v[13], 0, false);
        w3v = (unsigned)__builtin_amdgcn_cvt_pk_fp8_f32(v[14], v[15], (int)w3v, true);
        w4v = (unsigned)__builtin_amdgcn_cvt_pk_fp8_f32(v[16], v[17], 0, false);
        w4v = (unsigned)__builtin_amdgcn_cvt_pk_fp8_f32(v[18], v[19], (int)w4v, true);
        w5v = (unsigned)__builtin_amdgcn_cvt_pk_fp8_f32(v[20], v[21], 0, false);
        w5v = (unsigned)__builtin_amdgcn_cvt_pk_fp8_f32(v[22], v[23], (int)w5v, true);
        w6v = (unsigned)__builtin_amdgcn_cvt_pk_fp8_f32(v[24], v[25], 0, false);
        w6v = (unsigned)__builtin_amdgcn_cvt_pk_fp8_f32(v[26], v[27], (int)w6v, true);
        w7v = (unsigned)__builtin_amdgcn_cvt_pk_fp8_f32(v[28], v[29], 0, false);
        w7v = (unsigned)__builtin_amdgcn_cvt_pk_fp8_f32(v[30], v[31], (int)w7v, true);
        *(uint4*)(h1f + (size_t)n * 64 + half * 32)      = make_uint4(w0, w1v, w2v, w3v);
        *(uint4*)(h1f + (size_t)n * 64 + half * 32 + 16) = make_uint4(w4v, w5v, w6v, w7v);
    }
}

// ---------------- A3: partition edges into fixed-capacity buckets (packed) ----------------
__global__ __launch_bounds__(256) void partition_kernel(
    const int* __restrict__ ei, int* __restrict__ bcnt, int* __restrict__ pairs,
    int E, int NBK)
{
    __shared__ int hist[1024];
    __shared__ int scanb[1024];
    __shared__ int gbase[1024];
    __shared__ int partial[256];
    __shared__ int stage_pack[A3_TILE];
    __shared__ int stage_pos[A3_TILE];
    int t = threadIdx.x;
    int e0 = blockIdx.x * A3_TILE;
    for (int i = t; i < 1024; i += 256) hist[i] = 0;
    __syncthreads();
    int my_b[16], my_rank[16], my_pack[16];
    #pragma unroll
    for (int j = 0; j < 16; ++j) {
        int e = e0 + j * 256 + t;
        int b = -1, pack = 0, r = 0;
        if (e < E) {
            int s = ei[e], d = ei[E + e];
            b = d >> BSHIFT;
            pack = ((d & (BWIDTH - 1)) << 17) | s;
            r = atomicAdd(&hist[b], 1);
        }
        my_b[j] = b; my_pack[j] = pack; my_rank[j] = r;
    }
    __syncthreads();
    int b4 = t * 4;
    int h0 = hist[b4], h1v = hist[b4 + 1], h2v = hist[b4 + 2], h3v = hist[b4 + 3];
    int tot = h0 + h1v + h2v + h3v;
    partial[t] = tot;
    __syncthreads();
    for (int o = 1; o < 256; o <<= 1) {
        int u = (t >= o) ? partial[t - o] : 0;
        __syncthreads();
        partial[t] += u;
        __syncthreads();
    }
    int excl = partial[t] - tot;
    scanb[b4]     = excl;
    scanb[b4 + 1] = excl + h0;
    scanb[b4 + 2] = excl + h0 + h1v;
    scanb[b4 + 3] = excl + h0 + h1v + h2v;
    int nvalid = partial[255];
    for (int b = t; b < NBK; b += 256) {
        int c = hist[b];
        if (c > 0) gbase[b] = b * BCAP + atomicAdd(&bcnt[b], c);
    }
    __syncthreads();
    #pragma unroll
    for (int j = 0; j < 16; ++j) {
        int b = my_b[j];
        if (b >= 0) {
            int slot = scanb[b] + my_rank[j];
            stage_pack[slot] = my_pack[j];
            stage_pos[slot]  = gbase[b] + my_rank[j];
        }
    }
    __syncthreads();
    for (int i = t; i < nvalid; i += 256)
        pairs[stage_pos[i]] = stage_pack[i];
}

// ---- B: build padded CSR + meta from one bucket (LDS-staged, one pass) ----
// meta[n] = (local_start << 16) | deg ; csr row for n = (n>>7)*BCAP + local_start
__global__ __launch_bounds__(256) void buildcsr_kernel(
    const int* __restrict__ pairs, const int* __restrict__ bcnt,
    int* __restrict__ csr_src, int* __restrict__ meta, int N)
{
    int b = blockIdx.x;
    __shared__ int stage[BCAP];
    __shared__ int hist[BWIDTH];
    __shared__ int scn[BWIDTH];
    __shared__ int cur[BWIDTH];
    int t = threadIdx.x;
    if (t < BWIDTH) hist[t] = 0;
    __syncthreads();
    int cnt = bcnt[b];
    int base = b * BCAP;
    for (int i = t; i < cnt; i += 256) {
        int p = pairs[base + i];
        stage[i] = p;
        atomicAdd(&hist[(p >> 17) & (BWIDTH - 1)], 1);
    }
    __syncthreads();
    int v = (t < BWIDTH) ? hist[t] : 0;
    if (t < BWIDTH) scn[t] = v;
    __syncthreads();
    for (int o = 1; o < BWIDTH; o <<= 1) {
        int u = (t < BWIDTH && t >= o) ? scn[t - o] : 0;
        __syncthreads();
        if (t < BWIDTH) scn[t] += u;
        __syncthreads();
    }
    if (t < BWIDTH) {
        int excl = scn[t] - v;
        cur[t] = excl;
        int dst = b * BWIDTH + t;
        if (dst < N) meta[dst] = (excl << 16) | v;
    }
    __syncthreads();
    for (int i = t; i < cnt; i += 256) {
        int p = stage[i];
        int slot = atomicAdd(&cur[(p >> 17) & (BWIDTH - 1)], 1);
        csr_src[base + slot] = p & 0x1FFFF;
    }
}

// ---- Conv1 aggregation (fp8 gather, 2-edge unroll, pk-fma) + ELU + fused gemm2 ----
// 16 threads per node: 4 heads x 4 edge-quarters; gemm2 c-split across subs
__global__ __launch_bounds__(256) void agg1_kernel(
    const int* __restrict__ meta, const int* __restrict__ csr_src,
    const unsigned char* __restrict__ h1f, const float* __restrict__ s1s,
    const float* __restrict__ s1d, const float* __restrict__ b1,
    const float* __restrict__ W2, const float* __restrict__ as2,
    const float* __restrict__ ad2, unsigned short* __restrict__ h2p, int N)
{
    __shared__ float w2s[640];
    for (int i = threadIdx.x; i < 640; i += 256) w2s[i] = W2[i];
    __syncthreads();

    int tid = blockIdx.x * 256 + threadIdx.x;
    int n = tid >> 4, h = tid & 3, sub = (tid >> 2) & 3;
    floatx2 xq[8];
    #pragma unroll
    for (int j = 0; j < 8; ++j) { xq[j][0] = 0.f; xq[j][1] = 0.f; }
    float den = 0.f;

    if (n < N) {
        float sdst = s1d[n * 4 + h];
        if (sub == 0) {   // self-loop
            float s = s1s[n * 4 + h] + sdst;
            s = (s >= 0.f) ? s : 0.2f * s;
            float w = __expf(s);
            den = w;
            uint4 Wv = *(const uint4*)(h1f + ((size_t)n << 6) + (h << 4));
            fp8x16_fma2(Wv, w, xq);
        }
        int mn = meta[n];
        int row = (n >> BSHIFT) * BCAP + (mn >> 16);
        int end = row + (mn & 0xFFFF);
        int i = row + sub;
        for (; i + 4 < end; i += 8) {     // two edges per iteration (MLP)
            int src0 = csr_src[i];
            int src1 = csr_src[i + 4];
            uint4 W0 = *(const uint4*)(h1f + ((size_t)src0 << 6) + (h << 4));
            uint4 W1 = *(const uint4*)(h1f + ((size_t)src1 << 6) + (h << 4));
            float a0 = s1s[src0 * 4 + h];
            float a1 = s1s[src1 * 4 + h];
            float e0 = a0 + sdst; e0 = (e0 >= 0.f) ? e0 : 0.2f * e0;
            float e1 = a1 + sdst; e1 = (e1 >= 0.f) ? e1 : 0.2f * e1;
            float w0 = __expf(e0);
            float w1 = __expf(e1);
            den += w0 + w1;
            fp8x16_fma2(W0, w0, xq);
            fp8x16_fma2(W1, w1, xq);
        }
        if (i < end) {
            int src = csr_src[i];
            uint4 Wv = *(const uint4*)(h1f + ((size_t)src << 6) + (h << 4));
            float ss = s1s[src * 4 + h] + sdst;
            ss = (ss >= 0.f) ? ss : 0.2f * ss;
            float we = __expf(ss);
            den += we;
            fp8x16_fma2(Wv, we, xq);
        }
    }
    float* xl = (float*)xq;
    // merge edge-quarters within each head
    #pragma unroll
    for (int j = 0; j < 16; ++j) {
        xl[j] += __shfl_xor(xl[j], 4);
        xl[j] += __shfl_xor(xl[j], 8);
    }
    den += __shfl_xor(den, 4);
    den += __shfl_xor(den, 8);

    float inv = 1.f / (den + 1e-16f);
    #pragma unroll
    for (int j = 0; j < 16; ++j) {
        float v = xl[j] * inv + b1[h * 16 + j];
        xl[j] = (v > 0.f) ? v : (__expf(v) - 1.f);
    }

    // fused layer-2 matmul, c-split across subs: sub0:c0-2 sub1:c3-5 sub2:c6-8 sub3:c9
    int clo = sub * 3;
    int nc = (sub == 3) ? 1 : 3;
    float part[3] = {0.f, 0.f, 0.f};
    #pragma unroll
    for (int idx = 0; idx < 3; ++idx) {
        if (idx < nc) {
            const float* wr = &w2s[(clo + idx) * 64 + h * 16];
            float p = 0.f;
            #pragma unroll
            for (int j = 0; j < 16; ++j) p += xl[j] * wr[j];
            part[idx] = p;
        }
    }
    #pragma unroll
    for (int idx = 0; idx < 3; ++idx) {
        part[idx] += __shfl_xor(part[idx], 1);
        part[idx] += __shfl_xor(part[idx], 2);
    }
    float ssp = 0.f, sdp = 0.f;
    #pragma unroll
    for (int idx = 0; idx < 3; ++idx) {
        if (idx < nc) {
            ssp += part[idx] * as2[clo + idx];
            sdp += part[idx] * ad2[clo + idx];
        }
    }
    ssp += __shfl_xor(ssp, 4); ssp += __shfl_xor(ssp, 8);
    sdp += __shfl_xor(sdp, 4); sdp += __shfl_xor(sdp, 8);

    if (n < N && h == 0) {
        #pragma unroll
        for (int idx = 0; idx < 3; ++idx)
            if (idx < nc)
                h2p[(size_t)n * 16 + clo + idx] = (unsigned short)f2bf(part[idx]);
        if (sub == 3) {
            h2p[(size_t)n * 16 + 10] = (unsigned short)f2bf(ssp);
            h2p[(size_t)n * 16 + 11] = (unsigned short)f2bf(sdp);
        }
    }
}

// ---- Conv2 aggregation (bf16 rows, 8 threads/node, 2-edge unroll) -> node_out ----
__global__ __launch_bounds__(256) void agg2_kernel(
    const int* __restrict__ meta, const int* __restrict__ csr_src,
    const unsigned short* __restrict__ h2p, const float* __restrict__ b2,
    float* __restrict__ node_out, int N)
{
    int tid = blockIdx.x * 256 + threadIdx.x;
    int n = tid >> 3, t = tid & 7;
    if (n >= N) return;
    floatx2 aq[5];
    #pragma unroll
    for (int c = 0; c < 5; ++c) { aq[c][0] = 0.f; aq[c][1] = 0.f; }
    float den = 0.f;

    uint2 d1 = *(const uint2*)(h2p + (size_t)n * 16 + 8);  // {c8|c9, ss|sd}
    float sdst = bfhi(d1.y);
    if (t == 0) {
        uint4 d0 = *(const uint4*)(h2p + (size_t)n * 16);
        float s = bflo(d1.y) + sdst;
        s = (s >= 0.f) ? s : 0.2f * s;
        float w = __expf(s);
        den = w;
        floatx2 w2; w2[0] = w; w2[1] = w;
        floatx2 p;
        p[0] = bflo(d0.x); p[1] = bfhi(d0.x); aq[0] += w2 * p;
        p[0] = bflo(d0.y); p[1] = bfhi(d0.y); aq[1] += w2 * p;
        p[0] = bflo(d0.z); p[1] = bfhi(d0.z); aq[2] += w2 * p;
        p[0] = bflo(d0.w); p[1] = bfhi(d0.w); aq[3] += w2 * p;
        p[0] = bflo(d1.x); p[1] = bfhi(d1.x); aq[4] += w2 * p;
    }
    int mn = meta[n];
    int row = (n >> BSHIFT) * BCAP + (mn >> 16);
    int end = row + (mn & 0xFFFF);
    int i = row + t;
    for (; i + 8 < end; i += 16) {        // two edges per iteration (MLP)
        int src0 = csr_src[i];
        int src1 = csr_src[i + 8];
        uint4 A0 = *(const uint4*)(h2p + (size_t)src0 * 16);
        uint2 B0 = *(const uint2*)(h2p + (size_t)src0 * 16 + 8);
        uint4 A1 = *(const uint4*)(h2p + (size_t)src1 * 16);
        uint2 B1 = *(const uint2*)(h2p + (size_t)src1 * 16 + 8);
        float e0 = bflo(B0.y) + sdst; e0 = (e0 >= 0.f) ? e0 : 0.2f * e0;
        float e1 = bflo(B1.y) + sdst; e1 = (e1 >= 0.f) ? e1 : 0.2f * e1;
        float w0 = __expf(e0);
        float w1 = __expf(e1);
        den += w0 + w1;
        floatx2 w20; w20[0] = w0; w20[1] = w0;
        floatx2 w21; w21[0] = w1; w21[1] = w1;
        floatx2 p;
        p[0] = bflo(A0.x); p[1] = bfhi(A0.x); aq[0] += w20 * p;
        p[0] = bflo(A0.y); p[1] = bfhi(A0.y); aq[1] += w20 * p;
        p[0] = bflo(A0.z); p[1] = bfhi(A0.z); aq[2] += w20 * p;
        p[0] = bflo(A0.w); p[1] = bfhi(A0.w); aq[3] += w20 * p;
        p[0] = bflo(B0.x); p[1] = bfhi(B0.x); aq[4] += w20 * p;
        p[0] = bflo(A1.x); p[1] = bfhi(A1.x); aq[0] += w21 * p;
        p[0] = bflo(A1.y); p[1] = bfhi(A1.y); aq[1] += w21 * p;
        p[0] = bflo(A1.z); p[1] = bfhi(A1.z); aq[2] += w21 * p;
        p[0] = bflo(A1.w); p[1] = bfhi(A1.w); aq[3] += w21 * p;
        p[0] = bflo(B1.x); p[1] = bfhi(B1.x); aq[4] += w21 * p;
    }
    if (i < end) {
        int src = csr_src[i];
        uint4 A0 = *(const uint4*)(h2p + (size_t)src * 16);
        uint2 B0 = *(const uint2*)(h2p + (size_t)src * 16 + 8);
        float s = bflo(B0.y) + sdst;
        s = (s >= 0.f) ? s : 0.2f * s;
        float we = __expf(s);
        den += we;
        floatx2 w2; w2[0] = we; w2[1] = we;
        floatx2 p;
        p[0] = bflo(A0.x); p[1] = bfhi(A0.x); aq[0] += w2 * p;
        p[0] = bflo(A0.y); p[1] = bfhi(A0.y); aq[1] += w2 * p;
        p[0] = bflo(A0.z); p[1] = bfhi(A0.z); aq[2] += w2 * p;
        p[0] = bflo(A0.w); p[1] = bfhi(A0.w); aq[3] += w2 * p;
        p[0] = bflo(B0.x); p[1] = bfhi(B0.x); aq[4] += w2 * p;
    }
    float* acc = (float*)aq;
    #pragma unroll
    for (int c = 0; c < 10; ++c) {
        acc[c] += __shfl_xor(acc[c], 1);
        acc[c] += __shfl_xor(acc[c], 2);
        acc[c] += __shfl_xor(acc[c], 4);
    }
    den += __shfl_xor(den, 1);
    den += __shfl_xor(den, 2);
    den += __shfl_xor(den, 4);

    if (t == 0) {
        float inv = 1.f / (den + 1e-16f);
        float* o = &node_out[(size_t)n * 12];
        *(float4*)o = make_float4(acc[0]*inv + b2[0], acc[1]*inv + b2[1],
                                  acc[2]*inv + b2[2], acc[3]*inv + b2[3]);
        *(float4*)(o + 4) = make_float4(acc[4]*inv + b2[4], acc[5]*inv + b2[5],
                                        acc[6]*inv + b2[6], acc[7]*inv + b2[7]);
        *(float2*)(o + 8) = make_float2(acc[8]*inv + b2[8], acc[9]*inv + b2[9]);
    }
}

// ---- Pool: one block per graph; batch sorted -> binary-search range; no atomics ----
__global__ __launch_bounds__(256) void pool_kernel(
    const float* __restrict__ node_out, const int* __restrict__ batch,
    float* __restrict__ pooled, float* __restrict__ cnt, int N)
{
    int g = blockIdx.x;
    int lo = 0, hi = N;
    while (lo < hi) { int m = (lo + hi) >> 1; if (batch[m] < g) lo = m + 1; else hi = m; }
    int s0 = lo;
    hi = N;
    while (lo < hi) { int m = (lo + hi) >> 1; if (batch[m] < g + 1) lo = m + 1; else hi = m; }
    int s1 = lo;

    float acc[10];
    #pragma unroll
    for (int c = 0; c < 10; ++c) acc[c] = 0.f;
    for (int i = s0 + threadIdx.x; i < s1; i += 256) {
        const float* o = &node_out[(size_t)i * 12];
        float4 a = *(const float4*)o;
        float4 b = *(const float4*)(o + 4);
        float2 d = *(const float2*)(o + 8);
        acc[0] += a.x; acc[1] += a.y; acc[2] += a.z; acc[3] += a.w;
        acc[4] += b.x; acc[5] += b.y; acc[6] += b.z; acc[7] += b.w;
        acc[8] += d.x; acc[9] += d.y;
    }
    #pragma unroll
    for (int c = 0; c < 10; ++c)
        for (int o = 32; o > 0; o >>= 1) acc[c] += __shfl_down(acc[c], o);
    __shared__ float part[4][10];
    int wave = threadIdx.x >> 6, lane = threadIdx.x & 63;
    if (lane == 0)
        #pragma unroll
        for (int c = 0; c < 10; ++c) part[wave][c] = acc[c];
    __syncthreads();
    if (threadIdx.x < 10) {
        float s = part[0][threadIdx.x] + part[1][threadIdx.x]
                + part[2][threadIdx.x] + part[3][threadIdx.x];
        pooled[g * 10 + threadIdx.x] = s;
        if (threadIdx.x == 0) cnt[g] = (float)(s1 - s0);
    }
}

// ---------------- Final: mean + log_softmax ----------------
__global__ void final_kernel(const float* __restrict__ pooled,
                             const float* __restrict__ cnt, float* __restrict__ out)
{
    int g = threadIdx.x;
    if (g >= 64) return;
    float c = cnt[g];
    if (c < 1.f) c = 1.f;
    float v[10], m = -1e30f;
    #pragma unroll
    for (int i = 0; i < 10; ++i) {
        v[i] = pooled[g * 10 + i] / c;
        m = fmaxf(m, v[i]);
    }
    float s = 0.f;
    #pragma unroll
    for (int i = 0; i < 10; ++i) s += __expf(v[i] - m);
    float lse = m + logf(s);
    #pragma unroll
    for (int i = 0; i < 10; ++i) out[g * 10 + i] = v[i] - lse;
}

extern "C" void kernel_launch(void* const* d_in, const int* in_sizes, int n_in,
                              void* d_out, int out_size, void* d_ws, size_t ws_size,
                              hipStream_t stream) {
    const float* x       = (const float*)d_in[0];
    const int*   ei      = (const int*)  d_in[1];
    const int*   batch   = (const int*)  d_in[2];
    const float* W1      = (const float*)d_in[3];
    const float* a_src1  = (const float*)d_in[4];
    const float* a_dst1  = (const float*)d_in[5];
    const float* b1      = (const float*)d_in[6];
    const float* W2      = (const float*)d_in[7];
    const float* a_src2  = (const float*)d_in[8];
    const float* a_dst2  = (const float*)d_in[9];
    const float* b2      = (const float*)d_in[10];
    float* out = (float*)d_out;

    int N = in_sizes[0] / 128;
    int E = in_sizes[1] / 2;
    int NBK = (N + BWIDTH - 1) >> BSHIFT;

    float* f = (float*)d_ws;
    size_t off = 0;
    unsigned char* h1f = (unsigned char*)(f + off);
    float* node_out = (float*)h1f;      // aliased: h1f dead after agg1, node_out agg2..pool
    off += (size_t)N * 16;              // N*64 fp8 bytes = N*16 floats (>= N*12 floats)
    float* s1s  = f + off; off += (size_t)N * 4;
    float* s1d  = f + off; off += (size_t)N * 4;
    // time-aliased: pairs (NBK*BCAP ints, live partition..buildcsr) then h2p (N*16 bf16)
    unsigned short* h2p = (unsigned short*)(f + off);
    int*  pairs = (int*)(f + off);
    size_t r1 = ((size_t)N * 8 > (size_t)NBK * BCAP) ? (size_t)N * 8 : (size_t)NBK * BCAP;
    off += r1;
    int* iw = (int*)(f + off);
    size_t ioff = 0;
    int* meta    = iw + ioff; ioff += (size_t)N;
    int* csr_src = iw + ioff; ioff += (size_t)NBK * BCAP;
    int* bcnt    = iw + ioff; ioff += (size_t)NBK;
    float* pooled = (float*)(iw + ioff);
    float* cnt    = pooled + 640;

    hipMemsetAsync((void*)bcnt, 0, (size_t)NBK * sizeof(int), stream);

    int g1_blocks = (N + G1_BM - 1) / G1_BM;
    gemm1_kernel<<<g1_blocks, 256, 0, stream>>>(x, W1, a_src1, a_dst1, h1f, s1s, s1d, N);

    int ntiles = (E + A3_TILE - 1) / A3_TILE;
    partition_kernel<<<ntiles, 256, 0, stream>>>(ei, bcnt, pairs, E, NBK);
    buildcsr_kernel<<<NBK, 256, 0, stream>>>(pairs, bcnt, csr_src, meta, N);

    agg1_kernel<<<(N * 16 + 255) / 256, 256, 0, stream>>>(
        meta, csr_src, h1f, s1s, s1d, b1, W2, a_src2, a_dst2, h2p, N);

    agg2_kernel<<<(N * 8 + 255) / 256, 256, 0, stream>>>(
        meta, csr_src, h2p, b2, node_out, N);

    pool_kernel<<<64, 256, 0, stream>>>(node_out, batch, pooled, cnt, N);

    final_kernel<<<1, 64, 0, stream>>>(pooled, cnt, out);
}

// Round 14
// 124.652 us; speedup vs baseline: 4.1025x; 1.0729x over previous
//
#include <hip/hip_runtime.h>
#include <hip/hip_bf16.h>
#include <math.h>

#define BSHIFT 7
#define BWIDTH (1 << BSHIFT)       // 128 dst per bucket
#define BCAP 2560                  // bucket capacity (mean 2046, +11 sigma)
#define A3_TILE 4096

typedef float floatx2 __attribute__((ext_vector_type(2)));
typedef __attribute__((ext_vector_type(8))) short bf16x8;
typedef __attribute__((ext_vector_type(4))) float f32x4;

__device__ inline unsigned int f2bf(float f) {
    unsigned int u = __float_as_uint(f);
    return (u + 0x7FFFu + ((u >> 16) & 1u)) >> 16;   // RNE
}
__device__ inline float bflo(unsigned int u) { return __uint_as_float(u << 16); }
__device__ inline float bfhi(unsigned int u) { return __uint_as_float(u & 0xFFFF0000u); }

// decode 16 fp8 (one uint4), packed-FMA into 8 floatx2 accumulators
__device__ inline void fp8x16_fma2(uint4 Wv, float we, floatx2* q) {
    floatx2 w2; w2[0] = we; w2[1] = we;
    q[0] += w2 * __builtin_amdgcn_cvt_pk_f32_fp8((int)Wv.x, false);
    q[1] += w2 * __builtin_amdgcn_cvt_pk_f32_fp8((int)Wv.x, true);
    q[2] += w2 * __builtin_amdgcn_cvt_pk_f32_fp8((int)Wv.y, false);
    q[3] += w2 * __builtin_amdgcn_cvt_pk_f32_fp8((int)Wv.y, true);
    q[4] += w2 * __builtin_amdgcn_cvt_pk_f32_fp8((int)Wv.z, false);
    q[5] += w2 * __builtin_amdgcn_cvt_pk_f32_fp8((int)Wv.z, true);
    q[6] += w2 * __builtin_amdgcn_cvt_pk_f32_fp8((int)Wv.w, false);
    q[7] += w2 * __builtin_amdgcn_cvt_pk_f32_fp8((int)Wv.w, true);
}

#define G1_BM 128

// ---------------- gemm1 body (MFMA bf16): h1f(fp8) = x @ W1^T, plus s1s/s1d ----------------
__device__ void gemm1_body(char* smem, int bid,
    const float* __restrict__ x, const float* __restrict__ W1,
    const float* __restrict__ a_src, const float* __restrict__ a_dst,
    unsigned char* __restrict__ h1f, float* __restrict__ s1s,
    float* __restrict__ s1d, int N)
{
    unsigned short (*xb)[136] = (unsigned short(*)[136])smem;          // 128x136 bf16
    unsigned short (*wb)[136] = (unsigned short(*)[136])(smem + 34816);// 64x136 bf16
    float (*hls)[68] = (float(*)[68])smem;                             // epilogue overlay

    int tid = threadIdx.x;
    int nb = bid * G1_BM;

    #pragma unroll
    for (int r = 0; r < 8; ++r) {
        int i = tid + r * 256;
        int ch = i >> 5, kq = i & 31;
        float4 v = *(const float4*)&W1[ch * 128 + kq * 4];
        uint2 pk;
        pk.x = f2bf(v.x) | (f2bf(v.y) << 16);
        pk.y = f2bf(v.z) | (f2bf(v.w) << 16);
        *(uint2*)&wb[ch][kq * 4] = pk;
    }
    #pragma unroll
    for (int r = 0; r < 16; ++r) {
        int i = tid + r * 256;
        int nl = i >> 5, kq = i & 31;
        int n = nb + nl;
        float4 v = (n < N) ? *(const float4*)&x[(size_t)n * 128 + kq * 4]
                           : make_float4(0.f, 0.f, 0.f, 0.f);
        uint2 pk;
        pk.x = f2bf(v.x) | (f2bf(v.y) << 16);
        pk.y = f2bf(v.z) | (f2bf(v.w) << 16);
        *(uint2*)&xb[nl][kq * 4] = pk;
    }
    __syncthreads();

    int lane = tid & 63, wv = tid >> 6;
    int lr = lane & 15, lk = lane >> 4;
    f32x4 acc[2][4];
    #pragma unroll
    for (int mt = 0; mt < 2; ++mt)
        #pragma unroll
        for (int nt = 0; nt < 4; ++nt) acc[mt][nt] = (f32x4){0.f, 0.f, 0.f, 0.f};

    #pragma unroll
    for (int ks = 0; ks < 4; ++ks) {
        int k0 = ks * 32 + lk * 8;
        bf16x8 af0 = *(const bf16x8*)&xb[wv * 32 + lr][k0];
        bf16x8 af1 = *(const bf16x8*)&xb[wv * 32 + 16 + lr][k0];
        #pragma unroll
        for (int nt = 0; nt < 4; ++nt) {
            bf16x8 bf = *(const bf16x8*)&wb[nt * 16 + lr][k0];
            acc[0][nt] = __builtin_amdgcn_mfma_f32_16x16x32_bf16(af0, bf, acc[0][nt], 0, 0, 0);
            acc[1][nt] = __builtin_amdgcn_mfma_f32_16x16x32_bf16(af1, bf, acc[1][nt], 0, 0, 0);
        }
    }
    __syncthreads();
    #pragma unroll
    for (int mt = 0; mt < 2; ++mt)
        #pragma unroll
        for (int nt = 0; nt < 4; ++nt)
            #pragma unroll
            for (int reg = 0; reg < 4; ++reg)
                hls[wv * 32 + mt * 16 + lk * 4 + reg][nt * 16 + lr] = acc[mt][nt][reg];
    __syncthreads();

    int nl = tid >> 1, half = tid & 1;
    int n = nb + nl;
    if (n < N) {
        float v[32];
        #pragma unroll
        for (int q = 0; q < 8; ++q) {
            float4 t4 = *(const float4*)&hls[nl][half * 32 + q * 4];
            v[q*4+0] = t4.x; v[q*4+1] = t4.y; v[q*4+2] = t4.z; v[q*4+3] = t4.w;
        }
        int h0 = half * 2, h1 = half * 2 + 1;
        float ss0 = 0.f, sd0 = 0.f, ss1 = 0.f, sd1 = 0.f;
        #pragma unroll
        for (int j = 0; j < 16; ++j) {
            ss0 += v[j] * a_src[h0 * 16 + j];
            sd0 += v[j] * a_dst[h0 * 16 + j];
            ss1 += v[16 + j] * a_src[h1 * 16 + j];
            sd1 += v[16 + j] * a_dst[h1 * 16 + j];
        }
        s1s[n * 4 + h0] = ss0; s1d[n * 4 + h0] = sd0;
        s1s[n * 4 + h1] = ss1; s1d[n * 4 + h1] = sd1;

        unsigned int w0, w1v, w2v, w3v, w4v, w5v, w6v, w7v;
        w0  = (unsigned)__builtin_amdgcn_cvt_pk_fp8_f32(v[0],  v[1],  0, false);
        w0  = (unsigned)__builtin_amdgcn_cvt_pk_fp8_f32(v[2],  v[3],  (int)w0, true);
        w1v = (unsigned)__builtin_amdgcn_cvt_pk_fp8_f32(v[4],  v[5],  0, false);
        w1v = (unsigned)__builtin_amdgcn_cvt_pk_fp8_f32(v[6],  v[7],  (int)w1v, true);
        w2v = (unsigned)__builtin_amdgcn_cvt_pk_fp8_f32(v[8],  v[9],  0, false);
        w2v = (unsigned)__builtin_amdgcn_cvt_pk_fp8_f32(v[10], v[11], (int)w2v, true);
        w3v = (unsigned)__builtin_amdgcn_cvt_pk_fp8_f32(v[12], v[13], 0, false);
        w3v = (unsigned)__builtin_amdgcn_cvt_pk_fp8_f32(v[14], v[15], (int)w3v, true);
        w4v = (unsigned)__builtin_amdgcn_cvt_pk_fp8_f32(v[16], v[17], 0, false);
        w4v = (unsigned)__builtin_amdgcn_cvt_pk_fp8_f32(v[18], v[19], (int)w4v, true);
        w5v = (unsigned)__builtin_amdgcn_cvt_pk_fp8_f32(v[20], v[21], 0, false);
        w5v = (unsigned)__builtin_amdgcn_cvt_pk_fp8_f32(v[22], v[23], (int)w5v, true);
        w6v = (unsigned)__builtin_amdgcn_cvt_pk_fp8_f32(v[24], v[25], 0, false);
        w6v = (unsigned)__builtin_amdgcn_cvt_pk_fp8_f32(v[26], v[27], (int)w6v, true);
        w7v = (unsigned)__builtin_amdgcn_cvt_pk_fp8_f32(v[28], v[29], 0, false);
        w7v = (unsigned)__builtin_amdgcn_cvt_pk_fp8_f32(v[30], v[31], (int)w7v, true);
        *(uint4*)(h1f + (size_t)n * 64 + half * 32)      = make_uint4(w0, w1v, w2v, w3v);
        *(uint4*)(h1f + (size_t)n * 64 + half * 32 + 16) = make_uint4(w4v, w5v, w6v, w7v);
    }
}

// ---------------- partition body: edges -> fixed-capacity buckets (packed) ----------------
__device__ void partition_body(char* smem, int bid,
    const int* __restrict__ ei, int* __restrict__ bcnt, int* __restrict__ pairs,
    int E, int NBK)
{
    int* hist       = (int*)smem;            // 1024
    int* scanb      = hist + 1024;           // 1024
    int* gbase      = scanb + 1024;          // 1024
    int* partial    = gbase + 1024;          // 256
    int* stage_pack = partial + 256;         // 4096
    int* stage_pos  = stage_pack + A3_TILE;  // 4096  (total 46080 B < 52224)

    int t = threadIdx.x;
    int e0 = bid * A3_TILE;
    for (int i = t; i < 1024; i += 256) hist[i] = 0;
    __syncthreads();
    int my_b[16], my_rank[16], my_pack[16];
    #pragma unroll
    for (int j = 0; j < 16; ++j) {
        int e = e0 + j * 256 + t;
        int b = -1, pack = 0, r = 0;
        if (e < E) {
            int s = ei[e], d = ei[E + e];
            b = d >> BSHIFT;
            pack = ((d & (BWIDTH - 1)) << 17) | s;
            r = atomicAdd(&hist[b], 1);
        }
        my_b[j] = b; my_pack[j] = pack; my_rank[j] = r;
    }
    __syncthreads();
    int b4 = t * 4;
    int h0 = hist[b4], h1v = hist[b4 + 1], h2v = hist[b4 + 2], h3v = hist[b4 + 3];
    int tot = h0 + h1v + h2v + h3v;
    partial[t] = tot;
    __syncthreads();
    for (int o = 1; o < 256; o <<= 1) {
        int u = (t >= o) ? partial[t - o] : 0;
        __syncthreads();
        partial[t] += u;
        __syncthreads();
    }
    int excl = partial[t] - tot;
    scanb[b4]     = excl;
    scanb[b4 + 1] = excl + h0;
    scanb[b4 + 2] = excl + h0 + h1v;
    scanb[b4 + 3] = excl + h0 + h1v + h2v;
    int nvalid = partial[255];
    for (int b = t; b < NBK; b += 256) {
        int c = hist[b];
        if (c > 0) gbase[b] = b * BCAP + atomicAdd(&bcnt[b], c);
    }
    __syncthreads();
    #pragma unroll
    for (int j = 0; j < 16; ++j) {
        int b = my_b[j];
        if (b >= 0) {
            int slot = scanb[b] + my_rank[j];
            stage_pack[slot] = my_pack[j];
            stage_pos[slot]  = gbase[b] + my_rank[j];
        }
    }
    __syncthreads();
    for (int i = t; i < nvalid; i += 256)
        pairs[stage_pos[i]] = stage_pack[i];
}

// ---- Fat kernel: gemm1 blocks [0, G1B) || partition blocks [G1B, G1B+ntiles) ----
__global__ __launch_bounds__(256) void gp_kernel(
    const float* __restrict__ x, const float* __restrict__ W1,
    const float* __restrict__ a_src, const float* __restrict__ a_dst,
    unsigned char* __restrict__ h1f, float* __restrict__ s1s,
    float* __restrict__ s1d, const int* __restrict__ ei,
    int* __restrict__ bcnt, int* __restrict__ pairs,
    int N, int E, int NBK, int G1B)
{
    __shared__ __align__(16) char smem[52224];
    if ((int)blockIdx.x < G1B)
        gemm1_body(smem, blockIdx.x, x, W1, a_src, a_dst, h1f, s1s, s1d, N);
    else
        partition_body(smem, blockIdx.x - G1B, ei, bcnt, pairs, E, NBK);
}

// ---- B: build padded CSR + meta from one bucket (LDS-staged, one pass) ----
// meta[n] = (local_start << 16) | deg ; csr row for n = (n>>7)*BCAP + local_start
__global__ __launch_bounds__(256) void buildcsr_kernel(
    const int* __restrict__ pairs, const int* __restrict__ bcnt,
    int* __restrict__ csr_src, int* __restrict__ meta, int N)
{
    int b = blockIdx.x;
    __shared__ int stage[BCAP];
    __shared__ int hist[BWIDTH];
    __shared__ int scn[BWIDTH];
    __shared__ int cur[BWIDTH];
    int t = threadIdx.x;
    if (t < BWIDTH) hist[t] = 0;
    __syncthreads();
    int cnt = bcnt[b];
    int base = b * BCAP;
    for (int i = t; i < cnt; i += 256) {
        int p = pairs[base + i];
        stage[i] = p;
        atomicAdd(&hist[(p >> 17) & (BWIDTH - 1)], 1);
    }
    __syncthreads();
    int v = (t < BWIDTH) ? hist[t] : 0;
    if (t < BWIDTH) scn[t] = v;
    __syncthreads();
    for (int o = 1; o < BWIDTH; o <<= 1) {
        int u = (t < BWIDTH && t >= o) ? scn[t - o] : 0;
        __syncthreads();
        if (t < BWIDTH) scn[t] += u;
        __syncthreads();
    }
    if (t < BWIDTH) {
        int excl = scn[t] - v;
        cur[t] = excl;
        int dst = b * BWIDTH + t;
        if (dst < N) meta[dst] = (excl << 16) | v;
    }
    __syncthreads();
    for (int i = t; i < cnt; i += 256) {
        int p = stage[i];
        int slot = atomicAdd(&cur[(p >> 17) & (BWIDTH - 1)], 1);
        csr_src[base + slot] = p & 0x1FFFF;
    }
}

// ---- Conv1 aggregation (fp8 gather, 2-edge unroll, pk-fma) + ELU + fused gemm2 ----
// 16 threads per node: 4 heads x 4 edge-quarters; gemm2 c-split across subs
__global__ __launch_bounds__(256) void agg1_kernel(
    const int* __restrict__ meta, const int* __restrict__ csr_src,
    const unsigned char* __restrict__ h1f, const float* __restrict__ s1s,
    const float* __restrict__ s1d, const float* __restrict__ b1,
    const float* __restrict__ W2, const float* __restrict__ as2,
    const float* __restrict__ ad2, unsigned short* __restrict__ h2p, int N)
{
    __shared__ float w2s[640];
    for (int i = threadIdx.x; i < 640; i += 256) w2s[i] = W2[i];
    __syncthreads();

    int tid = blockIdx.x * 256 + threadIdx.x;
    int n = tid >> 4, h = tid & 3, sub = (tid >> 2) & 3;
    floatx2 xq[8];
    #pragma unroll
    for (int j = 0; j < 8; ++j) { xq[j][0] = 0.f; xq[j][1] = 0.f; }
    float den = 0.f;

    if (n < N) {
        float sdst = s1d[n * 4 + h];
        if (sub == 0) {   // self-loop
            float s = s1s[n * 4 + h] + sdst;
            s = (s >= 0.f) ? s : 0.2f * s;
            float w = __expf(s);
            den = w;
            uint4 Wv = *(const uint4*)(h1f + ((size_t)n << 6) + (h << 4));
            fp8x16_fma2(Wv, w, xq);
        }
        int mn = meta[n];
        int row = (n >> BSHIFT) * BCAP + (mn >> 16);
        int end = row + (mn & 0xFFFF);
        int i = row + sub;
        for (; i + 4 < end; i += 8) {     // two edges per iteration (MLP)
            int src0 = csr_src[i];
            int src1 = csr_src[i + 4];
            uint4 W0 = *(const uint4*)(h1f + ((size_t)src0 << 6) + (h << 4));
            uint4 W1 = *(const uint4*)(h1f + ((size_t)src1 << 6) + (h << 4));
            float a0 = s1s[src0 * 4 + h];
            float a1 = s1s[src1 * 4 + h];
            float e0 = a0 + sdst; e0 = (e0 >= 0.f) ? e0 : 0.2f * e0;
            float e1 = a1 + sdst; e1 = (e1 >= 0.f) ? e1 : 0.2f * e1;
            float w0 = __expf(e0);
            float w1 = __expf(e1);
            den += w0 + w1;
            fp8x16_fma2(W0, w0, xq);
            fp8x16_fma2(W1, w1, xq);
        }
        if (i < end) {
            int src = csr_src[i];
            uint4 Wv = *(const uint4*)(h1f + ((size_t)src << 6) + (h << 4));
            float ss = s1s[src * 4 + h] + sdst;
            ss = (ss >= 0.f) ? ss : 0.2f * ss;
            float we = __expf(ss);
            den += we;
            fp8x16_fma2(Wv, we, xq);
        }
    }
    float* xl = (float*)xq;
    // merge edge-quarters within each head
    #pragma unroll
    for (int j = 0; j < 16; ++j) {
        xl[j] += __shfl_xor(xl[j], 4);
        xl[j] += __shfl_xor(xl[j], 8);
    }
    den += __shfl_xor(den, 4);
    den += __shfl_xor(den, 8);

    float inv = 1.f / (den + 1e-16f);
    #pragma unroll
    for (int j = 0; j < 16; ++j) {
        float v = xl[j] * inv + b1[h * 16 + j];
        xl[j] = (v > 0.f) ? v : (__expf(v) - 1.f);
    }

    // fused layer-2 matmul, c-split across subs: sub0:c0-2 sub1:c3-5 sub2:c6-8 sub3:c9
    int clo = sub * 3;
    int nc = (sub == 3) ? 1 : 3;
    float part[3] = {0.f, 0.f, 0.f};
    #pragma unroll
    for (int idx = 0; idx < 3; ++idx) {
        if (idx < nc) {
            const float* wr = &w2s[(clo + idx) * 64 + h * 16];
            float p = 0.f;
            #pragma unroll
            for (int j = 0; j < 16; ++j) p += xl[j] * wr[j];
            part[idx] = p;
        }
    }
    #pragma unroll
    for (int idx = 0; idx < 3; ++idx) {
        part[idx] += __shfl_xor(part[idx], 1);
        part[idx] += __shfl_xor(part[idx], 2);
    }
    float ssp = 0.f, sdp = 0.f;
    #pragma unroll
    for (int idx = 0; idx < 3; ++idx) {
        if (idx < nc) {
            ssp += part[idx] * as2[clo + idx];
            sdp += part[idx] * ad2[clo + idx];
        }
    }
    ssp += __shfl_xor(ssp, 4); ssp += __shfl_xor(ssp, 8);
    sdp += __shfl_xor(sdp, 4); sdp += __shfl_xor(sdp, 8);

    if (n < N && h == 0) {
        #pragma unroll
        for (int idx = 0; idx < 3; ++idx)
            if (idx < nc)
                h2p[(size_t)n * 16 + clo + idx] = (unsigned short)f2bf(part[idx]);
        if (sub == 3) {
            h2p[(size_t)n * 16 + 10] = (unsigned short)f2bf(ssp);
            h2p[(size_t)n * 16 + 11] = (unsigned short)f2bf(sdp);
        }
    }
}

// ---- Conv2 aggregation (bf16 rows, 8 threads/node, 2-edge unroll) -> node_out ----
__global__ __launch_bounds__(256) void agg2_kernel(
    const int* __restrict__ meta, const int* __restrict__ csr_src,
    const unsigned short* __restrict__ h2p, const float* __restrict__ b2,
    float* __restrict__ node_out, int N)
{
    int tid = blockIdx.x * 256 + threadIdx.x;
    int n = tid >> 3, t = tid & 7;
    if (n >= N) return;
    floatx2 aq[5];
    #pragma unroll
    for (int c = 0; c < 5; ++c) { aq[c][0] = 0.f; aq[c][1] = 0.f; }
    float den = 0.f;

    uint2 d1 = *(const uint2*)(h2p + (size_t)n * 16 + 8);  // {c8|c9, ss|sd}
    float sdst = bfhi(d1.y);
    if (t == 0) {
        uint4 d0 = *(const uint4*)(h2p + (size_t)n * 16);
        float s = bflo(d1.y) + sdst;
        s = (s >= 0.f) ? s : 0.2f * s;
        float w = __expf(s);
        den = w;
        floatx2 w2; w2[0] = w; w2[1] = w;
        floatx2 p;
        p[0] = bflo(d0.x); p[1] = bfhi(d0.x); aq[0] += w2 * p;
        p[0] = bflo(d0.y); p[1] = bfhi(d0.y); aq[1] += w2 * p;
        p[0] = bflo(d0.z); p[1] = bfhi(d0.z); aq[2] += w2 * p;
        p[0] = bflo(d0.w); p[1] = bfhi(d0.w); aq[3] += w2 * p;
        p[0] = bflo(d1.x); p[1] = bfhi(d1.x); aq[4] += w2 * p;
    }
    int mn = meta[n];
    int row = (n >> BSHIFT) * BCAP + (mn >> 16);
    int end = row + (mn & 0xFFFF);
    int i = row + t;
    for (; i + 8 < end; i += 16) {        // two edges per iteration (MLP)
        int src0 = csr_src[i];
        int src1 = csr_src[i + 8];
        uint4 A0 = *(const uint4*)(h2p + (size_t)src0 * 16);
        uint2 B0 = *(const uint2*)(h2p + (size_t)src0 * 16 + 8);
        uint4 A1 = *(const uint4*)(h2p + (size_t)src1 * 16);
        uint2 B1 = *(const uint2*)(h2p + (size_t)src1 * 16 + 8);
        float e0 = bflo(B0.y) + sdst; e0 = (e0 >= 0.f) ? e0 : 0.2f * e0;
        float e1 = bflo(B1.y) + sdst; e1 = (e1 >= 0.f) ? e1 : 0.2f * e1;
        float w0 = __expf(e0);
        float w1 = __expf(e1);
        den += w0 + w1;
        floatx2 w20; w20[0] = w0; w20[1] = w0;
        floatx2 w21; w21[0] = w1; w21[1] = w1;
        floatx2 p;
        p[0] = bflo(A0.x); p[1] = bfhi(A0.x); aq[0] += w20 * p;
        p[0] = bflo(A0.y); p[1] = bfhi(A0.y); aq[1] += w20 * p;
        p[0] = bflo(A0.z); p[1] = bfhi(A0.z); aq[2] += w20 * p;
        p[0] = bflo(A0.w); p[1] = bfhi(A0.w); aq[3] += w20 * p;
        p[0] = bflo(B0.x); p[1] = bfhi(B0.x); aq[4] += w20 * p;
        p[0] = bflo(A1.x); p[1] = bfhi(A1.x); aq[0] += w21 * p;
        p[0] = bflo(A1.y); p[1] = bfhi(A1.y); aq[1] += w21 * p;
        p[0] = bflo(A1.z); p[1] = bfhi(A1.z); aq[2] += w21 * p;
        p[0] = bflo(A1.w); p[1] = bfhi(A1.w); aq[3] += w21 * p;
        p[0] = bflo(B1.x); p[1] = bfhi(B1.x); aq[4] += w21 * p;
    }
    if (i < end) {
        int src = csr_src[i];
        uint4 A0 = *(const uint4*)(h2p + (size_t)src * 16);
        uint2 B0 = *(const uint2*)(h2p + (size_t)src * 16 + 8);
        float s = bflo(B0.y) + sdst;
        s = (s >= 0.f) ? s : 0.2f * s;
        float we = __expf(s);
        den += we;
        floatx2 w2; w2[0] = we; w2[1] = we;
        floatx2 p;
        p[0] = bflo(A0.x); p[1] = bfhi(A0.x); aq[0] += w2 * p;
        p[0] = bflo(A0.y); p[1] = bfhi(A0.y); aq[1] += w2 * p;
        p[0] = bflo(A0.z); p[1] = bfhi(A0.z); aq[2] += w2 * p;
        p[0] = bflo(A0.w); p[1] = bfhi(A0.w); aq[3] += w2 * p;
        p[0] = bflo(B0.x); p[1] = bfhi(B0.x); aq[4] += w2 * p;
    }
    float* acc = (float*)aq;
    #pragma unroll
    for (int c = 0; c < 10; ++c) {
        acc[c] += __shfl_xor(acc[c], 1);
        acc[c] += __shfl_xor(acc[c], 2);
        acc[c] += __shfl_xor(acc[c], 4);
    }
    den += __shfl_xor(den, 1);
    den += __shfl_xor(den, 2);
    den += __shfl_xor(den, 4);

    if (t == 0) {
        float inv = 1.f / (den + 1e-16f);
        float* o = &node_out[(size_t)n * 12];
        *(float4*)o = make_float4(acc[0]*inv + b2[0], acc[1]*inv + b2[1],
                                  acc[2]*inv + b2[2], acc[3]*inv + b2[3]);
        *(float4*)(o + 4) = make_float4(acc[4]*inv + b2[4], acc[5]*inv + b2[5],
                                        acc[6]*inv + b2[6], acc[7]*inv + b2[7]);
        *(float2*)(o + 8) = make_float2(acc[8]*inv + b2[8], acc[9]*inv + b2[9]);
    }
}

// ---- Pool: one block per graph; batch sorted -> binary-search range; no atomics ----
__global__ __launch_bounds__(256) void pool_kernel(
    const float* __restrict__ node_out, const int* __restrict__ batch,
    float* __restrict__ pooled, float* __restrict__ cnt, int N)
{
    int g = blockIdx.x;
    int lo = 0, hi = N;
    while (lo < hi) { int m = (lo + hi) >> 1; if (batch[m] < g) lo = m + 1; else hi = m; }
    int s0 = lo;
    hi = N;
    while (lo < hi) { int m = (lo + hi) >> 1; if (batch[m] < g + 1) lo = m + 1; else hi = m; }
    int s1 = lo;

    float acc[10];
    #pragma unroll
    for (int c = 0; c < 10; ++c) acc[c] = 0.f;
    for (int i = s0 + threadIdx.x; i < s1; i += 256) {
        const float* o = &node_out[(size_t)i * 12];
        float4 a = *(const float4*)o;
        float4 b = *(const float4*)(o + 4);
        float2 d = *(const float2*)(o + 8);
        acc[0] += a.x; acc[1] += a.y; acc[2] += a.z; acc[3] += a.w;
        acc[4] += b.x; acc[5] += b.y; acc[6] += b.z; acc[7] += b.w;
        acc[8] += d.x; acc[9] += d.y;
    }
    #pragma unroll
    for (int c = 0; c < 10; ++c)
        for (int o = 32; o > 0; o >>= 1) acc[c] += __shfl_down(acc[c], o);
    __shared__ float part[4][10];
    int wave = threadIdx.x >> 6, lane = threadIdx.x & 63;
    if (lane == 0)
        #pragma unroll
        for (int c = 0; c < 10; ++c) part[wave][c] = acc[c];
    __syncthreads();
    if (threadIdx.x < 10) {
        float s = part[0][threadIdx.x] + part[1][threadIdx.x]
                + part[2][threadIdx.x] + part[3][threadIdx.x];
        pooled[g * 10 + threadIdx.x] = s;
        if (threadIdx.x == 0) cnt[g] = (float)(s1 - s0);
    }
}

// ---------------- Final: mean + log_softmax ----------------
__global__ void final_kernel(const float* __restrict__ pooled,
                             const float* __restrict__ cnt, float* __restrict__ out)
{
    int g = threadIdx.x;
    if (g >= 64) return;
    float c = cnt[g];
    if (c < 1.f) c = 1.f;
    float v[10], m = -1e30f;
    #pragma unroll
    for (int i = 0; i < 10; ++i) {
        v[i] = pooled[g * 10 + i] / c;
        m = fmaxf(m, v[i]);
    }
    float s = 0.f;
    #pragma unroll
    for (int i = 0; i < 10; ++i) s += __expf(v[i] - m);
    float lse = m + logf(s);
    #pragma unroll
    for (int i = 0; i < 10; ++i) out[g * 10 + i] = v[i] - lse;
}

extern "C" void kernel_launch(void* const* d_in, const int* in_sizes, int n_in,
                              void* d_out, int out_size, void* d_ws, size_t ws_size,
                              hipStream_t stream) {
    const float* x       = (const float*)d_in[0];
    const int*   ei      = (const int*)  d_in[1];
    const int*   batch   = (const int*)  d_in[2];
    const float* W1      = (const float*)d_in[3];
    const float* a_src1  = (const float*)d_in[4];
    const float* a_dst1  = (const float*)d_in[5];
    const float* b1      = (const float*)d_in[6];
    const float* W2      = (const float*)d_in[7];
    const float* a_src2  = (const float*)d_in[8];
    const float* a_dst2  = (const float*)d_in[9];
    const float* b2      = (const float*)d_in[10];
    float* out = (float*)d_out;

    int N = in_sizes[0] / 128;
    int E = in_sizes[1] / 2;
    int NBK = (N + BWIDTH - 1) >> BSHIFT;

    float* f = (float*)d_ws;
    size_t off = 0;
    unsigned char* h1f = (unsigned char*)(f + off);
    float* node_out = (float*)h1f;      // aliased: h1f dead after agg1, node_out agg2..pool
    off += (size_t)N * 16;              // N*64 fp8 bytes = N*16 floats (>= N*12 floats)
    float* s1s  = f + off; off += (size_t)N * 4;
    float* s1d  = f + off; off += (size_t)N * 4;
    // time-aliased: pairs (NBK*BCAP ints, live partition..buildcsr) then h2p (N*16 bf16)
    unsigned short* h2p = (unsigned short*)(f + off);
    int*  pairs = (int*)(f + off);
    size_t r1 = ((size_t)N * 8 > (size_t)NBK * BCAP) ? (size_t)N * 8 : (size_t)NBK * BCAP;
    off += r1;
    int* iw = (int*)(f + off);
    size_t ioff = 0;
    int* meta    = iw + ioff; ioff += (size_t)N;
    int* csr_src = iw + ioff; ioff += (size_t)NBK * BCAP;
    int* bcnt    = iw + ioff; ioff += (size_t)NBK;
    float* pooled = (float*)(iw + ioff);
    float* cnt    = pooled + 640;

    hipMemsetAsync((void*)bcnt, 0, (size_t)NBK * sizeof(int), stream);

    int g1_blocks = (N + G1_BM - 1) / G1_BM;
    int ntiles = (E + A3_TILE - 1) / A3_TILE;
    gp_kernel<<<g1_blocks + ntiles, 256, 0, stream>>>(
        x, W1, a_src1, a_dst1, h1f, s1s, s1d, ei, bcnt, pairs, N, E, NBK, g1_blocks);

    buildcsr_kernel<<<NBK, 256, 0, stream>>>(pairs, bcnt, csr_src, meta, N);

    agg1_kernel<<<(N * 16 + 255) / 256, 256, 0, stream>>>(
        meta, csr_src, h1f, s1s, s1d, b1, W2, a_src2, a_dst2, h2p, N);

    agg2_kernel<<<(N * 8 + 255) / 256, 256, 0, stream>>>(
        meta, csr_src, h2p, b2, node_out, N);

    pool_kernel<<<64, 256, 0, stream>>>(node_out, batch, pooled, cnt, N);

    final_kernel<<<1, 64, 0, stream>>>(pooled, cnt, out);
}